// Round 9
// baseline (491.182 us; speedup 1.0000x reference)
//
#include <hip/hip_runtime.h>
#include <cstdint>
#include <cstddef>

#define DI __device__ __forceinline__

typedef int v4i  __attribute__((ext_vector_type(4)));
typedef int v16i __attribute__((ext_vector_type(16)));

#if defined(__has_builtin)
#if __has_builtin(__builtin_amdgcn_sdot4)
#define HAS_SDOT4 1
#endif
#if __has_builtin(__builtin_amdgcn_alignbyte)
#define HAS_ALIGNBYTE 1
#endif
#endif

DI int dot4(unsigned a, unsigned b, int c) {
#ifdef HAS_SDOT4
  return __builtin_amdgcn_sdot4((int)a, (int)b, c, false);
#else
#pragma unroll
  for (int k = 0; k < 4; ++k)
    c += (int)(signed char)(a >> (8 * k)) * (int)(signed char)(b >> (8 * k));
  return c;
#endif
}

DI unsigned alignb(unsigned hi, unsigned lo, int sh) {  // bytes (hi:lo) >> 8*sh
#ifdef HAS_ALIGNBYTE
  return __builtin_amdgcn_alignbyte(hi, lo, sh);
#else
  return (lo >> (8 * sh)) | (hi << (32 - 8 * sh));
#endif
}

// ---------------- scalar block in workspace ----------------
struct Scal {
  unsigned max_x, max_w1, max_w2, max_wf1, max_wf2;  // float bits (abs-max, >=0)
  float s_in, sw1, sw2, swf1, swf2;
  int   max1; float s1;
  int   max2; float s2;
};

static constexpr int NX   = 32 * 3 * 224 * 224;     // 4,816,896
static constexpr int NP1  = 32 * 32 * 222 * 224;    // 50,921,472 padded conv1 outputs
static constexpr int NPIX = 222 * 224;              // 49,728 padded pixels per image
static constexpr int NW2 = 32 * 220 * 7;            // conv2 waves: 32 px x 64 oc tiles

// ---------------- reduction helpers (blockDim == 256) ----------------
DI float wave_maxf(float v) { for (int o = 32; o; o >>= 1) v = fmaxf(v, __shfl_down(v, o, 64)); return v; }
DI int   wave_maxi(int v)   { for (int o = 32; o; o >>= 1) v = max(v, __shfl_down(v, o, 64));   return v; }

DI float block_maxf(float v) {  // valid in thread 0; all values >= 0
  __shared__ float s[4];
  v = wave_maxf(v);
  int lane = threadIdx.x & 63, w = threadIdx.x >> 6;
  if (!lane) s[w] = v;
  __syncthreads();
  if (threadIdx.x < 64) {
    float t = (threadIdx.x < 4) ? s[threadIdx.x] : 0.f;
    v = wave_maxf(t);
  }
  return v;
}

DI int block_maxi(int v) {  // valid in thread 0; all values >= 0
  __shared__ int s[4];
  v = wave_maxi(v);
  int lane = threadIdx.x & 63, w = threadIdx.x >> 6;
  if (!lane) s[w] = v;
  __syncthreads();
  if (threadIdx.x < 64) {
    int t = (threadIdx.x < 4) ? s[threadIdx.x] : 0;
    v = wave_maxi(t);
  }
  return v;
}

// ---------------- stage kernels ----------------
__global__ void k_absmax_x(const float4* __restrict__ x, int n4, unsigned* slot) {
  float m = 0.f;
  for (int i = blockIdx.x * blockDim.x + threadIdx.x; i < n4; i += gridDim.x * blockDim.x) {
    float4 v = x[i];
    m = fmaxf(m, fmaxf(fmaxf(fabsf(v.x), fabsf(v.y)), fmaxf(fabsf(v.z), fabsf(v.w))));
  }
  m = block_maxf(m);
  if (!threadIdx.x) atomicMax(slot, __float_as_uint(m));
}

__global__ void k_absmax_w(const float* __restrict__ w1, const float* __restrict__ w2,
                           const float* __restrict__ wf1, const float* __restrict__ wf2,
                           Scal* sc) {
  const float* p; int n; unsigned* slot;
  if (blockIdx.x == 0)      { p = w1;  n = 864;   slot = &sc->max_w1; }
  else if (blockIdx.x == 1) { p = w2;  n = 18432; slot = &sc->max_w2; }
  else if (blockIdx.x == 2) { p = wf1; n = 8192;  slot = &sc->max_wf1; }
  else                      { p = wf2; n = 1280;  slot = &sc->max_wf2; }
  float m = 0.f;
  for (int i = threadIdx.x; i < n; i += blockDim.x) m = fmaxf(m, fabsf(p[i]));
  m = block_maxf(m);
  if (!threadIdx.x) atomicMax(slot, __float_as_uint(m));
}

__global__ void k_scales(Scal* sc) {
  sc->s_in = fmaxf(__uint_as_float(sc->max_x),  1e-8f) / 7.f;
  sc->sw1  = fmaxf(__uint_as_float(sc->max_w1), 1e-8f) / 7.f;
  sc->sw2  = fmaxf(__uint_as_float(sc->max_w2), 1e-8f) / 7.f;
  sc->swf1 = fmaxf(__uint_as_float(sc->max_wf1),1e-8f) / 7.f;
  sc->swf2 = fmaxf(__uint_as_float(sc->max_wf2),1e-8f) / 7.f;
}

// 4 floats -> 4 packed int8 codes per thread
__global__ void k_quant_x(const float4* __restrict__ x, unsigned* __restrict__ xq,
                          int n4, const Scal* __restrict__ sc) {
  float s = sc->s_in;
  int i = blockIdx.x * 256 + threadIdx.x;
  if (i >= n4) return;
  float4 v = x[i];
  float f[4] = {v.x, v.y, v.z, v.w};
  unsigned w = 0;
#pragma unroll
  for (int k = 0; k < 4; ++k) {
    float q = rintf(f[k] / s);
    q = fminf(fmaxf(q, -8.f), 7.f);
    w |= ((unsigned)((int)q & 255)) << (8 * k);
  }
  xq[i] = w;
}

// pack w1 as [oc][row] dwords {w0,w1,w2,0}; w2 as [oc][kh][kw][ic/4] dwords; bias1 ints
__global__ void k_quant_w(const float* __restrict__ w1, const float* __restrict__ w2,
                          const float* __restrict__ b1, const Scal* __restrict__ sc,
                          unsigned* __restrict__ w1pk, unsigned* __restrict__ w2pk,
                          int* __restrict__ bint1) {
  int i = blockIdx.x * blockDim.x + threadIdx.x;
  if (i < 288) {
    int oc = i / 9, r = i - oc * 9;   // r = ic*3 + kh; bytes = kw 0..2
    float s = sc->sw1;
    unsigned w = 0;
#pragma unroll
    for (int k = 0; k < 3; ++k) {
      float q = rintf(w1[oc * 27 + r * 3 + k] / s);
      q = fminf(fmaxf(q, -8.f), 7.f);
      w |= ((unsigned)((int)q & 255)) << (8 * k);
    }
    w1pk[i] = w;
  } else if (i < 288 + 4608) {
    int j = i - 288;           // output dword index
    int d = j & 7; int t = j >> 3;
    int kw = t % 3; t /= 3;
    int kh = t % 3; int oc = t / 3;
    float s = sc->sw2;
    unsigned w = 0;
#pragma unroll
    for (int k = 0; k < 4; ++k) {
      int ic = d * 4 + k;
      float q = rintf(w2[(oc * 32 + ic) * 9 + kh * 3 + kw] / s);
      q = fminf(fmaxf(q, -8.f), 7.f);
      w |= ((unsigned)((int)q & 255)) << (8 * k);
    }
    w2pk[j] = w;
  } else if (i < 288 + 4608 + 32) {
    int j = i - 4896;
    bint1[j] = (int)rintf(b1[j] / (sc->s_in * sc->sw1));
  }
}

// conv1 LDS-tiled: one block = (b, strip of 6 oh rows). Stage 3 ic x 8 input
// rows (5.3 KB) + weights + bias in LDS once; 256 threads sweep 28 g x 6 oh x
// 32 oc tasks (21 iters) with sdot4+alignbyte on LDS segments. Stores planar
// int16 acc; block max of relu(acc) over valid cols.
__global__ void __launch_bounds__(256) k_conv1(
    const signed char* __restrict__ xq, const unsigned* __restrict__ w1pk,
    const int* __restrict__ bint1, short* __restrict__ y1acc, int* __restrict__ max1) {
  __shared__ signed char lx[3 * 8 * 224 + 16];  // [ic][row 0..7][224] + pad
  __shared__ unsigned lw[288];
  __shared__ int lb[32];
  int tid = threadIdx.x;
  int strip = blockIdx.x;   // 0..36 (222 = 6*37)
  int b = blockIdx.y;       // 0..31
  int oh0 = strip * 6;

  for (int i = tid; i < 288; i += 256) lw[i] = w1pk[i];
  if (tid < 32) lb[tid] = bint1[tid];
  {
    const unsigned* src = (const unsigned*)(xq + (size_t)b * 3 * 224 * 224);
    unsigned* dst = (unsigned*)lx;
    // 24 rows x 56 dwords = 1344 dwords, coalesced
#pragma unroll
    for (int it = 0; it < 6; ++it) {
      int i = it * 256 + tid;
      if (i < 1344) {
        int row = i / 56, d = i - row * 56;   // row = ic*8 + r
        int ic = row >> 3, r = row & 7;
        dst[i] = src[(ic * 224 + (oh0 + r)) * 56 + d];
      }
    }
  }
  __syncthreads();

  int mx = 0;
  for (int it = 0; it < 21; ++it) {
    int i = it * 256 + tid;          // 5376 tasks: g fast, then oh_l, then oc
    int g = i % 28;
    int r = i / 28;
    int oh_l = r % 6;
    int oc = r / 6;

    int bias = lb[oc];
    int acc[8];
#pragma unroll
    for (int j = 0; j < 8; ++j) acc[j] = bias;

#pragma unroll
    for (int seg = 0; seg < 9; ++seg) {
      int ic = seg / 3, kh = seg - ic * 3;
      const signed char* base = lx + (ic * 8 + oh_l + kh) * 224 + g * 8;
      uint2 lo = *(const uint2*)base;            // 8B aligned
      unsigned d0 = lo.x, d1 = lo.y;
      unsigned d2 = *(const unsigned*)(base + 8);
      unsigned wr = lw[oc * 9 + ic * 3 + kh];
      acc[0] = dot4(d0, wr, acc[0]);
      acc[1] = dot4(alignb(d1, d0, 1), wr, acc[1]);
      acc[2] = dot4(alignb(d1, d0, 2), wr, acc[2]);
      acc[3] = dot4(alignb(d1, d0, 3), wr, acc[3]);
      acc[4] = dot4(d1, wr, acc[4]);
      acc[5] = dot4(alignb(d2, d1, 1), wr, acc[5]);
      acc[6] = dot4(alignb(d2, d1, 2), wr, acc[6]);
      acc[7] = dot4(alignb(d2, d1, 3), wr, acc[7]);
    }

    size_t off = ((size_t)((b * 32 + oc) * 222 + oh0 + oh_l)) * 224 + g * 8;
    uint4 st;
    st.x = ((unsigned)(unsigned short)acc[0]) | ((unsigned)(unsigned short)acc[1] << 16);
    st.y = ((unsigned)(unsigned short)acc[2]) | ((unsigned)(unsigned short)acc[3] << 16);
    st.z = ((unsigned)(unsigned short)acc[4]) | ((unsigned)(unsigned short)acc[5] << 16);
    st.w = ((unsigned)(unsigned short)acc[6]) | ((unsigned)(unsigned short)acc[7] << 16);
    *(uint4*)(y1acc + off) = st;

#pragma unroll
    for (int j = 0; j < 8; ++j) if (g * 8 + j < 222) mx = max(mx, acc[j]);
  }
  mx = block_maxi(max(mx, 0));
  if (!tid) atomicMax(max1, mx);
}

__global__ void k_fin1(Scal* sc, const float* __restrict__ b2, int* __restrict__ bint2) {
  float sc1 = sc->s_in * sc->sw1;
  float s1 = fmaxf((float)sc->max1 * sc1, 1e-8f) / 15.f;
  if (!threadIdx.x) sc->s1 = s1;
  float sb = s1 * sc->sw2;
  bint2[threadIdx.x] = (int)rintf(b2[threadIdx.x] / sb);
}

// int16 planar acc -> NHWC uint8 relu4 codes (32 ic bytes contiguous per pixel)
__global__ void k_requant_t(const short* __restrict__ y1acc, const Scal* __restrict__ sc,
                            unsigned char* __restrict__ y1n) {
  int p = blockIdx.x * 256 + threadIdx.x;  // pixel within image (padded space)
  int b = blockIdx.y;
  if (p >= NPIX) return;
  float sc1 = sc->s_in * sc->sw1, s1 = sc->s1;
  const short* base = y1acc + (size_t)b * 32 * NPIX + p;
  unsigned w[8] = {0, 0, 0, 0, 0, 0, 0, 0};
#pragma unroll
  for (int oc = 0; oc < 32; ++oc) {
    int a = (int)base[(size_t)oc * NPIX];
    float y = (float)a * sc1;
    float q = rintf(y / s1);
    q = fminf(fmaxf(q, 0.f), 15.f);
    w[oc >> 2] |= ((unsigned)(int)q) << (8 * (oc & 3));
  }
  uint4* dst = (uint4*)(y1n + ((size_t)b * NPIX + p) * 32);
  dst[0] = make_uint4(w[0], w[1], w[2], w[3]);
  dst[1] = make_uint4(w[4], w[5], w[6], w[7]);
}

// conv2 pass A: MFMA i8 implicit GEMM, max(relu(acc)) only — no stores.
__global__ void __launch_bounds__(256) k_conv2a(
    const unsigned char* __restrict__ y1n, const unsigned* __restrict__ w2pk,
    const int* __restrict__ bint2, int* __restrict__ max2) {
  __shared__ unsigned lw[4608];
  int tid = threadIdx.x;
  for (int i = tid; i < 4608; i += 256) {
    int oc = i / 72, r = i - oc * 72;
    int tap = r >> 3, icq = r & 7;
    int dl = (oc & 31) | ((icq >> 2) << 5);
    lw[(((tap * 2) + (oc >> 5)) * 64 + dl) * 4 + (icq & 3)] = w2pk[i];
  }
  __syncthreads();

  int lane = tid & 63;
  int lane31 = lane & 31, lhalf = lane >> 5;
  int wv = blockIdx.x * 4 + (tid >> 6);
  int owg = wv % 7; int t = wv / 7;
  int oh = t % 220; int b = t / 220;
  int ow0 = owg * 32;

  int bias0 = bint2[lane31];
  int bias1 = bint2[32 + lane31];
  v16i acc0, acc1;
#pragma unroll
  for (int r = 0; r < 16; ++r) { acc0[r] = bias0; acc1[r] = bias1; }

  size_t aoff = (size_t)lane31 * 32 + (size_t)lhalf * 16;
#pragma unroll
  for (int kh = 0; kh < 3; ++kh) {
    const unsigned char* rowb = y1n + ((size_t)((b * 222 + oh + kh) * 224 + ow0)) * 32 + aoff;
#pragma unroll
    for (int kw = 0; kw < 3; ++kw) {
      int tap = kh * 3 + kw;
      v4i a = *(const v4i*)(rowb + kw * 32);
      v4i b0 = *(const v4i*)(lw + ((tap * 2 + 0) * 64 + lane) * 4);
      v4i b1 = *(const v4i*)(lw + ((tap * 2 + 1) * 64 + lane) * 4);
      acc0 = __builtin_amdgcn_mfma_i32_32x32x32_i8(a, b0, acc0, 0, 0, 0);
      acc1 = __builtin_amdgcn_mfma_i32_32x32x32_i8(a, b1, acc1, 0, 0, 0);
    }
  }

  int mx = 0;
#pragma unroll
  for (int r = 0; r < 16; ++r) {
    int m = (r & 3) + 8 * (r >> 2) + 4 * lhalf;
    if (ow0 + m < 220) mx = max(mx, max(acc0[r], acc1[r]));
  }
  mx = block_maxi(max(mx, 0));
  if (!tid) atomicMax(max2, mx);
}

// conv2 pass B: recompute acc, quantize in-register, accumulate per-(b,oc)
// integer sums (pool fused). b is block-uniform (1540 waves per b, 4 per block).
__global__ void __launch_bounds__(256) k_conv2b(
    const unsigned char* __restrict__ y1n, const unsigned* __restrict__ w2pk,
    const int* __restrict__ bint2, const Scal* __restrict__ sc,
    int* __restrict__ pooled_i) {
  __shared__ unsigned lw[4608];
  __shared__ int ls[64];
  int tid = threadIdx.x;
  for (int i = tid; i < 4608; i += 256) {
    int oc = i / 72, r = i - oc * 72;
    int tap = r >> 3, icq = r & 7;
    int dl = (oc & 31) | ((icq >> 2) << 5);
    lw[(((tap * 2) + (oc >> 5)) * 64 + dl) * 4 + (icq & 3)] = w2pk[i];
  }
  if (tid < 64) ls[tid] = 0;
  __syncthreads();

  int lane = tid & 63;
  int lane31 = lane & 31, lhalf = lane >> 5;
  int wv = blockIdx.x * 4 + (tid >> 6);
  int owg = wv % 7; int t = wv / 7;
  int oh = t % 220; int b = t / 220;
  int ow0 = owg * 32;

  int bias0 = bint2[lane31];
  int bias1 = bint2[32 + lane31];
  v16i acc0, acc1;
#pragma unroll
  for (int r = 0; r < 16; ++r) { acc0[r] = bias0; acc1[r] = bias1; }

  size_t aoff = (size_t)lane31 * 32 + (size_t)lhalf * 16;
#pragma unroll
  for (int kh = 0; kh < 3; ++kh) {
    const unsigned char* rowb = y1n + ((size_t)((b * 222 + oh + kh) * 224 + ow0)) * 32 + aoff;
#pragma unroll
    for (int kw = 0; kw < 3; ++kw) {
      int tap = kh * 3 + kw;
      v4i a = *(const v4i*)(rowb + kw * 32);
      v4i b0 = *(const v4i*)(lw + ((tap * 2 + 0) * 64 + lane) * 4);
      v4i b1 = *(const v4i*)(lw + ((tap * 2 + 1) * 64 + lane) * 4);
      acc0 = __builtin_amdgcn_mfma_i32_32x32x32_i8(a, b0, acc0, 0, 0, 0);
      acc1 = __builtin_amdgcn_mfma_i32_32x32x32_i8(a, b1, acc1, 0, 0, 0);
    }
  }

  float h = (sc->s1 * sc->sw2) * (1.0f / sc->s2);
  int isum0 = 0, isum1 = 0;
#pragma unroll
  for (int r = 0; r < 16; ++r) {
    int m = (r & 3) + 8 * (r >> 2) + 4 * lhalf;
    if (ow0 + m < 220) {
      float q0 = fminf(fmaxf(rintf((float)acc0[r] * h), 0.f), 15.f);
      float q1 = fminf(fmaxf(rintf((float)acc1[r] * h), 0.f), 15.f);
      isum0 += (int)q0;
      isum1 += (int)q1;
    }
  }
  isum0 += __shfl_down(isum0, 32, 64);
  isum1 += __shfl_down(isum1, 32, 64);
  if (lhalf == 0) {
    atomicAdd(&ls[lane31], isum0);
    atomicAdd(&ls[32 + lane31], isum1);
  }
  __syncthreads();
  if (tid < 64) atomicAdd(&pooled_i[b * 64 + tid], ls[tid]);
}

__global__ void k_fin2(Scal* sc) {
  sc->s2 = fmaxf((float)sc->max2 * (sc->s1 * sc->sw2), 1e-8f) / 15.f;
}

// whole FC head + log_softmax in one block
__global__ void k_fc(const int* __restrict__ pooled_i, const float* __restrict__ wf1,
                     const float* __restrict__ bf1, const float* __restrict__ wf2,
                     const float* __restrict__ bf2, const Scal* __restrict__ sc,
                     float* __restrict__ out) {
  __shared__ float pl[2048];
  __shared__ float wq1[8192];
  __shared__ float y3[4096];
  __shared__ float zz[320];
  __shared__ float s3sh;
  int tid = threadIdx.x;
  float swf1 = sc->swf1, swf2 = sc->swf2, s2 = sc->s2;
  for (int i = tid; i < 2048; i += 256) pl[i] = (float)pooled_i[i] * s2 / 48400.0f;
  for (int i = tid; i < 8192; i += 256) {
    float q = rintf(wf1[i] / swf1);
    q = fminf(fmaxf(q, -8.f), 7.f);
    wq1[i] = q * swf1;
  }
  __syncthreads();
  float sb1 = s2 * swf1;
  float lmax = 0.f;
  for (int o = tid; o < 4096; o += 256) {
    int b = o >> 7, j = o & 127;
    float acc = rintf(bf1[j] / sb1) * sb1;
    const float* wrow = &wq1[j * 64];
    const float* xrow = &pl[b * 64];
#pragma unroll 16
    for (int k = 0; k < 64; ++k) acc += xrow[k] * wrow[k];
    float r = fmaxf(acc, 0.f);
    y3[o] = r;
    lmax = fmaxf(lmax, r);
  }
  float m = block_maxf(lmax);  // contains a __syncthreads (after y3 writes)
  if (!tid) s3sh = fmaxf(m, 1e-8f) / 15.f;
  __syncthreads();
  float s3 = s3sh;
  float sb2 = s3 * swf2;
  for (int o = tid; o < 320; o += 256) {
    int b = o / 10, j = o - b * 10;
    float acc = rintf(bf2[j] / sb2) * sb2;
    const float* yy = &y3[b * 128];
    const float* wrow = &wf2[j * 128];
    for (int k = 0; k < 128; ++k) {
      float q = rintf(yy[k] / s3);
      q = fminf(fmaxf(q, 0.f), 15.f);
      float wv = rintf(wrow[k] / swf2);
      wv = fminf(fmaxf(wv, -8.f), 7.f);
      acc += (q * s3) * (wv * swf2);
    }
    zz[o] = acc;
  }
  __syncthreads();
  if (tid < 32) {
    const float* z = &zz[tid * 10];
    float mm = z[0];
    for (int k = 1; k < 10; ++k) mm = fmaxf(mm, z[k]);
    float ssum = 0.f;
    for (int k = 0; k < 10; ++k) ssum += expf(z[k] - mm);
    float l = mm + logf(ssum);
    for (int k = 0; k < 10; ++k) out[tid * 10 + k] = z[k] - l;
  }
}

extern "C" void kernel_launch(void* const* d_in, const int* in_sizes, int n_in,
                              void* d_out, int out_size, void* d_ws, size_t ws_size,
                              hipStream_t stream) {
  const float* x   = (const float*)d_in[0];
  const float* w1  = (const float*)d_in[1];
  const float* b1  = (const float*)d_in[2];
  const float* w2  = (const float*)d_in[3];
  const float* b2  = (const float*)d_in[4];
  const float* wf1 = (const float*)d_in[5];
  const float* bf1 = (const float*)d_in[6];
  const float* wf2 = (const float*)d_in[7];
  const float* bf2 = (const float*)d_in[8];
  float* out = (float*)d_out;

  char* ws = (char*)d_ws;
  Scal* sc = (Scal*)ws;
  size_t off = 1024;
  signed char* xq = (signed char*)(ws + off);   off += (size_t)NX + 256;  // +slack
  off = (off + 255) & ~(size_t)255;
  unsigned* w1pk = (unsigned*)(ws + off);       off += 2048;              // [oc][row] {w0,w1,w2,0}
  unsigned* w2pk = (unsigned*)(ws + off);       off += 4608 * 4;          // [oc][kh][kw][ic/4]
  int* bint1 = (int*)(ws + off);                off += 256;
  int* bint2 = (int*)(ws + off);                off += 256;
  unsigned char* y1n = (unsigned char*)(ws + off); off += (size_t)NP1;    // NHWC codes
  off = (off + 255) & ~(size_t)255;
  int* pooled_i = (int*)(ws + off);             off += 8192;              // also slack for conv2 tail reads
  off = (off + 255) & ~(size_t)255;
  short* y1acc = (short*)(ws + off);            off += (size_t)NP1 * 2;   // planar int16 conv1 acc
  (void)ws_size; (void)in_sizes; (void)n_in; (void)out_size;

  hipMemsetAsync(sc, 0, 1024, stream);
  hipMemsetAsync(pooled_i, 0, 8192, stream);
  k_absmax_x<<<1024, 256, 0, stream>>>((const float4*)x, NX / 4, &sc->max_x);
  k_absmax_w<<<4, 256, 0, stream>>>(w1, w2, wf1, wf2, sc);
  k_scales<<<1, 1, 0, stream>>>(sc);
  k_quant_x<<<NX / 4 / 256, 256, 0, stream>>>((const float4*)x, (unsigned*)xq, NX / 4, sc);
  k_quant_w<<<22, 256, 0, stream>>>(w1, w2, b1, sc, w1pk, w2pk, bint1);
  k_conv1<<<dim3(37, 32), 256, 0, stream>>>(xq, w1pk, bint1, y1acc, &sc->max1);
  k_fin1<<<1, 64, 0, stream>>>(sc, b2, bint2);
  k_requant_t<<<dim3(195, 32), 256, 0, stream>>>(y1acc, sc, y1n);
  k_conv2a<<<NW2 / 4, 256, 0, stream>>>(y1n, w2pk, bint2, &sc->max2);
  k_fin2<<<1, 1, 0, stream>>>(sc);
  k_conv2b<<<NW2 / 4, 256, 0, stream>>>(y1n, w2pk, bint2, sc, pooled_i);
  k_fc<<<1, 256, 0, stream>>>(pooled_i, wf1, bf1, wf2, bf2, sc, out);
}

// Round 10
// 479.394 us; speedup vs baseline: 1.0246x; 1.0246x over previous
//
#include <hip/hip_runtime.h>
#include <cstdint>
#include <cstddef>

#define DI __device__ __forceinline__

typedef int v4i  __attribute__((ext_vector_type(4)));
typedef int v16i __attribute__((ext_vector_type(16)));

#if defined(__has_builtin)
#if __has_builtin(__builtin_amdgcn_sdot4)
#define HAS_SDOT4 1
#endif
#if __has_builtin(__builtin_amdgcn_alignbyte)
#define HAS_ALIGNBYTE 1
#endif
#endif

DI int dot4(unsigned a, unsigned b, int c) {
#ifdef HAS_SDOT4
  return __builtin_amdgcn_sdot4((int)a, (int)b, c, false);
#else
#pragma unroll
  for (int k = 0; k < 4; ++k)
    c += (int)(signed char)(a >> (8 * k)) * (int)(signed char)(b >> (8 * k));
  return c;
#endif
}

DI unsigned alignb(unsigned hi, unsigned lo, int sh) {  // bytes (hi:lo) >> 8*sh
#ifdef HAS_ALIGNBYTE
  return __builtin_amdgcn_alignbyte(hi, lo, sh);
#else
  return (lo >> (8 * sh)) | (hi << (32 - 8 * sh));
#endif
}

// ---------------- scalar block in workspace ----------------
struct Scal {
  unsigned max_x, max_w1, max_w2, max_wf1, max_wf2;  // float bits (abs-max, >=0)
  float s_in, sw1, sw2, swf1, swf2;
  int   max1; float s1;
  int   max2; float s2;
};

static constexpr int NX   = 32 * 3 * 224 * 224;     // 4,816,896
static constexpr int NP1  = 32 * 32 * 222 * 224;    // 50,921,472 padded conv1 outputs
static constexpr int NPIX = 222 * 224;              // 49,728 padded pixels per image
static constexpr int NW2 = 32 * 220 * 7;            // conv2 waves: 32 px x 64 oc tiles

// ---------------- reduction helpers (blockDim == 256) ----------------
DI float wave_maxf(float v) { for (int o = 32; o; o >>= 1) v = fmaxf(v, __shfl_down(v, o, 64)); return v; }
DI int   wave_maxi(int v)   { for (int o = 32; o; o >>= 1) v = max(v, __shfl_down(v, o, 64));   return v; }

DI float block_maxf(float v) {  // valid in thread 0; all values >= 0
  __shared__ float s[4];
  v = wave_maxf(v);
  int lane = threadIdx.x & 63, w = threadIdx.x >> 6;
  if (!lane) s[w] = v;
  __syncthreads();
  if (threadIdx.x < 64) {
    float t = (threadIdx.x < 4) ? s[threadIdx.x] : 0.f;
    v = wave_maxf(t);
  }
  return v;
}

DI int block_maxi(int v) {  // valid in thread 0; all values >= 0
  __shared__ int s[4];
  v = wave_maxi(v);
  int lane = threadIdx.x & 63, w = threadIdx.x >> 6;
  if (!lane) s[w] = v;
  __syncthreads();
  if (threadIdx.x < 64) {
    int t = (threadIdx.x < 4) ? s[threadIdx.x] : 0;
    v = wave_maxi(t);
  }
  return v;
}

// ---------------- stage kernels ----------------
__global__ void k_absmax_x(const float4* __restrict__ x, int n4, unsigned* slot) {
  float m = 0.f;
  for (int i = blockIdx.x * blockDim.x + threadIdx.x; i < n4; i += gridDim.x * blockDim.x) {
    float4 v = x[i];
    m = fmaxf(m, fmaxf(fmaxf(fabsf(v.x), fabsf(v.y)), fmaxf(fabsf(v.z), fabsf(v.w))));
  }
  m = block_maxf(m);
  if (!threadIdx.x) atomicMax(slot, __float_as_uint(m));
}

__global__ void k_absmax_w(const float* __restrict__ w1, const float* __restrict__ w2,
                           const float* __restrict__ wf1, const float* __restrict__ wf2,
                           Scal* sc) {
  const float* p; int n; unsigned* slot;
  if (blockIdx.x == 0)      { p = w1;  n = 864;   slot = &sc->max_w1; }
  else if (blockIdx.x == 1) { p = w2;  n = 18432; slot = &sc->max_w2; }
  else if (blockIdx.x == 2) { p = wf1; n = 8192;  slot = &sc->max_wf1; }
  else                      { p = wf2; n = 1280;  slot = &sc->max_wf2; }
  float m = 0.f;
  for (int i = threadIdx.x; i < n; i += blockDim.x) m = fmaxf(m, fabsf(p[i]));
  m = block_maxf(m);
  if (!threadIdx.x) atomicMax(slot, __float_as_uint(m));
}

__global__ void k_scales(Scal* sc) {
  sc->s_in = fmaxf(__uint_as_float(sc->max_x),  1e-8f) / 7.f;
  sc->sw1  = fmaxf(__uint_as_float(sc->max_w1), 1e-8f) / 7.f;
  sc->sw2  = fmaxf(__uint_as_float(sc->max_w2), 1e-8f) / 7.f;
  sc->swf1 = fmaxf(__uint_as_float(sc->max_wf1),1e-8f) / 7.f;
  sc->swf2 = fmaxf(__uint_as_float(sc->max_wf2),1e-8f) / 7.f;
}

// 4 floats -> 4 packed int8 codes per thread
__global__ void k_quant_x(const float4* __restrict__ x, unsigned* __restrict__ xq,
                          int n4, const Scal* __restrict__ sc) {
  float s = sc->s_in;
  int i = blockIdx.x * 256 + threadIdx.x;
  if (i >= n4) return;
  float4 v = x[i];
  float f[4] = {v.x, v.y, v.z, v.w};
  unsigned w = 0;
#pragma unroll
  for (int k = 0; k < 4; ++k) {
    float q = rintf(f[k] / s);
    q = fminf(fmaxf(q, -8.f), 7.f);
    w |= ((unsigned)((int)q & 255)) << (8 * k);
  }
  xq[i] = w;
}

// pack w1 as [oc][row] dwords {w0,w1,w2,0}; w2 directly into the MFMA B-frag
// layout w2frag[((tap*2+half)*64 + dl)*4 + q] (what conv2's LDS staging used
// to compute per-block — now done once); bias1 ints
__global__ void k_quant_w(const float* __restrict__ w1, const float* __restrict__ w2,
                          const float* __restrict__ b1, const Scal* __restrict__ sc,
                          unsigned* __restrict__ w1pk, unsigned* __restrict__ w2frag,
                          int* __restrict__ bint1) {
  int i = blockIdx.x * blockDim.x + threadIdx.x;
  if (i < 288) {
    int oc = i / 9, r = i - oc * 9;   // r = ic*3 + kh; bytes = kw 0..2
    float s = sc->sw1;
    unsigned w = 0;
#pragma unroll
    for (int k = 0; k < 3; ++k) {
      float q = rintf(w1[oc * 27 + r * 3 + k] / s);
      q = fminf(fmaxf(q, -8.f), 7.f);
      w |= ((unsigned)((int)q & 255)) << (8 * k);
    }
    w1pk[i] = w;
  } else if (i < 288 + 4608) {
    int j = i - 288;
    int icq = j & 7; int t = j >> 3;
    int kw = t % 3; t /= 3;
    int kh = t % 3; int oc = t / 3;
    float s = sc->sw2;
    unsigned w = 0;
#pragma unroll
    for (int k = 0; k < 4; ++k) {
      int ic = icq * 4 + k;
      float q = rintf(w2[(oc * 32 + ic) * 9 + kh * 3 + kw] / s);
      q = fminf(fmaxf(q, -8.f), 7.f);
      w |= ((unsigned)((int)q & 255)) << (8 * k);
    }
    int tap = kh * 3 + kw;
    int dl = (oc & 31) | ((icq >> 2) << 5);
    w2frag[(((tap * 2) + (oc >> 5)) * 64 + dl) * 4 + (icq & 3)] = w;
  } else if (i < 288 + 4608 + 32) {
    int j = i - 4896;
    bint1[j] = (int)rintf(b1[j] / (sc->s_in * sc->sw1));
  }
}

// conv1 LDS-tiled: one block = (b, strip of 6 oh rows). Stage 3 ic x 8 input
// rows (5.3 KB) + weights + bias in LDS once; 256 threads sweep 28 g x 6 oh x
// 32 oc tasks (21 iters) with sdot4+alignbyte on LDS segments. Stores planar
// int16 acc; block max of relu(acc) over valid cols.
__global__ void __launch_bounds__(256) k_conv1(
    const signed char* __restrict__ xq, const unsigned* __restrict__ w1pk,
    const int* __restrict__ bint1, short* __restrict__ y1acc, int* __restrict__ max1) {
  __shared__ signed char lx[3 * 8 * 224 + 16];  // [ic][row 0..7][224] + pad
  __shared__ unsigned lw[288];
  __shared__ int lb[32];
  int tid = threadIdx.x;
  int strip = blockIdx.x;   // 0..36 (222 = 6*37)
  int b = blockIdx.y;       // 0..31
  int oh0 = strip * 6;

  for (int i = tid; i < 288; i += 256) lw[i] = w1pk[i];
  if (tid < 32) lb[tid] = bint1[tid];
  {
    const unsigned* src = (const unsigned*)(xq + (size_t)b * 3 * 224 * 224);
    unsigned* dst = (unsigned*)lx;
    // 24 rows x 56 dwords = 1344 dwords, coalesced
#pragma unroll
    for (int it = 0; it < 6; ++it) {
      int i = it * 256 + tid;
      if (i < 1344) {
        int row = i / 56, d = i - row * 56;   // row = ic*8 + r
        int ic = row >> 3, r = row & 7;
        dst[i] = src[(ic * 224 + (oh0 + r)) * 56 + d];
      }
    }
  }
  __syncthreads();

  int mx = 0;
  for (int it = 0; it < 21; ++it) {
    int i = it * 256 + tid;          // 5376 tasks: g fast, then oh_l, then oc
    int g = i % 28;
    int r = i / 28;
    int oh_l = r % 6;
    int oc = r / 6;

    int bias = lb[oc];
    int acc[8];
#pragma unroll
    for (int j = 0; j < 8; ++j) acc[j] = bias;

#pragma unroll
    for (int seg = 0; seg < 9; ++seg) {
      int ic = seg / 3, kh = seg - ic * 3;
      const signed char* base = lx + (ic * 8 + oh_l + kh) * 224 + g * 8;
      uint2 lo = *(const uint2*)base;            // 8B aligned
      unsigned d0 = lo.x, d1 = lo.y;
      unsigned d2 = *(const unsigned*)(base + 8);
      unsigned wr = lw[oc * 9 + ic * 3 + kh];
      acc[0] = dot4(d0, wr, acc[0]);
      acc[1] = dot4(alignb(d1, d0, 1), wr, acc[1]);
      acc[2] = dot4(alignb(d1, d0, 2), wr, acc[2]);
      acc[3] = dot4(alignb(d1, d0, 3), wr, acc[3]);
      acc[4] = dot4(d1, wr, acc[4]);
      acc[5] = dot4(alignb(d2, d1, 1), wr, acc[5]);
      acc[6] = dot4(alignb(d2, d1, 2), wr, acc[6]);
      acc[7] = dot4(alignb(d2, d1, 3), wr, acc[7]);
    }

    size_t off = ((size_t)((b * 32 + oc) * 222 + oh0 + oh_l)) * 224 + g * 8;
    uint4 st;
    st.x = ((unsigned)(unsigned short)acc[0]) | ((unsigned)(unsigned short)acc[1] << 16);
    st.y = ((unsigned)(unsigned short)acc[2]) | ((unsigned)(unsigned short)acc[3] << 16);
    st.z = ((unsigned)(unsigned short)acc[4]) | ((unsigned)(unsigned short)acc[5] << 16);
    st.w = ((unsigned)(unsigned short)acc[6]) | ((unsigned)(unsigned short)acc[7] << 16);
    *(uint4*)(y1acc + off) = st;

#pragma unroll
    for (int j = 0; j < 8; ++j) if (g * 8 + j < 222) mx = max(mx, acc[j]);
  }
  mx = block_maxi(max(mx, 0));
  if (!tid) atomicMax(max1, mx);
}

__global__ void k_fin1(Scal* sc, const float* __restrict__ b2, int* __restrict__ bint2) {
  float sc1 = sc->s_in * sc->sw1;
  float s1 = fmaxf((float)sc->max1 * sc1, 1e-8f) / 15.f;
  if (!threadIdx.x) sc->s1 = s1;
  float sb = s1 * sc->sw2;
  bint2[threadIdx.x] = (int)rintf(b2[threadIdx.x] / sb);
}

// int16 planar acc -> NHWC uint8 relu4 codes (32 ic bytes contiguous per pixel)
__global__ void k_requant_t(const short* __restrict__ y1acc, const Scal* __restrict__ sc,
                            unsigned char* __restrict__ y1n) {
  int p = blockIdx.x * 256 + threadIdx.x;  // pixel within image (padded space)
  int b = blockIdx.y;
  if (p >= NPIX) return;
  float sc1 = sc->s_in * sc->sw1, s1 = sc->s1;
  const short* base = y1acc + (size_t)b * 32 * NPIX + p;
  unsigned w[8] = {0, 0, 0, 0, 0, 0, 0, 0};
#pragma unroll
  for (int oc = 0; oc < 32; ++oc) {
    int a = (int)base[(size_t)oc * NPIX];
    float y = (float)a * sc1;
    float q = rintf(y / s1);
    q = fminf(fmaxf(q, 0.f), 15.f);
    w[oc >> 2] |= ((unsigned)(int)q) << (8 * (oc & 3));
  }
  uint4* dst = (uint4*)(y1n + ((size_t)b * NPIX + p) * 32);
  dst[0] = make_uint4(w[0], w[1], w[2], w[3]);
  dst[1] = make_uint4(w[4], w[5], w[6], w[7]);
}

// conv2 pass A: MFMA i8 implicit GEMM, max(relu(acc)) only — no stores, no LDS
// weights (B-frags read directly from w2frag, 18KB, L2/L3-hot, coalesced
// 1024B wave loads). 9 A-frag loads issued upfront.
__global__ void __launch_bounds__(256) k_conv2a(
    const unsigned char* __restrict__ y1n, const unsigned* __restrict__ w2frag,
    const int* __restrict__ bint2, int* __restrict__ max2) {
  int tid = threadIdx.x;
  int lane = tid & 63;
  int lane31 = lane & 31, lhalf = lane >> 5;
  int wv = blockIdx.x * 4 + (tid >> 6);
  int owg = wv % 7; int t = wv / 7;
  int oh = t % 220; int b = t / 220;
  int ow0 = owg * 32;

  size_t aoff = (size_t)lane31 * 32 + (size_t)lhalf * 16;
  const unsigned char* base0 = y1n + ((size_t)((b * 222 + oh) * 224 + ow0)) * 32 + aoff;
  v4i a[9];
#pragma unroll
  for (int kh = 0; kh < 3; ++kh)
#pragma unroll
    for (int kw = 0; kw < 3; ++kw)
      a[kh * 3 + kw] = *(const v4i*)(base0 + (size_t)kh * (224 * 32) + kw * 32);

  int bias0 = bint2[lane31];
  int bias1 = bint2[32 + lane31];
  v16i acc0, acc1;
#pragma unroll
  for (int r = 0; r < 16; ++r) { acc0[r] = bias0; acc1[r] = bias1; }

  const v4i* wf = (const v4i*)w2frag;  // [(tap*2+half)*64 + lane]
#pragma unroll
  for (int tap = 0; tap < 9; ++tap) {
    v4i b0 = wf[(tap * 2 + 0) * 64 + lane];
    v4i b1 = wf[(tap * 2 + 1) * 64 + lane];
    acc0 = __builtin_amdgcn_mfma_i32_32x32x32_i8(a[tap], b0, acc0, 0, 0, 0);
    acc1 = __builtin_amdgcn_mfma_i32_32x32x32_i8(a[tap], b1, acc1, 0, 0, 0);
  }

  int mx = 0;
#pragma unroll
  for (int r = 0; r < 16; ++r) {
    int m = (r & 3) + 8 * (r >> 2) + 4 * lhalf;
    if (ow0 + m < 220) mx = max(mx, max(acc0[r], acc1[r]));
  }
  mx = block_maxi(max(mx, 0));
  if (!tid) atomicMax(max2, mx);
}

// conv2 pass B: recompute acc, quantize in-register, accumulate per-(b,oc)
// integer sums (pool fused). b is block-uniform (1540 waves per b, 4 per block).
__global__ void __launch_bounds__(256) k_conv2b(
    const unsigned char* __restrict__ y1n, const unsigned* __restrict__ w2frag,
    const int* __restrict__ bint2, const Scal* __restrict__ sc,
    int* __restrict__ pooled_i) {
  __shared__ int ls[64];
  int tid = threadIdx.x;
  if (tid < 64) ls[tid] = 0;
  int lane = tid & 63;
  int lane31 = lane & 31, lhalf = lane >> 5;
  int wv = blockIdx.x * 4 + (tid >> 6);
  int owg = wv % 7; int t = wv / 7;
  int oh = t % 220; int b = t / 220;
  int ow0 = owg * 32;

  size_t aoff = (size_t)lane31 * 32 + (size_t)lhalf * 16;
  const unsigned char* base0 = y1n + ((size_t)((b * 222 + oh) * 224 + ow0)) * 32 + aoff;
  v4i a[9];
#pragma unroll
  for (int kh = 0; kh < 3; ++kh)
#pragma unroll
    for (int kw = 0; kw < 3; ++kw)
      a[kh * 3 + kw] = *(const v4i*)(base0 + (size_t)kh * (224 * 32) + kw * 32);

  int bias0 = bint2[lane31];
  int bias1 = bint2[32 + lane31];
  v16i acc0, acc1;
#pragma unroll
  for (int r = 0; r < 16; ++r) { acc0[r] = bias0; acc1[r] = bias1; }

  const v4i* wf = (const v4i*)w2frag;
#pragma unroll
  for (int tap = 0; tap < 9; ++tap) {
    v4i b0 = wf[(tap * 2 + 0) * 64 + lane];
    v4i b1 = wf[(tap * 2 + 1) * 64 + lane];
    acc0 = __builtin_amdgcn_mfma_i32_32x32x32_i8(a[tap], b0, acc0, 0, 0, 0);
    acc1 = __builtin_amdgcn_mfma_i32_32x32x32_i8(a[tap], b1, acc1, 0, 0, 0);
  }

  __syncthreads();  // ls zero-init visible
  float h = (sc->s1 * sc->sw2) * (1.0f / sc->s2);
  int isum0 = 0, isum1 = 0;
#pragma unroll
  for (int r = 0; r < 16; ++r) {
    int m = (r & 3) + 8 * (r >> 2) + 4 * lhalf;
    if (ow0 + m < 220) {
      float q0 = fminf(fmaxf(rintf((float)acc0[r] * h), 0.f), 15.f);
      float q1 = fminf(fmaxf(rintf((float)acc1[r] * h), 0.f), 15.f);
      isum0 += (int)q0;
      isum1 += (int)q1;
    }
  }
  isum0 += __shfl_down(isum0, 32, 64);
  isum1 += __shfl_down(isum1, 32, 64);
  if (lhalf == 0) {
    atomicAdd(&ls[lane31], isum0);
    atomicAdd(&ls[32 + lane31], isum1);
  }
  __syncthreads();
  if (tid < 64) atomicAdd(&pooled_i[b * 64 + tid], ls[tid]);
}

__global__ void k_fin2(Scal* sc) {
  sc->s2 = fmaxf((float)sc->max2 * (sc->s1 * sc->sw2), 1e-8f) / 15.f;
}

// whole FC head + log_softmax in one block
__global__ void k_fc(const int* __restrict__ pooled_i, const float* __restrict__ wf1,
                     const float* __restrict__ bf1, const float* __restrict__ wf2,
                     const float* __restrict__ bf2, const Scal* __restrict__ sc,
                     float* __restrict__ out) {
  __shared__ float pl[2048];
  __shared__ float wq1[8192];
  __shared__ float y3[4096];
  __shared__ float zz[320];
  __shared__ float s3sh;
  int tid = threadIdx.x;
  float swf1 = sc->swf1, swf2 = sc->swf2, s2 = sc->s2;
  for (int i = tid; i < 2048; i += 256) pl[i] = (float)pooled_i[i] * s2 / 48400.0f;
  for (int i = tid; i < 8192; i += 256) {
    float q = rintf(wf1[i] / swf1);
    q = fminf(fmaxf(q, -8.f), 7.f);
    wq1[i] = q * swf1;
  }
  __syncthreads();
  float sb1 = s2 * swf1;
  float lmax = 0.f;
  for (int o = tid; o < 4096; o += 256) {
    int b = o >> 7, j = o & 127;
    float acc = rintf(bf1[j] / sb1) * sb1;
    const float* wrow = &wq1[j * 64];
    const float* xrow = &pl[b * 64];
#pragma unroll 16
    for (int k = 0; k < 64; ++k) acc += xrow[k] * wrow[k];
    float r = fmaxf(acc, 0.f);
    y3[o] = r;
    lmax = fmaxf(lmax, r);
  }
  float m = block_maxf(lmax);  // contains a __syncthreads (after y3 writes)
  if (!tid) s3sh = fmaxf(m, 1e-8f) / 15.f;
  __syncthreads();
  float s3 = s3sh;
  float sb2 = s3 * swf2;
  for (int o = tid; o < 320; o += 256) {
    int b = o / 10, j = o - b * 10;
    float acc = rintf(bf2[j] / sb2) * sb2;
    const float* yy = &y3[b * 128];
    const float* wrow = &wf2[j * 128];
    for (int k = 0; k < 128; ++k) {
      float q = rintf(yy[k] / s3);
      q = fminf(fmaxf(q, 0.f), 15.f);
      float wv = rintf(wrow[k] / swf2);
      wv = fminf(fmaxf(wv, -8.f), 7.f);
      acc += (q * s3) * (wv * swf2);
    }
    zz[o] = acc;
  }
  __syncthreads();
  if (tid < 32) {
    const float* z = &zz[tid * 10];
    float mm = z[0];
    for (int k = 1; k < 10; ++k) mm = fmaxf(mm, z[k]);
    float ssum = 0.f;
    for (int k = 0; k < 10; ++k) ssum += expf(z[k] - mm);
    float l = mm + logf(ssum);
    for (int k = 0; k < 10; ++k) out[tid * 10 + k] = z[k] - l;
  }
}

extern "C" void kernel_launch(void* const* d_in, const int* in_sizes, int n_in,
                              void* d_out, int out_size, void* d_ws, size_t ws_size,
                              hipStream_t stream) {
  const float* x   = (const float*)d_in[0];
  const float* w1  = (const float*)d_in[1];
  const float* b1  = (const float*)d_in[2];
  const float* w2  = (const float*)d_in[3];
  const float* b2  = (const float*)d_in[4];
  const float* wf1 = (const float*)d_in[5];
  const float* bf1 = (const float*)d_in[6];
  const float* wf2 = (const float*)d_in[7];
  const float* bf2 = (const float*)d_in[8];
  float* out = (float*)d_out;

  char* ws = (char*)d_ws;
  Scal* sc = (Scal*)ws;
  size_t off = 1024;
  signed char* xq = (signed char*)(ws + off);   off += (size_t)NX + 256;  // +slack
  off = (off + 255) & ~(size_t)255;
  unsigned* w1pk = (unsigned*)(ws + off);       off += 2048;              // [oc][row] {w0,w1,w2,0}
  unsigned* w2frag = (unsigned*)(ws + off);     off += 4608 * 4;          // MFMA B-frag layout
  int* bint1 = (int*)(ws + off);                off += 256;
  int* bint2 = (int*)(ws + off);                off += 256;
  unsigned char* y1n = (unsigned char*)(ws + off); off += (size_t)NP1;    // NHWC codes
  off = (off + 255) & ~(size_t)255;
  int* pooled_i = (int*)(ws + off);             off += 8192;              // also slack for conv2 tail reads
  off = (off + 255) & ~(size_t)255;
  short* y1acc = (short*)(ws + off);            off += (size_t)NP1 * 2;   // planar int16 conv1 acc
  (void)ws_size; (void)in_sizes; (void)n_in; (void)out_size;

  hipMemsetAsync(sc, 0, 1024, stream);
  hipMemsetAsync(pooled_i, 0, 8192, stream);
  k_absmax_x<<<1024, 256, 0, stream>>>((const float4*)x, NX / 4, &sc->max_x);
  k_absmax_w<<<4, 256, 0, stream>>>(w1, w2, wf1, wf2, sc);
  k_scales<<<1, 1, 0, stream>>>(sc);
  k_quant_x<<<NX / 4 / 256, 256, 0, stream>>>((const float4*)x, (unsigned*)xq, NX / 4, sc);
  k_quant_w<<<22, 256, 0, stream>>>(w1, w2, b1, sc, w1pk, w2frag, bint1);
  k_conv1<<<dim3(37, 32), 256, 0, stream>>>(xq, w1pk, bint1, y1acc, &sc->max1);
  k_fin1<<<1, 64, 0, stream>>>(sc, b2, bint2);
  k_requant_t<<<dim3(195, 32), 256, 0, stream>>>(y1acc, sc, y1n);
  k_conv2a<<<NW2 / 4, 256, 0, stream>>>(y1n, w2frag, bint2, &sc->max2);
  k_fin2<<<1, 1, 0, stream>>>(sc);
  k_conv2b<<<NW2 / 4, 256, 0, stream>>>(y1n, w2frag, bint2, sc, pooled_i);
  k_fc<<<1, 256, 0, stream>>>(pooled_i, wf1, bf1, wf2, bf2, sc, out);
}

// Round 11
// 403.668 us; speedup vs baseline: 1.2168x; 1.1876x over previous
//
#include <hip/hip_runtime.h>
#include <cstdint>
#include <cstddef>

#define DI __device__ __forceinline__

typedef int v4i  __attribute__((ext_vector_type(4)));
typedef int v16i __attribute__((ext_vector_type(16)));

#if defined(__has_builtin)
#if __has_builtin(__builtin_amdgcn_sdot4)
#define HAS_SDOT4 1
#endif
#if __has_builtin(__builtin_amdgcn_alignbyte)
#define HAS_ALIGNBYTE 1
#endif
#endif

DI int dot4(unsigned a, unsigned b, int c) {
#ifdef HAS_SDOT4
  return __builtin_amdgcn_sdot4((int)a, (int)b, c, false);
#else
#pragma unroll
  for (int k = 0; k < 4; ++k)
    c += (int)(signed char)(a >> (8 * k)) * (int)(signed char)(b >> (8 * k));
  return c;
#endif
}

DI unsigned alignb(unsigned hi, unsigned lo, int sh) {  // bytes (hi:lo) >> 8*sh
#ifdef HAS_ALIGNBYTE
  return __builtin_amdgcn_alignbyte(hi, lo, sh);
#else
  return (lo >> (8 * sh)) | (hi << (32 - 8 * sh));
#endif
}

// ---------------- scalar block in workspace ----------------
struct Scal {
  unsigned max_x, max_w1, max_w2, max_wf1, max_wf2;  // float bits (abs-max, >=0)
  float s_in, sw1, sw2, swf1, swf2;
  int   max1; float s1;
  int   max2; float s2;
};

static constexpr int NX   = 32 * 3 * 224 * 224;     // 4,816,896
static constexpr int NP1  = 32 * 32 * 222 * 224;    // 50,921,472 padded conv1 outputs
static constexpr int NPIX = 222 * 224;              // 49,728 padded pixels per image
static constexpr int NW2R = 32 * 110 * 7;           // conv2 waves: 32px x 2 rows x 64 oc
static constexpr int WPB2 = 770;                    // waves per batch image (110*7)

// ---------------- reduction helpers (blockDim == 256) ----------------
DI float wave_maxf(float v) { for (int o = 32; o; o >>= 1) v = fmaxf(v, __shfl_down(v, o, 64)); return v; }
DI int   wave_maxi(int v)   { for (int o = 32; o; o >>= 1) v = max(v, __shfl_down(v, o, 64));   return v; }

DI float block_maxf(float v) {  // valid in thread 0; all values >= 0
  __shared__ float s[4];
  v = wave_maxf(v);
  int lane = threadIdx.x & 63, w = threadIdx.x >> 6;
  if (!lane) s[w] = v;
  __syncthreads();
  if (threadIdx.x < 64) {
    float t = (threadIdx.x < 4) ? s[threadIdx.x] : 0.f;
    v = wave_maxf(t);
  }
  return v;
}

DI int block_maxi(int v) {  // valid in thread 0; all values >= 0
  __shared__ int s[4];
  v = wave_maxi(v);
  int lane = threadIdx.x & 63, w = threadIdx.x >> 6;
  if (!lane) s[w] = v;
  __syncthreads();
  if (threadIdx.x < 64) {
    int t = (threadIdx.x < 4) ? s[threadIdx.x] : 0;
    v = wave_maxi(t);
  }
  return v;
}

// ---------------- stage kernels ----------------
__global__ void k_absmax_x(const float4* __restrict__ x, int n4, unsigned* slot) {
  float m = 0.f;
  for (int i = blockIdx.x * blockDim.x + threadIdx.x; i < n4; i += gridDim.x * blockDim.x) {
    float4 v = x[i];
    m = fmaxf(m, fmaxf(fmaxf(fabsf(v.x), fabsf(v.y)), fmaxf(fabsf(v.z), fabsf(v.w))));
  }
  m = block_maxf(m);
  if (!threadIdx.x) atomicMax(slot, __float_as_uint(m));
}

__global__ void k_absmax_w(const float* __restrict__ w1, const float* __restrict__ w2,
                           const float* __restrict__ wf1, const float* __restrict__ wf2,
                           Scal* sc) {
  const float* p; int n; unsigned* slot;
  if (blockIdx.x == 0)      { p = w1;  n = 864;   slot = &sc->max_w1; }
  else if (blockIdx.x == 1) { p = w2;  n = 18432; slot = &sc->max_w2; }
  else if (blockIdx.x == 2) { p = wf1; n = 8192;  slot = &sc->max_wf1; }
  else                      { p = wf2; n = 1280;  slot = &sc->max_wf2; }
  float m = 0.f;
  for (int i = threadIdx.x; i < n; i += blockDim.x) m = fmaxf(m, fabsf(p[i]));
  m = block_maxf(m);
  if (!threadIdx.x) atomicMax(slot, __float_as_uint(m));
}

__global__ void k_scales(Scal* sc) {
  sc->s_in = fmaxf(__uint_as_float(sc->max_x),  1e-8f) / 7.f;
  sc->sw1  = fmaxf(__uint_as_float(sc->max_w1), 1e-8f) / 7.f;
  sc->sw2  = fmaxf(__uint_as_float(sc->max_w2), 1e-8f) / 7.f;
  sc->swf1 = fmaxf(__uint_as_float(sc->max_wf1),1e-8f) / 7.f;
  sc->swf2 = fmaxf(__uint_as_float(sc->max_wf2),1e-8f) / 7.f;
}

// 4 floats -> 4 packed int8 codes per thread
__global__ void k_quant_x(const float4* __restrict__ x, unsigned* __restrict__ xq,
                          int n4, const Scal* __restrict__ sc) {
  float s = sc->s_in;
  int i = blockIdx.x * 256 + threadIdx.x;
  if (i >= n4) return;
  float4 v = x[i];
  float f[4] = {v.x, v.y, v.z, v.w};
  unsigned w = 0;
#pragma unroll
  for (int k = 0; k < 4; ++k) {
    float q = rintf(f[k] / s);
    q = fminf(fmaxf(q, -8.f), 7.f);
    w |= ((unsigned)((int)q & 255)) << (8 * k);
  }
  xq[i] = w;
}

// pack w1 as [oc][row] dwords {w0,w1,w2,0}; w2 directly into the MFMA B-frag
// layout w2frag[((tap*2+half)*64 + dl)*4 + q]; bias1 ints
__global__ void k_quant_w(const float* __restrict__ w1, const float* __restrict__ w2,
                          const float* __restrict__ b1, const Scal* __restrict__ sc,
                          unsigned* __restrict__ w1pk, unsigned* __restrict__ w2frag,
                          int* __restrict__ bint1) {
  int i = blockIdx.x * blockDim.x + threadIdx.x;
  if (i < 288) {
    int oc = i / 9, r = i - oc * 9;   // r = ic*3 + kh; bytes = kw 0..2
    float s = sc->sw1;
    unsigned w = 0;
#pragma unroll
    for (int k = 0; k < 3; ++k) {
      float q = rintf(w1[oc * 27 + r * 3 + k] / s);
      q = fminf(fmaxf(q, -8.f), 7.f);
      w |= ((unsigned)((int)q & 255)) << (8 * k);
    }
    w1pk[i] = w;
  } else if (i < 288 + 4608) {
    int j = i - 288;
    int icq = j & 7; int t = j >> 3;
    int kw = t % 3; t /= 3;
    int kh = t % 3; int oc = t / 3;
    float s = sc->sw2;
    unsigned w = 0;
#pragma unroll
    for (int k = 0; k < 4; ++k) {
      int ic = icq * 4 + k;
      float q = rintf(w2[(oc * 32 + ic) * 9 + kh * 3 + kw] / s);
      q = fminf(fmaxf(q, -8.f), 7.f);
      w |= ((unsigned)((int)q & 255)) << (8 * k);
    }
    int tap = kh * 3 + kw;
    int dl = (oc & 31) | ((icq >> 2) << 5);
    w2frag[(((tap * 2) + (oc >> 5)) * 64 + dl) * 4 + (icq & 3)] = w;
  } else if (i < 288 + 4608 + 32) {
    int j = i - 4896;
    bint1[j] = (int)rintf(b1[j] / (sc->s_in * sc->sw1));
  }
}

// conv1 LDS-tiled: one block = (b, strip of 6 oh rows). Stage 3 ic x 8 input
// rows (5.3 KB) + weights + bias in LDS once; 256 threads sweep 28 g x 6 oh x
// 32 oc tasks (21 iters) with sdot4+alignbyte on LDS segments. Stores planar
// int16 acc; block max of relu(acc) over valid cols.
__global__ void __launch_bounds__(256) k_conv1(
    const signed char* __restrict__ xq, const unsigned* __restrict__ w1pk,
    const int* __restrict__ bint1, short* __restrict__ y1acc, int* __restrict__ max1) {
  __shared__ signed char lx[3 * 8 * 224 + 16];  // [ic][row 0..7][224] + pad
  __shared__ unsigned lw[288];
  __shared__ int lb[32];
  int tid = threadIdx.x;
  int strip = blockIdx.x;   // 0..36 (222 = 6*37)
  int b = blockIdx.y;       // 0..31
  int oh0 = strip * 6;

  for (int i = tid; i < 288; i += 256) lw[i] = w1pk[i];
  if (tid < 32) lb[tid] = bint1[tid];
  {
    const unsigned* src = (const unsigned*)(xq + (size_t)b * 3 * 224 * 224);
    unsigned* dst = (unsigned*)lx;
    // 24 rows x 56 dwords = 1344 dwords, coalesced
#pragma unroll
    for (int it = 0; it < 6; ++it) {
      int i = it * 256 + tid;
      if (i < 1344) {
        int row = i / 56, d = i - row * 56;   // row = ic*8 + r
        int ic = row >> 3, r = row & 7;
        dst[i] = src[(ic * 224 + (oh0 + r)) * 56 + d];
      }
    }
  }
  __syncthreads();

  int mx = 0;
  for (int it = 0; it < 21; ++it) {
    int i = it * 256 + tid;          // 5376 tasks: g fast, then oh_l, then oc
    int g = i % 28;
    int r = i / 28;
    int oh_l = r % 6;
    int oc = r / 6;

    int bias = lb[oc];
    int acc[8];
#pragma unroll
    for (int j = 0; j < 8; ++j) acc[j] = bias;

#pragma unroll
    for (int seg = 0; seg < 9; ++seg) {
      int ic = seg / 3, kh = seg - ic * 3;
      const signed char* base = lx + (ic * 8 + oh_l + kh) * 224 + g * 8;
      uint2 lo = *(const uint2*)base;            // 8B aligned
      unsigned d0 = lo.x, d1 = lo.y;
      unsigned d2 = *(const unsigned*)(base + 8);
      unsigned wr = lw[oc * 9 + ic * 3 + kh];
      acc[0] = dot4(d0, wr, acc[0]);
      acc[1] = dot4(alignb(d1, d0, 1), wr, acc[1]);
      acc[2] = dot4(alignb(d1, d0, 2), wr, acc[2]);
      acc[3] = dot4(alignb(d1, d0, 3), wr, acc[3]);
      acc[4] = dot4(d1, wr, acc[4]);
      acc[5] = dot4(alignb(d2, d1, 1), wr, acc[5]);
      acc[6] = dot4(alignb(d2, d1, 2), wr, acc[6]);
      acc[7] = dot4(alignb(d2, d1, 3), wr, acc[7]);
    }

    size_t off = ((size_t)((b * 32 + oc) * 222 + oh0 + oh_l)) * 224 + g * 8;
    uint4 st;
    st.x = ((unsigned)(unsigned short)acc[0]) | ((unsigned)(unsigned short)acc[1] << 16);
    st.y = ((unsigned)(unsigned short)acc[2]) | ((unsigned)(unsigned short)acc[3] << 16);
    st.z = ((unsigned)(unsigned short)acc[4]) | ((unsigned)(unsigned short)acc[5] << 16);
    st.w = ((unsigned)(unsigned short)acc[6]) | ((unsigned)(unsigned short)acc[7] << 16);
    *(uint4*)(y1acc + off) = st;

#pragma unroll
    for (int j = 0; j < 8; ++j) if (g * 8 + j < 222) mx = max(mx, acc[j]);
  }
  mx = block_maxi(max(mx, 0));
  if (!tid) atomicMax(max1, mx);
}

__global__ void k_fin1(Scal* sc, const float* __restrict__ b2, int* __restrict__ bint2) {
  float sc1 = sc->s_in * sc->sw1;
  float s1 = fmaxf((float)sc->max1 * sc1, 1e-8f) / 15.f;
  if (!threadIdx.x) sc->s1 = s1;
  float sb = s1 * sc->sw2;
  bint2[threadIdx.x] = (int)rintf(b2[threadIdx.x] / sb);
}

// int16 planar acc -> NHWC uint8 relu4 codes (32 ic bytes contiguous per pixel)
__global__ void k_requant_t(const short* __restrict__ y1acc, const Scal* __restrict__ sc,
                            unsigned char* __restrict__ y1n) {
  int p = blockIdx.x * 256 + threadIdx.x;  // pixel within image (padded space)
  int b = blockIdx.y;
  if (p >= NPIX) return;
  float sc1 = sc->s_in * sc->sw1, s1 = sc->s1;
  const short* base = y1acc + (size_t)b * 32 * NPIX + p;
  unsigned w[8] = {0, 0, 0, 0, 0, 0, 0, 0};
#pragma unroll
  for (int oc = 0; oc < 32; ++oc) {
    int a = (int)base[(size_t)oc * NPIX];
    float y = (float)a * sc1;
    float q = rintf(y / s1);
    q = fminf(fmaxf(q, 0.f), 15.f);
    w[oc >> 2] |= ((unsigned)(int)q) << (8 * (oc & 3));
  }
  uint4* dst = (uint4*)(y1n + ((size_t)b * NPIX + p) * 32);
  dst[0] = make_uint4(w[0], w[1], w[2], w[3]);
  dst[1] = make_uint4(w[4], w[5], w[6], w[7]);
}

// conv2 pass A: MFMA i8 implicit GEMM, 2 output rows per wave (36 MFMA/wave),
// B-frags staged once per block via trivial linear LDS copy (conflict-free),
// A-frags (12) hoisted. max(relu(acc)) only, no stores.
__global__ void __launch_bounds__(256) k_conv2a(
    const unsigned char* __restrict__ y1n, const unsigned* __restrict__ w2frag,
    const int* __restrict__ bint2, int* __restrict__ max2) {
  __shared__ unsigned lw[4608];
  int tid = threadIdx.x;
  for (int i = tid; i < 4608; i += 256) lw[i] = w2frag[i];
  __syncthreads();

  int lane = tid & 63;
  int lane31 = lane & 31, lhalf = lane >> 5;
  int wv = blockIdx.x * 4 + (tid >> 6);
  int owg = wv % 7; int t = wv / 7;
  int ohg = t % 110; int b = t / 110;
  int oh0 = ohg * 2, ow0 = owg * 32;

  size_t aoff = (size_t)lane31 * 32 + (size_t)lhalf * 16;
  const unsigned char* base0 = y1n + ((size_t)((b * 222 + oh0) * 224 + ow0)) * 32 + aoff;
  v4i a[4][3];
#pragma unroll
  for (int i = 0; i < 4; ++i)
#pragma unroll
    for (int kw = 0; kw < 3; ++kw)
      a[i][kw] = *(const v4i*)(base0 + (size_t)i * (224 * 32) + kw * 32);

  int bias0 = bint2[lane31], bias1 = bint2[32 + lane31];
  v16i acc00, acc01, acc10, acc11;
#pragma unroll
  for (int r = 0; r < 16; ++r) {
    acc00[r] = bias0; acc01[r] = bias1;
    acc10[r] = bias0; acc11[r] = bias1;
  }

#pragma unroll
  for (int kh = 0; kh < 3; ++kh)
#pragma unroll
    for (int kw = 0; kw < 3; ++kw) {
      int tap = kh * 3 + kw;
      v4i b0 = *(const v4i*)(lw + (tap * 2 + 0) * 256 + lane * 4);
      v4i b1 = *(const v4i*)(lw + (tap * 2 + 1) * 256 + lane * 4);
      acc00 = __builtin_amdgcn_mfma_i32_32x32x32_i8(a[kh][kw], b0, acc00, 0, 0, 0);
      acc01 = __builtin_amdgcn_mfma_i32_32x32x32_i8(a[kh][kw], b1, acc01, 0, 0, 0);
      acc10 = __builtin_amdgcn_mfma_i32_32x32x32_i8(a[kh + 1][kw], b0, acc10, 0, 0, 0);
      acc11 = __builtin_amdgcn_mfma_i32_32x32x32_i8(a[kh + 1][kw], b1, acc11, 0, 0, 0);
    }

  int mx = 0;
#pragma unroll
  for (int r = 0; r < 16; ++r) {
    int m = (r & 3) + 8 * (r >> 2) + 4 * lhalf;
    if (ow0 + m < 220) {
      mx = max(mx, max(acc00[r], acc01[r]));
      mx = max(mx, max(acc10[r], acc11[r]));
    }
  }
  mx = block_maxi(max(mx, 0));
  if (!tid) atomicMax(max2, mx);
}

// conv2 pass B: recompute acc (2 rows/wave), quantize in-register, accumulate
// per-(b,oc) integer sums (pool fused). Blocks may straddle two batch images:
// 2-slot LDS accumulator keyed by b - b_first.
__global__ void __launch_bounds__(256) k_conv2b(
    const unsigned char* __restrict__ y1n, const unsigned* __restrict__ w2frag,
    const int* __restrict__ bint2, const Scal* __restrict__ sc,
    int* __restrict__ pooled_i) {
  __shared__ unsigned lw[4608];
  __shared__ int ls[128];
  int tid = threadIdx.x;
  for (int i = tid; i < 4608; i += 256) lw[i] = w2frag[i];
  if (tid < 128) ls[tid] = 0;
  __syncthreads();

  int lane = tid & 63;
  int lane31 = lane & 31, lhalf = lane >> 5;
  int wv = blockIdx.x * 4 + (tid >> 6);
  int owg = wv % 7; int t = wv / 7;
  int ohg = t % 110; int b = t / 110;
  int oh0 = ohg * 2, ow0 = owg * 32;
  int b_first = (blockIdx.x * 4) / WPB2;
  int slot = b - b_first;  // 0 or 1

  size_t aoff = (size_t)lane31 * 32 + (size_t)lhalf * 16;
  const unsigned char* base0 = y1n + ((size_t)((b * 222 + oh0) * 224 + ow0)) * 32 + aoff;
  v4i a[4][3];
#pragma unroll
  for (int i = 0; i < 4; ++i)
#pragma unroll
    for (int kw = 0; kw < 3; ++kw)
      a[i][kw] = *(const v4i*)(base0 + (size_t)i * (224 * 32) + kw * 32);

  int bias0 = bint2[lane31], bias1 = bint2[32 + lane31];
  v16i acc00, acc01, acc10, acc11;
#pragma unroll
  for (int r = 0; r < 16; ++r) {
    acc00[r] = bias0; acc01[r] = bias1;
    acc10[r] = bias0; acc11[r] = bias1;
  }

#pragma unroll
  for (int kh = 0; kh < 3; ++kh)
#pragma unroll
    for (int kw = 0; kw < 3; ++kw) {
      int tap = kh * 3 + kw;
      v4i b0 = *(const v4i*)(lw + (tap * 2 + 0) * 256 + lane * 4);
      v4i b1 = *(const v4i*)(lw + (tap * 2 + 1) * 256 + lane * 4);
      acc00 = __builtin_amdgcn_mfma_i32_32x32x32_i8(a[kh][kw], b0, acc00, 0, 0, 0);
      acc01 = __builtin_amdgcn_mfma_i32_32x32x32_i8(a[kh][kw], b1, acc01, 0, 0, 0);
      acc10 = __builtin_amdgcn_mfma_i32_32x32x32_i8(a[kh + 1][kw], b0, acc10, 0, 0, 0);
      acc11 = __builtin_amdgcn_mfma_i32_32x32x32_i8(a[kh + 1][kw], b1, acc11, 0, 0, 0);
    }

  float h = (sc->s1 * sc->sw2) * (1.0f / sc->s2);
  int isum0 = 0, isum1 = 0;
#pragma unroll
  for (int r = 0; r < 16; ++r) {
    int m = (r & 3) + 8 * (r >> 2) + 4 * lhalf;
    if (ow0 + m < 220) {
      isum0 += (int)fminf(fmaxf(rintf((float)acc00[r] * h), 0.f), 15.f);
      isum1 += (int)fminf(fmaxf(rintf((float)acc01[r] * h), 0.f), 15.f);
      isum0 += (int)fminf(fmaxf(rintf((float)acc10[r] * h), 0.f), 15.f);
      isum1 += (int)fminf(fmaxf(rintf((float)acc11[r] * h), 0.f), 15.f);
    }
  }
  isum0 += __shfl_down(isum0, 32, 64);
  isum1 += __shfl_down(isum1, 32, 64);
  if (lhalf == 0) {
    atomicAdd(&ls[slot * 64 + lane31], isum0);
    atomicAdd(&ls[slot * 64 + 32 + lane31], isum1);
  }
  __syncthreads();
  if (tid < 128) {
    int bb = b_first + (tid >> 6);
    if (bb < 32 && ls[tid] != 0)
      atomicAdd(&pooled_i[bb * 64 + (tid & 63)], ls[tid]);
  }
}

__global__ void k_fin2(Scal* sc) {
  sc->s2 = fmaxf((float)sc->max2 * (sc->s1 * sc->sw2), 1e-8f) / 15.f;
}

// whole FC head + log_softmax in one block
__global__ void k_fc(const int* __restrict__ pooled_i, const float* __restrict__ wf1,
                     const float* __restrict__ bf1, const float* __restrict__ wf2,
                     const float* __restrict__ bf2, const Scal* __restrict__ sc,
                     float* __restrict__ out) {
  __shared__ float pl[2048];
  __shared__ float wq1[8192];
  __shared__ float y3[4096];
  __shared__ float zz[320];
  __shared__ float s3sh;
  int tid = threadIdx.x;
  float swf1 = sc->swf1, swf2 = sc->swf2, s2 = sc->s2;
  for (int i = tid; i < 2048; i += 256) pl[i] = (float)pooled_i[i] * s2 / 48400.0f;
  for (int i = tid; i < 8192; i += 256) {
    float q = rintf(wf1[i] / swf1);
    q = fminf(fmaxf(q, -8.f), 7.f);
    wq1[i] = q * swf1;
  }
  __syncthreads();
  float sb1 = s2 * swf1;
  float lmax = 0.f;
  for (int o = tid; o < 4096; o += 256) {
    int b = o >> 7, j = o & 127;
    float acc = rintf(bf1[j] / sb1) * sb1;
    const float* wrow = &wq1[j * 64];
    const float* xrow = &pl[b * 64];
#pragma unroll 16
    for (int k = 0; k < 64; ++k) acc += xrow[k] * wrow[k];
    float r = fmaxf(acc, 0.f);
    y3[o] = r;
    lmax = fmaxf(lmax, r);
  }
  float m = block_maxf(lmax);  // contains a __syncthreads (after y3 writes)
  if (!tid) s3sh = fmaxf(m, 1e-8f) / 15.f;
  __syncthreads();
  float s3 = s3sh;
  float sb2 = s3 * swf2;
  for (int o = tid; o < 320; o += 256) {
    int b = o / 10, j = o - b * 10;
    float acc = rintf(bf2[j] / sb2) * sb2;
    const float* yy = &y3[b * 128];
    const float* wrow = &wf2[j * 128];
    for (int k = 0; k < 128; ++k) {
      float q = rintf(yy[k] / s3);
      q = fminf(fmaxf(q, 0.f), 15.f);
      float wv = rintf(wrow[k] / swf2);
      wv = fminf(fmaxf(wv, -8.f), 7.f);
      acc += (q * s3) * (wv * swf2);
    }
    zz[o] = acc;
  }
  __syncthreads();
  if (tid < 32) {
    const float* z = &zz[tid * 10];
    float mm = z[0];
    for (int k = 1; k < 10; ++k) mm = fmaxf(mm, z[k]);
    float ssum = 0.f;
    for (int k = 0; k < 10; ++k) ssum += expf(z[k] - mm);
    float l = mm + logf(ssum);
    for (int k = 0; k < 10; ++k) out[tid * 10 + k] = z[k] - l;
  }
}

extern "C" void kernel_launch(void* const* d_in, const int* in_sizes, int n_in,
                              void* d_out, int out_size, void* d_ws, size_t ws_size,
                              hipStream_t stream) {
  const float* x   = (const float*)d_in[0];
  const float* w1  = (const float*)d_in[1];
  const float* b1  = (const float*)d_in[2];
  const float* w2  = (const float*)d_in[3];
  const float* b2  = (const float*)d_in[4];
  const float* wf1 = (const float*)d_in[5];
  const float* bf1 = (const float*)d_in[6];
  const float* wf2 = (const float*)d_in[7];
  const float* bf2 = (const float*)d_in[8];
  float* out = (float*)d_out;

  char* ws = (char*)d_ws;
  Scal* sc = (Scal*)ws;
  size_t off = 1024;
  signed char* xq = (signed char*)(ws + off);   off += (size_t)NX + 256;  // +slack
  off = (off + 255) & ~(size_t)255;
  unsigned* w1pk = (unsigned*)(ws + off);       off += 2048;              // [oc][row] {w0,w1,w2,0}
  unsigned* w2frag = (unsigned*)(ws + off);     off += 4608 * 4;          // MFMA B-frag layout
  int* bint1 = (int*)(ws + off);                off += 256;
  int* bint2 = (int*)(ws + off);                off += 256;
  unsigned char* y1n = (unsigned char*)(ws + off); off += (size_t)NP1;    // NHWC codes
  off = (off + 255) & ~(size_t)255;
  int* pooled_i = (int*)(ws + off);             off += 8192;              // also slack for conv2 tail reads
  off = (off + 255) & ~(size_t)255;
  short* y1acc = (short*)(ws + off);            off += (size_t)NP1 * 2;   // planar int16 conv1 acc
  (void)ws_size; (void)in_sizes; (void)n_in; (void)out_size;

  hipMemsetAsync(sc, 0, 1024, stream);
  hipMemsetAsync(pooled_i, 0, 8192, stream);
  k_absmax_x<<<1024, 256, 0, stream>>>((const float4*)x, NX / 4, &sc->max_x);
  k_absmax_w<<<4, 256, 0, stream>>>(w1, w2, wf1, wf2, sc);
  k_scales<<<1, 1, 0, stream>>>(sc);
  k_quant_x<<<NX / 4 / 256, 256, 0, stream>>>((const float4*)x, (unsigned*)xq, NX / 4, sc);
  k_quant_w<<<22, 256, 0, stream>>>(w1, w2, b1, sc, w1pk, w2frag, bint1);
  k_conv1<<<dim3(37, 32), 256, 0, stream>>>(xq, w1pk, bint1, y1acc, &sc->max1);
  k_fin1<<<1, 64, 0, stream>>>(sc, b2, bint2);
  k_requant_t<<<dim3(195, 32), 256, 0, stream>>>(y1acc, sc, y1n);
  k_conv2a<<<NW2R / 4, 256, 0, stream>>>(y1n, w2frag, bint2, &sc->max2);
  k_fin2<<<1, 1, 0, stream>>>(sc);
  k_conv2b<<<NW2R / 4, 256, 0, stream>>>(y1n, w2frag, bint2, sc, pooled_i);
  k_fc<<<1, 256, 0, stream>>>(pooled_i, wf1, bf1, wf2, bf2, sc, out);
}

// Round 12
// 372.762 us; speedup vs baseline: 1.3177x; 1.0829x over previous
//
#include <hip/hip_runtime.h>
#include <cstdint>
#include <cstddef>

#define DI __device__ __forceinline__

typedef int v4i  __attribute__((ext_vector_type(4)));
typedef int v16i __attribute__((ext_vector_type(16)));

#if defined(__has_builtin)
#if __has_builtin(__builtin_amdgcn_sdot4)
#define HAS_SDOT4 1
#endif
#if __has_builtin(__builtin_amdgcn_alignbyte)
#define HAS_ALIGNBYTE 1
#endif
#endif

DI int dot4(unsigned a, unsigned b, int c) {
#ifdef HAS_SDOT4
  return __builtin_amdgcn_sdot4((int)a, (int)b, c, false);
#else
#pragma unroll
  for (int k = 0; k < 4; ++k)
    c += (int)(signed char)(a >> (8 * k)) * (int)(signed char)(b >> (8 * k));
  return c;
#endif
}

DI unsigned alignb(unsigned hi, unsigned lo, int sh) {  // bytes (hi:lo) >> 8*sh
#ifdef HAS_ALIGNBYTE
  return __builtin_amdgcn_alignbyte(hi, lo, sh);
#else
  return (lo >> (8 * sh)) | (hi << (32 - 8 * sh));
#endif
}

// ---------------- scalar block in workspace ----------------
struct Scal {
  unsigned max_x, max_w1, max_w2, max_wf1, max_wf2;  // float bits (abs-max, >=0)
  float s_in, sw1, sw2, swf1, swf2;
  int   max1; float s1;
  int   max2; float s2;
};

static constexpr int NX   = 32 * 3 * 224 * 224;     // 4,816,896
static constexpr int NP1  = 32 * 32 * 222 * 224;    // 50,921,472 padded conv1 outputs
static constexpr int NPIX = 222 * 224;              // 49,728 padded pixels per image
static constexpr int NBLK2 = 616;                   // persistent conv2 blocks
static constexpr int ITER2 = 10;                    // tiles per wave (6160 tile-blocks total)

// ---------------- reduction helpers (blockDim == 256) ----------------
DI float wave_maxf(float v) { for (int o = 32; o; o >>= 1) v = fmaxf(v, __shfl_down(v, o, 64)); return v; }
DI int   wave_maxi(int v)   { for (int o = 32; o; o >>= 1) v = max(v, __shfl_down(v, o, 64));   return v; }

DI float block_maxf(float v) {  // valid in thread 0; all values >= 0
  __shared__ float s[4];
  v = wave_maxf(v);
  int lane = threadIdx.x & 63, w = threadIdx.x >> 6;
  if (!lane) s[w] = v;
  __syncthreads();
  if (threadIdx.x < 64) {
    float t = (threadIdx.x < 4) ? s[threadIdx.x] : 0.f;
    v = wave_maxf(t);
  }
  return v;
}

DI int block_maxi(int v) {  // valid in thread 0; all values >= 0
  __shared__ int s[4];
  v = wave_maxi(v);
  int lane = threadIdx.x & 63, w = threadIdx.x >> 6;
  if (!lane) s[w] = v;
  __syncthreads();
  if (threadIdx.x < 64) {
    int t = (threadIdx.x < 4) ? s[threadIdx.x] : 0;
    v = wave_maxi(t);
  }
  return v;
}

// ---------------- stage kernels ----------------
__global__ void k_absmax_x(const float4* __restrict__ x, int n4, unsigned* slot) {
  float m = 0.f;
  for (int i = blockIdx.x * blockDim.x + threadIdx.x; i < n4; i += gridDim.x * blockDim.x) {
    float4 v = x[i];
    m = fmaxf(m, fmaxf(fmaxf(fabsf(v.x), fabsf(v.y)), fmaxf(fabsf(v.z), fabsf(v.w))));
  }
  m = block_maxf(m);
  if (!threadIdx.x) atomicMax(slot, __float_as_uint(m));
}

__global__ void k_absmax_w(const float* __restrict__ w1, const float* __restrict__ w2,
                           const float* __restrict__ wf1, const float* __restrict__ wf2,
                           Scal* sc) {
  const float* p; int n; unsigned* slot;
  if (blockIdx.x == 0)      { p = w1;  n = 864;   slot = &sc->max_w1; }
  else if (blockIdx.x == 1) { p = w2;  n = 18432; slot = &sc->max_w2; }
  else if (blockIdx.x == 2) { p = wf1; n = 8192;  slot = &sc->max_wf1; }
  else                      { p = wf2; n = 1280;  slot = &sc->max_wf2; }
  float m = 0.f;
  for (int i = threadIdx.x; i < n; i += blockDim.x) m = fmaxf(m, fabsf(p[i]));
  m = block_maxf(m);
  if (!threadIdx.x) atomicMax(slot, __float_as_uint(m));
}

__global__ void k_scales(Scal* sc) {
  sc->s_in = fmaxf(__uint_as_float(sc->max_x),  1e-8f) / 7.f;
  sc->sw1  = fmaxf(__uint_as_float(sc->max_w1), 1e-8f) / 7.f;
  sc->sw2  = fmaxf(__uint_as_float(sc->max_w2), 1e-8f) / 7.f;
  sc->swf1 = fmaxf(__uint_as_float(sc->max_wf1),1e-8f) / 7.f;
  sc->swf2 = fmaxf(__uint_as_float(sc->max_wf2),1e-8f) / 7.f;
}

// 4 floats -> 4 packed int8 codes per thread
__global__ void k_quant_x(const float4* __restrict__ x, unsigned* __restrict__ xq,
                          int n4, const Scal* __restrict__ sc) {
  float s = sc->s_in;
  int i = blockIdx.x * 256 + threadIdx.x;
  if (i >= n4) return;
  float4 v = x[i];
  float f[4] = {v.x, v.y, v.z, v.w};
  unsigned w = 0;
#pragma unroll
  for (int k = 0; k < 4; ++k) {
    float q = rintf(f[k] / s);
    q = fminf(fmaxf(q, -8.f), 7.f);
    w |= ((unsigned)((int)q & 255)) << (8 * k);
  }
  xq[i] = w;
}

// pack w1 as [oc][row] dwords {w0,w1,w2,0}; w2 directly into the MFMA B-frag
// layout w2frag[((tap*2+half)*64 + dl)*4 + q]; bias1 ints
__global__ void k_quant_w(const float* __restrict__ w1, const float* __restrict__ w2,
                          const float* __restrict__ b1, const Scal* __restrict__ sc,
                          unsigned* __restrict__ w1pk, unsigned* __restrict__ w2frag,
                          int* __restrict__ bint1) {
  int i = blockIdx.x * blockDim.x + threadIdx.x;
  if (i < 288) {
    int oc = i / 9, r = i - oc * 9;   // r = ic*3 + kh; bytes = kw 0..2
    float s = sc->sw1;
    unsigned w = 0;
#pragma unroll
    for (int k = 0; k < 3; ++k) {
      float q = rintf(w1[oc * 27 + r * 3 + k] / s);
      q = fminf(fmaxf(q, -8.f), 7.f);
      w |= ((unsigned)((int)q & 255)) << (8 * k);
    }
    w1pk[i] = w;
  } else if (i < 288 + 4608) {
    int j = i - 288;
    int icq = j & 7; int t = j >> 3;
    int kw = t % 3; t /= 3;
    int kh = t % 3; int oc = t / 3;
    float s = sc->sw2;
    unsigned w = 0;
#pragma unroll
    for (int k = 0; k < 4; ++k) {
      int ic = icq * 4 + k;
      float q = rintf(w2[(oc * 32 + ic) * 9 + kh * 3 + kw] / s);
      q = fminf(fmaxf(q, -8.f), 7.f);
      w |= ((unsigned)((int)q & 255)) << (8 * k);
    }
    int tap = kh * 3 + kw;
    int dl = (oc & 31) | ((icq >> 2) << 5);
    w2frag[(((tap * 2) + (oc >> 5)) * 64 + dl) * 4 + (icq & 3)] = w;
  } else if (i < 288 + 4608 + 32) {
    int j = i - 4896;
    bint1[j] = (int)rintf(b1[j] / (sc->s_in * sc->sw1));
  }
}

// conv1 LDS-tiled: one block = (b, strip of 6 oh rows). Stage 3 ic x 8 input
// rows (5.3 KB) + weights + bias in LDS once; 256 threads sweep 28 g x 6 oh x
// 32 oc tasks (21 iters) with sdot4+alignbyte on LDS segments. Stores planar
// int16 acc; block max of relu(acc) over valid cols.
__global__ void __launch_bounds__(256) k_conv1(
    const signed char* __restrict__ xq, const unsigned* __restrict__ w1pk,
    const int* __restrict__ bint1, short* __restrict__ y1acc, int* __restrict__ max1) {
  __shared__ signed char lx[3 * 8 * 224 + 16];  // [ic][row 0..7][224] + pad
  __shared__ unsigned lw[288];
  __shared__ int lb[32];
  int tid = threadIdx.x;
  int strip = blockIdx.x;   // 0..36 (222 = 6*37)
  int b = blockIdx.y;       // 0..31
  int oh0 = strip * 6;

  for (int i = tid; i < 288; i += 256) lw[i] = w1pk[i];
  if (tid < 32) lb[tid] = bint1[tid];
  {
    const unsigned* src = (const unsigned*)(xq + (size_t)b * 3 * 224 * 224);
    unsigned* dst = (unsigned*)lx;
    // 24 rows x 56 dwords = 1344 dwords, coalesced
#pragma unroll
    for (int it = 0; it < 6; ++it) {
      int i = it * 256 + tid;
      if (i < 1344) {
        int row = i / 56, d = i - row * 56;   // row = ic*8 + r
        int ic = row >> 3, r = row & 7;
        dst[i] = src[(ic * 224 + (oh0 + r)) * 56 + d];
      }
    }
  }
  __syncthreads();

  int mx = 0;
  for (int it = 0; it < 21; ++it) {
    int i = it * 256 + tid;          // 5376 tasks: g fast, then oh_l, then oc
    int g = i % 28;
    int r = i / 28;
    int oh_l = r % 6;
    int oc = r / 6;

    int bias = lb[oc];
    int acc[8];
#pragma unroll
    for (int j = 0; j < 8; ++j) acc[j] = bias;

#pragma unroll
    for (int seg = 0; seg < 9; ++seg) {
      int ic = seg / 3, kh = seg - ic * 3;
      const signed char* base = lx + (ic * 8 + oh_l + kh) * 224 + g * 8;
      uint2 lo = *(const uint2*)base;            // 8B aligned
      unsigned d0 = lo.x, d1 = lo.y;
      unsigned d2 = *(const unsigned*)(base + 8);
      unsigned wr = lw[oc * 9 + ic * 3 + kh];
      acc[0] = dot4(d0, wr, acc[0]);
      acc[1] = dot4(alignb(d1, d0, 1), wr, acc[1]);
      acc[2] = dot4(alignb(d1, d0, 2), wr, acc[2]);
      acc[3] = dot4(alignb(d1, d0, 3), wr, acc[3]);
      acc[4] = dot4(d1, wr, acc[4]);
      acc[5] = dot4(alignb(d2, d1, 1), wr, acc[5]);
      acc[6] = dot4(alignb(d2, d1, 2), wr, acc[6]);
      acc[7] = dot4(alignb(d2, d1, 3), wr, acc[7]);
    }

    size_t off = ((size_t)((b * 32 + oc) * 222 + oh0 + oh_l)) * 224 + g * 8;
    uint4 st;
    st.x = ((unsigned)(unsigned short)acc[0]) | ((unsigned)(unsigned short)acc[1] << 16);
    st.y = ((unsigned)(unsigned short)acc[2]) | ((unsigned)(unsigned short)acc[3] << 16);
    st.z = ((unsigned)(unsigned short)acc[4]) | ((unsigned)(unsigned short)acc[5] << 16);
    st.w = ((unsigned)(unsigned short)acc[6]) | ((unsigned)(unsigned short)acc[7] << 16);
    *(uint4*)(y1acc + off) = st;

#pragma unroll
    for (int j = 0; j < 8; ++j) if (g * 8 + j < 222) mx = max(mx, acc[j]);
  }
  mx = block_maxi(max(mx, 0));
  if (!tid) atomicMax(max1, mx);
}

__global__ void k_fin1(Scal* sc, const float* __restrict__ b2, int* __restrict__ bint2) {
  float sc1 = sc->s_in * sc->sw1;
  float s1 = fmaxf((float)sc->max1 * sc1, 1e-8f) / 15.f;
  if (!threadIdx.x) sc->s1 = s1;
  float sb = s1 * sc->sw2;
  bint2[threadIdx.x] = (int)rintf(b2[threadIdx.x] / sb);
}

// int16 planar acc -> NHWC uint8 relu4 codes (32 ic bytes contiguous per pixel)
__global__ void k_requant_t(const short* __restrict__ y1acc, const Scal* __restrict__ sc,
                            unsigned char* __restrict__ y1n) {
  int p = blockIdx.x * 256 + threadIdx.x;  // pixel within image (padded space)
  int b = blockIdx.y;
  if (p >= NPIX) return;
  float sc1 = sc->s_in * sc->sw1, s1 = sc->s1;
  const short* base = y1acc + (size_t)b * 32 * NPIX + p;
  unsigned w[8] = {0, 0, 0, 0, 0, 0, 0, 0};
#pragma unroll
  for (int oc = 0; oc < 32; ++oc) {
    int a = (int)base[(size_t)oc * NPIX];
    float y = (float)a * sc1;
    float q = rintf(y / s1);
    q = fminf(fmaxf(q, 0.f), 15.f);
    w[oc >> 2] |= ((unsigned)(int)q) << (8 * (oc & 3));
  }
  uint4* dst = (uint4*)(y1n + ((size_t)b * NPIX + p) * 32);
  dst[0] = make_uint4(w[0], w[1], w[2], w[3]);
  dst[1] = make_uint4(w[4], w[5], w[6], w[7]);
}

// conv2 pass A (persistent): 616 blocks, each wave grid-strides 10 tiles
// (tile = 32px x 2 rows x 64oc, 36 MFMA). Weights staged once; no barriers in
// the loop; per-thread running max; one block reduce at the end.
__global__ void __launch_bounds__(256) k_conv2a(
    const unsigned char* __restrict__ y1n, const unsigned* __restrict__ w2frag,
    const int* __restrict__ bint2, int* __restrict__ max2) {
  __shared__ unsigned lw[4608];
  int tid = threadIdx.x;
  for (int i = tid; i < 4608; i += 256) lw[i] = w2frag[i];
  __syncthreads();

  int lane = tid & 63;
  int lane31 = lane & 31, lhalf = lane >> 5;
  int bias0 = bint2[lane31], bias1 = bint2[32 + lane31];
  size_t aoff = (size_t)lane31 * 32 + (size_t)lhalf * 16;
  int mx = 0;

  for (int it = 0; it < ITER2; ++it) {
    int tb = blockIdx.x + it * NBLK2;
    int wv = tb * 4 + (tid >> 6);
    int owg = wv % 7; int t = wv / 7;
    int ohg = t % 110; int b = t / 110;
    int oh0 = ohg * 2, ow0 = owg * 32;

    const unsigned char* base0 = y1n + ((size_t)((b * 222 + oh0) * 224 + ow0)) * 32 + aoff;
    v4i a[4][3];
#pragma unroll
    for (int i = 0; i < 4; ++i)
#pragma unroll
      for (int kw = 0; kw < 3; ++kw)
        a[i][kw] = *(const v4i*)(base0 + (size_t)i * (224 * 32) + kw * 32);

    v16i acc00, acc01, acc10, acc11;
#pragma unroll
    for (int r = 0; r < 16; ++r) {
      acc00[r] = bias0; acc01[r] = bias1;
      acc10[r] = bias0; acc11[r] = bias1;
    }

#pragma unroll
    for (int kh = 0; kh < 3; ++kh)
#pragma unroll
      for (int kw = 0; kw < 3; ++kw) {
        int tap = kh * 3 + kw;
        v4i b0 = *(const v4i*)(lw + (tap * 2 + 0) * 256 + lane * 4);
        v4i b1 = *(const v4i*)(lw + (tap * 2 + 1) * 256 + lane * 4);
        acc00 = __builtin_amdgcn_mfma_i32_32x32x32_i8(a[kh][kw], b0, acc00, 0, 0, 0);
        acc01 = __builtin_amdgcn_mfma_i32_32x32x32_i8(a[kh][kw], b1, acc01, 0, 0, 0);
        acc10 = __builtin_amdgcn_mfma_i32_32x32x32_i8(a[kh + 1][kw], b0, acc10, 0, 0, 0);
        acc11 = __builtin_amdgcn_mfma_i32_32x32x32_i8(a[kh + 1][kw], b1, acc11, 0, 0, 0);
      }

#pragma unroll
    for (int r = 0; r < 16; ++r) {
      int m = (r & 3) + 8 * (r >> 2) + 4 * lhalf;
      if (ow0 + m < 220) {
        mx = max(mx, max(acc00[r], acc01[r]));
        mx = max(mx, max(acc10[r], acc11[r]));
      }
    }
  }
  mx = block_maxi(max(mx, 0));
  if (!tid) atomicMax(max2, mx);
}

// conv2 pass B (persistent): recompute acc per tile, quantize in-register,
// pool-accumulate into block-local ls[2048] (b*64+oc), flush once at end.
__global__ void __launch_bounds__(256) k_conv2b(
    const unsigned char* __restrict__ y1n, const unsigned* __restrict__ w2frag,
    const int* __restrict__ bint2, const Scal* __restrict__ sc,
    int* __restrict__ pooled_i) {
  __shared__ unsigned lw[4608];
  __shared__ int ls[2048];
  int tid = threadIdx.x;
  for (int i = tid; i < 4608; i += 256) lw[i] = w2frag[i];
  for (int i = tid; i < 2048; i += 256) ls[i] = 0;
  __syncthreads();

  int lane = tid & 63;
  int lane31 = lane & 31, lhalf = lane >> 5;
  int bias0 = bint2[lane31], bias1 = bint2[32 + lane31];
  size_t aoff = (size_t)lane31 * 32 + (size_t)lhalf * 16;
  float h = (sc->s1 * sc->sw2) * (1.0f / sc->s2);

  for (int it = 0; it < ITER2; ++it) {
    int tb = blockIdx.x + it * NBLK2;
    int wv = tb * 4 + (tid >> 6);
    int owg = wv % 7; int t = wv / 7;
    int ohg = t % 110; int b = t / 110;
    int oh0 = ohg * 2, ow0 = owg * 32;

    const unsigned char* base0 = y1n + ((size_t)((b * 222 + oh0) * 224 + ow0)) * 32 + aoff;
    v4i a[4][3];
#pragma unroll
    for (int i = 0; i < 4; ++i)
#pragma unroll
      for (int kw = 0; kw < 3; ++kw)
        a[i][kw] = *(const v4i*)(base0 + (size_t)i * (224 * 32) + kw * 32);

    v16i acc00, acc01, acc10, acc11;
#pragma unroll
    for (int r = 0; r < 16; ++r) {
      acc00[r] = bias0; acc01[r] = bias1;
      acc10[r] = bias0; acc11[r] = bias1;
    }

#pragma unroll
    for (int kh = 0; kh < 3; ++kh)
#pragma unroll
      for (int kw = 0; kw < 3; ++kw) {
        int tap = kh * 3 + kw;
        v4i b0 = *(const v4i*)(lw + (tap * 2 + 0) * 256 + lane * 4);
        v4i b1 = *(const v4i*)(lw + (tap * 2 + 1) * 256 + lane * 4);
        acc00 = __builtin_amdgcn_mfma_i32_32x32x32_i8(a[kh][kw], b0, acc00, 0, 0, 0);
        acc01 = __builtin_amdgcn_mfma_i32_32x32x32_i8(a[kh][kw], b1, acc01, 0, 0, 0);
        acc10 = __builtin_amdgcn_mfma_i32_32x32x32_i8(a[kh + 1][kw], b0, acc10, 0, 0, 0);
        acc11 = __builtin_amdgcn_mfma_i32_32x32x32_i8(a[kh + 1][kw], b1, acc11, 0, 0, 0);
      }

    int isum0 = 0, isum1 = 0;
#pragma unroll
    for (int r = 0; r < 16; ++r) {
      int m = (r & 3) + 8 * (r >> 2) + 4 * lhalf;
      if (ow0 + m < 220) {
        isum0 += (int)fminf(fmaxf(rintf((float)acc00[r] * h), 0.f), 15.f);
        isum1 += (int)fminf(fmaxf(rintf((float)acc01[r] * h), 0.f), 15.f);
        isum0 += (int)fminf(fmaxf(rintf((float)acc10[r] * h), 0.f), 15.f);
        isum1 += (int)fminf(fmaxf(rintf((float)acc11[r] * h), 0.f), 15.f);
      }
    }
    isum0 += __shfl_down(isum0, 32, 64);
    isum1 += __shfl_down(isum1, 32, 64);
    if (lhalf == 0) {
      atomicAdd(&ls[b * 64 + lane31], isum0);
      atomicAdd(&ls[b * 64 + 32 + lane31], isum1);
    }
  }
  __syncthreads();
  for (int i = tid; i < 2048; i += 256) {
    int v = ls[i];
    if (v != 0) atomicAdd(&pooled_i[i], v);
  }
}

__global__ void k_fin2(Scal* sc) {
  sc->s2 = fmaxf((float)sc->max2 * (sc->s1 * sc->sw2), 1e-8f) / 15.f;
}

// whole FC head + log_softmax in one block
__global__ void k_fc(const int* __restrict__ pooled_i, const float* __restrict__ wf1,
                     const float* __restrict__ bf1, const float* __restrict__ wf2,
                     const float* __restrict__ bf2, const Scal* __restrict__ sc,
                     float* __restrict__ out) {
  __shared__ float pl[2048];
  __shared__ float wq1[8192];
  __shared__ float y3[4096];
  __shared__ float zz[320];
  __shared__ float s3sh;
  int tid = threadIdx.x;
  float swf1 = sc->swf1, swf2 = sc->swf2, s2 = sc->s2;
  for (int i = tid; i < 2048; i += 256) pl[i] = (float)pooled_i[i] * s2 / 48400.0f;
  for (int i = tid; i < 8192; i += 256) {
    float q = rintf(wf1[i] / swf1);
    q = fminf(fmaxf(q, -8.f), 7.f);
    wq1[i] = q * swf1;
  }
  __syncthreads();
  float sb1 = s2 * swf1;
  float lmax = 0.f;
  for (int o = tid; o < 4096; o += 256) {
    int b = o >> 7, j = o & 127;
    float acc = rintf(bf1[j] / sb1) * sb1;
    const float* wrow = &wq1[j * 64];
    const float* xrow = &pl[b * 64];
#pragma unroll 16
    for (int k = 0; k < 64; ++k) acc += xrow[k] * wrow[k];
    float r = fmaxf(acc, 0.f);
    y3[o] = r;
    lmax = fmaxf(lmax, r);
  }
  float m = block_maxf(lmax);  // contains a __syncthreads (after y3 writes)
  if (!tid) s3sh = fmaxf(m, 1e-8f) / 15.f;
  __syncthreads();
  float s3 = s3sh;
  float sb2 = s3 * swf2;
  for (int o = tid; o < 320; o += 256) {
    int b = o / 10, j = o - b * 10;
    float acc = rintf(bf2[j] / sb2) * sb2;
    const float* yy = &y3[b * 128];
    const float* wrow = &wf2[j * 128];
    for (int k = 0; k < 128; ++k) {
      float q = rintf(yy[k] / s3);
      q = fminf(fmaxf(q, 0.f), 15.f);
      float wv = rintf(wrow[k] / swf2);
      wv = fminf(fmaxf(wv, -8.f), 7.f);
      acc += (q * s3) * (wv * swf2);
    }
    zz[o] = acc;
  }
  __syncthreads();
  if (tid < 32) {
    const float* z = &zz[tid * 10];
    float mm = z[0];
    for (int k = 1; k < 10; ++k) mm = fmaxf(mm, z[k]);
    float ssum = 0.f;
    for (int k = 0; k < 10; ++k) ssum += expf(z[k] - mm);
    float l = mm + logf(ssum);
    for (int k = 0; k < 10; ++k) out[tid * 10 + k] = z[k] - l;
  }
}

extern "C" void kernel_launch(void* const* d_in, const int* in_sizes, int n_in,
                              void* d_out, int out_size, void* d_ws, size_t ws_size,
                              hipStream_t stream) {
  const float* x   = (const float*)d_in[0];
  const float* w1  = (const float*)d_in[1];
  const float* b1  = (const float*)d_in[2];
  const float* w2  = (const float*)d_in[3];
  const float* b2  = (const float*)d_in[4];
  const float* wf1 = (const float*)d_in[5];
  const float* bf1 = (const float*)d_in[6];
  const float* wf2 = (const float*)d_in[7];
  const float* bf2 = (const float*)d_in[8];
  float* out = (float*)d_out;

  char* ws = (char*)d_ws;
  Scal* sc = (Scal*)ws;
  size_t off = 1024;
  signed char* xq = (signed char*)(ws + off);   off += (size_t)NX + 256;  // +slack
  off = (off + 255) & ~(size_t)255;
  unsigned* w1pk = (unsigned*)(ws + off);       off += 2048;              // [oc][row] {w0,w1,w2,0}
  unsigned* w2frag = (unsigned*)(ws + off);     off += 4608 * 4;          // MFMA B-frag layout
  int* bint1 = (int*)(ws + off);                off += 256;
  int* bint2 = (int*)(ws + off);                off += 256;
  unsigned char* y1n = (unsigned char*)(ws + off); off += (size_t)NP1;    // NHWC codes
  off = (off + 255) & ~(size_t)255;
  int* pooled_i = (int*)(ws + off);             off += 8192;              // also slack for conv2 tail reads
  off = (off + 255) & ~(size_t)255;
  short* y1acc = (short*)(ws + off);            off += (size_t)NP1 * 2;   // planar int16 conv1 acc
  (void)ws_size; (void)in_sizes; (void)n_in; (void)out_size;

  hipMemsetAsync(sc, 0, 1024, stream);
  hipMemsetAsync(pooled_i, 0, 8192, stream);
  k_absmax_x<<<1024, 256, 0, stream>>>((const float4*)x, NX / 4, &sc->max_x);
  k_absmax_w<<<4, 256, 0, stream>>>(w1, w2, wf1, wf2, sc);
  k_scales<<<1, 1, 0, stream>>>(sc);
  k_quant_x<<<NX / 4 / 256, 256, 0, stream>>>((const float4*)x, (unsigned*)xq, NX / 4, sc);
  k_quant_w<<<22, 256, 0, stream>>>(w1, w2, b1, sc, w1pk, w2frag, bint1);
  k_conv1<<<dim3(37, 32), 256, 0, stream>>>(xq, w1pk, bint1, y1acc, &sc->max1);
  k_fin1<<<1, 64, 0, stream>>>(sc, b2, bint2);
  k_requant_t<<<dim3(195, 32), 256, 0, stream>>>(y1acc, sc, y1n);
  k_conv2a<<<NBLK2, 256, 0, stream>>>(y1n, w2frag, bint2, &sc->max2);
  k_fin2<<<1, 1, 0, stream>>>(sc);
  k_conv2b<<<NBLK2, 256, 0, stream>>>(y1n, w2frag, bint2, sc, pooled_i);
  k_fc<<<1, 256, 0, stream>>>(pooled_i, wf1, bf1, wf2, bf2, sc, out);
}

// Round 13
// 352.670 us; speedup vs baseline: 1.3928x; 1.0570x over previous
//
#include <hip/hip_runtime.h>
#include <cstdint>
#include <cstddef>

#define DI __device__ __forceinline__

typedef int v4i  __attribute__((ext_vector_type(4)));
typedef int v16i __attribute__((ext_vector_type(16)));

#if defined(__has_builtin)
#if __has_builtin(__builtin_amdgcn_sdot4)
#define HAS_SDOT4 1
#endif
#if __has_builtin(__builtin_amdgcn_alignbyte)
#define HAS_ALIGNBYTE 1
#endif
#endif

DI int dot4(unsigned a, unsigned b, int c) {
#ifdef HAS_SDOT4
  return __builtin_amdgcn_sdot4((int)a, (int)b, c, false);
#else
#pragma unroll
  for (int k = 0; k < 4; ++k)
    c += (int)(signed char)(a >> (8 * k)) * (int)(signed char)(b >> (8 * k));
  return c;
#endif
}

DI unsigned alignb(unsigned hi, unsigned lo, int sh) {  // bytes (hi:lo) >> 8*sh
#ifdef HAS_ALIGNBYTE
  return __builtin_amdgcn_alignbyte(hi, lo, sh);
#else
  return (lo >> (8 * sh)) | (hi << (32 - 8 * sh));
#endif
}

DI float qclamp(int a, float h) {  // clamp(rint(a*h), 0, 15) as float
  return fminf(fmaxf(rintf((float)a * h), 0.f), 15.f);
}

// ---------------- scalar block in workspace ----------------
struct Scal {
  unsigned max_x, max_w1, max_w2, max_wf1, max_wf2;  // float bits (abs-max, >=0)
  float s_in, sw1, sw2, swf1, swf2;
  int   max1; float s1;
  int   max2; float s2;
};

static constexpr int NX   = 32 * 3 * 224 * 224;     // 4,816,896
static constexpr int NP1  = 32 * 32 * 222 * 224;    // 50,921,472 padded conv1 outputs
static constexpr int NPIX = 222 * 224;              // 49,728 padded pixels per image
static constexpr int NBLK2 = 1232;                  // conv2 blocks
static constexpr int ITER2 = 5;                     // contiguous tiles per wave (6160 total)

// ---------------- reduction helpers (blockDim == 256) ----------------
DI float wave_maxf(float v) { for (int o = 32; o; o >>= 1) v = fmaxf(v, __shfl_down(v, o, 64)); return v; }
DI int   wave_maxi(int v)   { for (int o = 32; o; o >>= 1) v = max(v, __shfl_down(v, o, 64));   return v; }

DI float block_maxf(float v) {  // valid in thread 0; all values >= 0
  __shared__ float s[4];
  v = wave_maxf(v);
  int lane = threadIdx.x & 63, w = threadIdx.x >> 6;
  if (!lane) s[w] = v;
  __syncthreads();
  if (threadIdx.x < 64) {
    float t = (threadIdx.x < 4) ? s[threadIdx.x] : 0.f;
    v = wave_maxf(t);
  }
  return v;
}

DI int block_maxi(int v) {  // valid in thread 0; all values >= 0
  __shared__ int s[4];
  v = wave_maxi(v);
  int lane = threadIdx.x & 63, w = threadIdx.x >> 6;
  if (!lane) s[w] = v;
  __syncthreads();
  if (threadIdx.x < 64) {
    int t = (threadIdx.x < 4) ? s[threadIdx.x] : 0;
    v = wave_maxi(t);
  }
  return v;
}

// ---------------- stage kernels ----------------
__global__ void k_absmax_x(const float4* __restrict__ x, int n4, unsigned* slot) {
  float m = 0.f;
  for (int i = blockIdx.x * blockDim.x + threadIdx.x; i < n4; i += gridDim.x * blockDim.x) {
    float4 v = x[i];
    m = fmaxf(m, fmaxf(fmaxf(fabsf(v.x), fabsf(v.y)), fmaxf(fabsf(v.z), fabsf(v.w))));
  }
  m = block_maxf(m);
  if (!threadIdx.x) atomicMax(slot, __float_as_uint(m));
}

__global__ void k_absmax_w(const float* __restrict__ w1, const float* __restrict__ w2,
                           const float* __restrict__ wf1, const float* __restrict__ wf2,
                           Scal* sc) {
  const float* p; int n; unsigned* slot;
  if (blockIdx.x == 0)      { p = w1;  n = 864;   slot = &sc->max_w1; }
  else if (blockIdx.x == 1) { p = w2;  n = 18432; slot = &sc->max_w2; }
  else if (blockIdx.x == 2) { p = wf1; n = 8192;  slot = &sc->max_wf1; }
  else                      { p = wf2; n = 1280;  slot = &sc->max_wf2; }
  float m = 0.f;
  for (int i = threadIdx.x; i < n; i += blockDim.x) m = fmaxf(m, fabsf(p[i]));
  m = block_maxf(m);
  if (!threadIdx.x) atomicMax(slot, __float_as_uint(m));
}

__global__ void k_scales(Scal* sc) {
  sc->s_in = fmaxf(__uint_as_float(sc->max_x),  1e-8f) / 7.f;
  sc->sw1  = fmaxf(__uint_as_float(sc->max_w1), 1e-8f) / 7.f;
  sc->sw2  = fmaxf(__uint_as_float(sc->max_w2), 1e-8f) / 7.f;
  sc->swf1 = fmaxf(__uint_as_float(sc->max_wf1),1e-8f) / 7.f;
  sc->swf2 = fmaxf(__uint_as_float(sc->max_wf2),1e-8f) / 7.f;
}

// 4 floats -> 4 packed int8 codes per thread
__global__ void k_quant_x(const float4* __restrict__ x, unsigned* __restrict__ xq,
                          int n4, const Scal* __restrict__ sc) {
  float s = sc->s_in;
  int i = blockIdx.x * 256 + threadIdx.x;
  if (i >= n4) return;
  float4 v = x[i];
  float f[4] = {v.x, v.y, v.z, v.w};
  unsigned w = 0;
#pragma unroll
  for (int k = 0; k < 4; ++k) {
    float q = rintf(f[k] / s);
    q = fminf(fmaxf(q, -8.f), 7.f);
    w |= ((unsigned)((int)q & 255)) << (8 * k);
  }
  xq[i] = w;
}

// pack w1 as [oc][row] dwords {w0,w1,w2,0}; w2 directly into the MFMA B-frag
// layout w2frag[((tap*2+half)*64 + dl)*4 + q]; bias1 ints
__global__ void k_quant_w(const float* __restrict__ w1, const float* __restrict__ w2,
                          const float* __restrict__ b1, const Scal* __restrict__ sc,
                          unsigned* __restrict__ w1pk, unsigned* __restrict__ w2frag,
                          int* __restrict__ bint1) {
  int i = blockIdx.x * blockDim.x + threadIdx.x;
  if (i < 288) {
    int oc = i / 9, r = i - oc * 9;   // r = ic*3 + kh; bytes = kw 0..2
    float s = sc->sw1;
    unsigned w = 0;
#pragma unroll
    for (int k = 0; k < 3; ++k) {
      float q = rintf(w1[oc * 27 + r * 3 + k] / s);
      q = fminf(fmaxf(q, -8.f), 7.f);
      w |= ((unsigned)((int)q & 255)) << (8 * k);
    }
    w1pk[i] = w;
  } else if (i < 288 + 4608) {
    int j = i - 288;
    int icq = j & 7; int t = j >> 3;
    int kw = t % 3; t /= 3;
    int kh = t % 3; int oc = t / 3;
    float s = sc->sw2;
    unsigned w = 0;
#pragma unroll
    for (int k = 0; k < 4; ++k) {
      int ic = icq * 4 + k;
      float q = rintf(w2[(oc * 32 + ic) * 9 + kh * 3 + kw] / s);
      q = fminf(fmaxf(q, -8.f), 7.f);
      w |= ((unsigned)((int)q & 255)) << (8 * k);
    }
    int tap = kh * 3 + kw;
    int dl = (oc & 31) | ((icq >> 2) << 5);
    w2frag[(((tap * 2) + (oc >> 5)) * 64 + dl) * 4 + (icq & 3)] = w;
  } else if (i < 288 + 4608 + 32) {
    int j = i - 4896;
    bint1[j] = (int)rintf(b1[j] / (sc->s_in * sc->sw1));
  }
}

// conv1 LDS-tiled: one block = (b, strip of 6 oh rows). Stage 3 ic x 8 input
// rows (5.3 KB) + weights + bias in LDS once; 256 threads sweep 28 g x 6 oh x
// 32 oc tasks (21 iters) with sdot4+alignbyte on LDS segments. Stores planar
// int16 acc; block max of relu(acc) over valid cols.
__global__ void __launch_bounds__(256) k_conv1(
    const signed char* __restrict__ xq, const unsigned* __restrict__ w1pk,
    const int* __restrict__ bint1, short* __restrict__ y1acc, int* __restrict__ max1) {
  __shared__ signed char lx[3 * 8 * 224 + 16];  // [ic][row 0..7][224] + pad
  __shared__ unsigned lw[288];
  __shared__ int lb[32];
  int tid = threadIdx.x;
  int strip = blockIdx.x;   // 0..36 (222 = 6*37)
  int b = blockIdx.y;       // 0..31
  int oh0 = strip * 6;

  for (int i = tid; i < 288; i += 256) lw[i] = w1pk[i];
  if (tid < 32) lb[tid] = bint1[tid];
  {
    const unsigned* src = (const unsigned*)(xq + (size_t)b * 3 * 224 * 224);
    unsigned* dst = (unsigned*)lx;
    // 24 rows x 56 dwords = 1344 dwords, coalesced
#pragma unroll
    for (int it = 0; it < 6; ++it) {
      int i = it * 256 + tid;
      if (i < 1344) {
        int row = i / 56, d = i - row * 56;   // row = ic*8 + r
        int ic = row >> 3, r = row & 7;
        dst[i] = src[(ic * 224 + (oh0 + r)) * 56 + d];
      }
    }
  }
  __syncthreads();

  int mx = 0;
  for (int it = 0; it < 21; ++it) {
    int i = it * 256 + tid;          // 5376 tasks: g fast, then oh_l, then oc
    int g = i % 28;
    int r = i / 28;
    int oh_l = r % 6;
    int oc = r / 6;

    int bias = lb[oc];
    int acc[8];
#pragma unroll
    for (int j = 0; j < 8; ++j) acc[j] = bias;

#pragma unroll
    for (int seg = 0; seg < 9; ++seg) {
      int ic = seg / 3, kh = seg - ic * 3;
      const signed char* base = lx + (ic * 8 + oh_l + kh) * 224 + g * 8;
      uint2 lo = *(const uint2*)base;            // 8B aligned
      unsigned d0 = lo.x, d1 = lo.y;
      unsigned d2 = *(const unsigned*)(base + 8);
      unsigned wr = lw[oc * 9 + ic * 3 + kh];
      acc[0] = dot4(d0, wr, acc[0]);
      acc[1] = dot4(alignb(d1, d0, 1), wr, acc[1]);
      acc[2] = dot4(alignb(d1, d0, 2), wr, acc[2]);
      acc[3] = dot4(alignb(d1, d0, 3), wr, acc[3]);
      acc[4] = dot4(d1, wr, acc[4]);
      acc[5] = dot4(alignb(d2, d1, 1), wr, acc[5]);
      acc[6] = dot4(alignb(d2, d1, 2), wr, acc[6]);
      acc[7] = dot4(alignb(d2, d1, 3), wr, acc[7]);
    }

    size_t off = ((size_t)((b * 32 + oc) * 222 + oh0 + oh_l)) * 224 + g * 8;
    uint4 st;
    st.x = ((unsigned)(unsigned short)acc[0]) | ((unsigned)(unsigned short)acc[1] << 16);
    st.y = ((unsigned)(unsigned short)acc[2]) | ((unsigned)(unsigned short)acc[3] << 16);
    st.z = ((unsigned)(unsigned short)acc[4]) | ((unsigned)(unsigned short)acc[5] << 16);
    st.w = ((unsigned)(unsigned short)acc[6]) | ((unsigned)(unsigned short)acc[7] << 16);
    *(uint4*)(y1acc + off) = st;

#pragma unroll
    for (int j = 0; j < 8; ++j) if (g * 8 + j < 222) mx = max(mx, acc[j]);
  }
  mx = block_maxi(max(mx, 0));
  if (!tid) atomicMax(max1, mx);
}

__global__ void k_fin1(Scal* sc, const float* __restrict__ b2, int* __restrict__ bint2) {
  float sc1 = sc->s_in * sc->sw1;
  float s1 = fmaxf((float)sc->max1 * sc1, 1e-8f) / 15.f;
  if (!threadIdx.x) sc->s1 = s1;
  float sb = s1 * sc->sw2;
  bint2[threadIdx.x] = (int)rintf(b2[threadIdx.x] / sb);
}

// int16 planar acc -> NHWC uint8 relu4 codes (32 ic bytes contiguous per pixel)
__global__ void k_requant_t(const short* __restrict__ y1acc, const Scal* __restrict__ sc,
                            unsigned char* __restrict__ y1n) {
  int p = blockIdx.x * 256 + threadIdx.x;  // pixel within image (padded space)
  int b = blockIdx.y;
  if (p >= NPIX) return;
  float sc1 = sc->s_in * sc->sw1, s1 = sc->s1;
  const short* base = y1acc + (size_t)b * 32 * NPIX + p;
  unsigned w[8] = {0, 0, 0, 0, 0, 0, 0, 0};
#pragma unroll
  for (int oc = 0; oc < 32; ++oc) {
    int a = (int)base[(size_t)oc * NPIX];
    float y = (float)a * sc1;
    float q = rintf(y / s1);
    q = fminf(fmaxf(q, 0.f), 15.f);
    w[oc >> 2] |= ((unsigned)(int)q) << (8 * (oc & 3));
  }
  uint4* dst = (uint4*)(y1n + ((size_t)b * NPIX + p) * 32);
  dst[0] = make_uint4(w[0], w[1], w[2], w[3]);
  dst[1] = make_uint4(w[4], w[5], w[6], w[7]);
}

// conv2 pass A: each wave owns ITER2 CONTIGUOUS tiles (tile = 32px x 2 rows x
// 64oc, 36 MFMA) for L1 halo reuse. Weights staged once; no barriers in loop;
// owg!=6 fast path drops boundary predicates; one block reduce at the end.
__global__ void __launch_bounds__(256) k_conv2a(
    const unsigned char* __restrict__ y1n, const unsigned* __restrict__ w2frag,
    const int* __restrict__ bint2, int* __restrict__ max2) {
  __shared__ unsigned lw[4608];
  int tid = threadIdx.x;
  for (int i = tid; i < 4608; i += 256) lw[i] = w2frag[i];
  __syncthreads();

  int lane = tid & 63;
  int lane31 = lane & 31, lhalf = lane >> 5;
  int bias0 = bint2[lane31], bias1 = bint2[32 + lane31];
  size_t aoff = (size_t)lane31 * 32 + (size_t)lhalf * 16;
  int mx = 0;

  for (int it = 0; it < ITER2; ++it) {
    int tb = blockIdx.x * ITER2 + it;
    int wv = tb * 4 + (tid >> 6);
    int owg = wv % 7; int t = wv / 7;
    int ohg = t % 110; int b = t / 110;
    int oh0 = ohg * 2, ow0 = owg * 32;

    const unsigned char* base0 = y1n + ((size_t)((b * 222 + oh0) * 224 + ow0)) * 32 + aoff;
    v4i a[4][3];
#pragma unroll
    for (int i = 0; i < 4; ++i)
#pragma unroll
      for (int kw = 0; kw < 3; ++kw)
        a[i][kw] = *(const v4i*)(base0 + (size_t)i * (224 * 32) + kw * 32);

    v16i acc00, acc01, acc10, acc11;
#pragma unroll
    for (int r = 0; r < 16; ++r) {
      acc00[r] = bias0; acc01[r] = bias1;
      acc10[r] = bias0; acc11[r] = bias1;
    }

#pragma unroll
    for (int kh = 0; kh < 3; ++kh)
#pragma unroll
      for (int kw = 0; kw < 3; ++kw) {
        int tap = kh * 3 + kw;
        v4i b0 = *(const v4i*)(lw + (tap * 2 + 0) * 256 + lane * 4);
        v4i b1 = *(const v4i*)(lw + (tap * 2 + 1) * 256 + lane * 4);
        acc00 = __builtin_amdgcn_mfma_i32_32x32x32_i8(a[kh][kw], b0, acc00, 0, 0, 0);
        acc01 = __builtin_amdgcn_mfma_i32_32x32x32_i8(a[kh][kw], b1, acc01, 0, 0, 0);
        acc10 = __builtin_amdgcn_mfma_i32_32x32x32_i8(a[kh + 1][kw], b0, acc10, 0, 0, 0);
        acc11 = __builtin_amdgcn_mfma_i32_32x32x32_i8(a[kh + 1][kw], b1, acc11, 0, 0, 0);
      }

    if (owg != 6) {  // wave-uniform: all 32 columns valid
#pragma unroll
      for (int r = 0; r < 16; ++r)
        mx = max(mx, max(max(acc00[r], acc01[r]), max(acc10[r], acc11[r])));
    } else {
#pragma unroll
      for (int r = 0; r < 16; ++r) {
        int m = (r & 3) + 8 * (r >> 2) + 4 * lhalf;
        if (ow0 + m < 220)
          mx = max(mx, max(max(acc00[r], acc01[r]), max(acc10[r], acc11[r])));
      }
    }
  }
  mx = block_maxi(max(mx, 0));
  if (!tid) atomicMax(max2, mx);
}

// conv2 pass B: recompute acc per tile (contiguous chunk), quantize in-register
// (float sums, one int convert), pool into block-local ls[2048], flush at end.
__global__ void __launch_bounds__(256) k_conv2b(
    const unsigned char* __restrict__ y1n, const unsigned* __restrict__ w2frag,
    const int* __restrict__ bint2, const Scal* __restrict__ sc,
    int* __restrict__ pooled_i) {
  __shared__ unsigned lw[4608];
  __shared__ int ls[2048];
  int tid = threadIdx.x;
  for (int i = tid; i < 4608; i += 256) lw[i] = w2frag[i];
  for (int i = tid; i < 2048; i += 256) ls[i] = 0;
  __syncthreads();

  int lane = tid & 63;
  int lane31 = lane & 31, lhalf = lane >> 5;
  int bias0 = bint2[lane31], bias1 = bint2[32 + lane31];
  size_t aoff = (size_t)lane31 * 32 + (size_t)lhalf * 16;
  float h = (sc->s1 * sc->sw2) * (1.0f / sc->s2);

  for (int it = 0; it < ITER2; ++it) {
    int tb = blockIdx.x * ITER2 + it;
    int wv = tb * 4 + (tid >> 6);
    int owg = wv % 7; int t = wv / 7;
    int ohg = t % 110; int b = t / 110;
    int oh0 = ohg * 2, ow0 = owg * 32;

    const unsigned char* base0 = y1n + ((size_t)((b * 222 + oh0) * 224 + ow0)) * 32 + aoff;
    v4i a[4][3];
#pragma unroll
    for (int i = 0; i < 4; ++i)
#pragma unroll
      for (int kw = 0; kw < 3; ++kw)
        a[i][kw] = *(const v4i*)(base0 + (size_t)i * (224 * 32) + kw * 32);

    v16i acc00, acc01, acc10, acc11;
#pragma unroll
    for (int r = 0; r < 16; ++r) {
      acc00[r] = bias0; acc01[r] = bias1;
      acc10[r] = bias0; acc11[r] = bias1;
    }

#pragma unroll
    for (int kh = 0; kh < 3; ++kh)
#pragma unroll
      for (int kw = 0; kw < 3; ++kw) {
        int tap = kh * 3 + kw;
        v4i b0 = *(const v4i*)(lw + (tap * 2 + 0) * 256 + lane * 4);
        v4i b1 = *(const v4i*)(lw + (tap * 2 + 1) * 256 + lane * 4);
        acc00 = __builtin_amdgcn_mfma_i32_32x32x32_i8(a[kh][kw], b0, acc00, 0, 0, 0);
        acc01 = __builtin_amdgcn_mfma_i32_32x32x32_i8(a[kh][kw], b1, acc01, 0, 0, 0);
        acc10 = __builtin_amdgcn_mfma_i32_32x32x32_i8(a[kh + 1][kw], b0, acc10, 0, 0, 0);
        acc11 = __builtin_amdgcn_mfma_i32_32x32x32_i8(a[kh + 1][kw], b1, acc11, 0, 0, 0);
      }

    float fs0 = 0.f, fs1 = 0.f;
    if (owg != 6) {  // wave-uniform: all 32 columns valid
#pragma unroll
      for (int r = 0; r < 16; ++r) {
        fs0 += qclamp(acc00[r], h) + qclamp(acc10[r], h);
        fs1 += qclamp(acc01[r], h) + qclamp(acc11[r], h);
      }
    } else {
#pragma unroll
      for (int r = 0; r < 16; ++r) {
        int m = (r & 3) + 8 * (r >> 2) + 4 * lhalf;
        if (ow0 + m < 220) {
          fs0 += qclamp(acc00[r], h) + qclamp(acc10[r], h);
          fs1 += qclamp(acc01[r], h) + qclamp(acc11[r], h);
        }
      }
    }
    int isum0 = (int)fs0, isum1 = (int)fs1;  // exact: <= 32*15
    isum0 += __shfl_down(isum0, 32, 64);
    isum1 += __shfl_down(isum1, 32, 64);
    if (lhalf == 0) {
      atomicAdd(&ls[b * 64 + lane31], isum0);
      atomicAdd(&ls[b * 64 + 32 + lane31], isum1);
    }
  }
  __syncthreads();
  for (int i = tid; i < 2048; i += 256) {
    int v = ls[i];
    if (v != 0) atomicAdd(&pooled_i[i], v);
  }
}

__global__ void k_fin2(Scal* sc) {
  sc->s2 = fmaxf((float)sc->max2 * (sc->s1 * sc->sw2), 1e-8f) / 15.f;
}

// whole FC head + log_softmax in one block
__global__ void k_fc(const int* __restrict__ pooled_i, const float* __restrict__ wf1,
                     const float* __restrict__ bf1, const float* __restrict__ wf2,
                     const float* __restrict__ bf2, const Scal* __restrict__ sc,
                     float* __restrict__ out) {
  __shared__ float pl[2048];
  __shared__ float wq1[8192];
  __shared__ float y3[4096];
  __shared__ float zz[320];
  __shared__ float s3sh;
  int tid = threadIdx.x;
  float swf1 = sc->swf1, swf2 = sc->swf2, s2 = sc->s2;
  for (int i = tid; i < 2048; i += 256) pl[i] = (float)pooled_i[i] * s2 / 48400.0f;
  for (int i = tid; i < 8192; i += 256) {
    float q = rintf(wf1[i] / swf1);
    q = fminf(fmaxf(q, -8.f), 7.f);
    wq1[i] = q * swf1;
  }
  __syncthreads();
  float sb1 = s2 * swf1;
  float lmax = 0.f;
  for (int o = tid; o < 4096; o += 256) {
    int b = o >> 7, j = o & 127;
    float acc = rintf(bf1[j] / sb1) * sb1;
    const float* wrow = &wq1[j * 64];
    const float* xrow = &pl[b * 64];
#pragma unroll 16
    for (int k = 0; k < 64; ++k) acc += xrow[k] * wrow[k];
    float r = fmaxf(acc, 0.f);
    y3[o] = r;
    lmax = fmaxf(lmax, r);
  }
  float m = block_maxf(lmax);  // contains a __syncthreads (after y3 writes)
  if (!tid) s3sh = fmaxf(m, 1e-8f) / 15.f;
  __syncthreads();
  float s3 = s3sh;
  float sb2 = s3 * swf2;
  for (int o = tid; o < 320; o += 256) {
    int b = o / 10, j = o - b * 10;
    float acc = rintf(bf2[j] / sb2) * sb2;
    const float* yy = &y3[b * 128];
    const float* wrow = &wf2[j * 128];
    for (int k = 0; k < 128; ++k) {
      float q = rintf(yy[k] / s3);
      q = fminf(fmaxf(q, 0.f), 15.f);
      float wv = rintf(wrow[k] / swf2);
      wv = fminf(fmaxf(wv, -8.f), 7.f);
      acc += (q * s3) * (wv * swf2);
    }
    zz[o] = acc;
  }
  __syncthreads();
  if (tid < 32) {
    const float* z = &zz[tid * 10];
    float mm = z[0];
    for (int k = 1; k < 10; ++k) mm = fmaxf(mm, z[k]);
    float ssum = 0.f;
    for (int k = 0; k < 10; ++k) ssum += expf(z[k] - mm);
    float l = mm + logf(ssum);
    for (int k = 0; k < 10; ++k) out[tid * 10 + k] = z[k] - l;
  }
}

extern "C" void kernel_launch(void* const* d_in, const int* in_sizes, int n_in,
                              void* d_out, int out_size, void* d_ws, size_t ws_size,
                              hipStream_t stream) {
  const float* x   = (const float*)d_in[0];
  const float* w1  = (const float*)d_in[1];
  const float* b1  = (const float*)d_in[2];
  const float* w2  = (const float*)d_in[3];
  const float* b2  = (const float*)d_in[4];
  const float* wf1 = (const float*)d_in[5];
  const float* bf1 = (const float*)d_in[6];
  const float* wf2 = (const float*)d_in[7];
  const float* bf2 = (const float*)d_in[8];
  float* out = (float*)d_out;

  char* ws = (char*)d_ws;
  Scal* sc = (Scal*)ws;
  size_t off = 1024;
  signed char* xq = (signed char*)(ws + off);   off += (size_t)NX + 256;  // +slack
  off = (off + 255) & ~(size_t)255;
  unsigned* w1pk = (unsigned*)(ws + off);       off += 2048;              // [oc][row] {w0,w1,w2,0}
  unsigned* w2frag = (unsigned*)(ws + off);     off += 4608 * 4;          // MFMA B-frag layout
  int* bint1 = (int*)(ws + off);                off += 256;
  int* bint2 = (int*)(ws + off);                off += 256;
  unsigned char* y1n = (unsigned char*)(ws + off); off += (size_t)NP1;    // NHWC codes
  off = (off + 255) & ~(size_t)255;
  int* pooled_i = (int*)(ws + off);             off += 8192;              // also slack for conv2 tail reads
  off = (off + 255) & ~(size_t)255;
  short* y1acc = (short*)(ws + off);            off += (size_t)NP1 * 2;   // planar int16 conv1 acc
  (void)ws_size; (void)in_sizes; (void)n_in; (void)out_size;

  hipMemsetAsync(sc, 0, 1024, stream);
  hipMemsetAsync(pooled_i, 0, 8192, stream);
  k_absmax_x<<<1024, 256, 0, stream>>>((const float4*)x, NX / 4, &sc->max_x);
  k_absmax_w<<<4, 256, 0, stream>>>(w1, w2, wf1, wf2, sc);
  k_scales<<<1, 1, 0, stream>>>(sc);
  k_quant_x<<<NX / 4 / 256, 256, 0, stream>>>((const float4*)x, (unsigned*)xq, NX / 4, sc);
  k_quant_w<<<22, 256, 0, stream>>>(w1, w2, b1, sc, w1pk, w2frag, bint1);
  k_conv1<<<dim3(37, 32), 256, 0, stream>>>(xq, w1pk, bint1, y1acc, &sc->max1);
  k_fin1<<<1, 64, 0, stream>>>(sc, b2, bint2);
  k_requant_t<<<dim3(195, 32), 256, 0, stream>>>(y1acc, sc, y1n);
  k_conv2a<<<NBLK2, 256, 0, stream>>>(y1n, w2frag, bint2, &sc->max2);
  k_fin2<<<1, 1, 0, stream>>>(sc);
  k_conv2b<<<NBLK2, 256, 0, stream>>>(y1n, w2frag, bint2, sc, pooled_i);
  k_fc<<<1, 256, 0, stream>>>(pooled_i, wf1, bf1, wf2, bf2, sc, out);
}

// Round 14
// 321.273 us; speedup vs baseline: 1.5289x; 1.0977x over previous
//
#include <hip/hip_runtime.h>
#include <cstdint>
#include <cstddef>

#define DI __device__ __forceinline__

typedef int v4i  __attribute__((ext_vector_type(4)));
typedef int v16i __attribute__((ext_vector_type(16)));

#if defined(__has_builtin)
#if __has_builtin(__builtin_amdgcn_sdot4)
#define HAS_SDOT4 1
#endif
#if __has_builtin(__builtin_amdgcn_alignbyte)
#define HAS_ALIGNBYTE 1
#endif
#endif

DI int dot4(unsigned a, unsigned b, int c) {
#ifdef HAS_SDOT4
  return __builtin_amdgcn_sdot4((int)a, (int)b, c, false);
#else
#pragma unroll
  for (int k = 0; k < 4; ++k)
    c += (int)(signed char)(a >> (8 * k)) * (int)(signed char)(b >> (8 * k));
  return c;
#endif
}

DI unsigned alignb(unsigned hi, unsigned lo, int sh) {  // bytes (hi:lo) >> 8*sh
#ifdef HAS_ALIGNBYTE
  return __builtin_amdgcn_alignbyte(hi, lo, sh);
#else
  return (lo >> (8 * sh)) | (hi << (32 - 8 * sh));
#endif
}

DI float qclamp(int a, float h) {  // clamp(rint(a*h), 0, 15) as float
  return fminf(fmaxf(rintf((float)a * h), 0.f), 15.f);
}

// ---------------- scalar block in workspace ----------------
struct Scal {
  unsigned max_x, max_w1, max_w2, max_wf1, max_wf2;  // float bits (abs-max, >=0)
  float s_in, sw1, sw2, swf1, swf2;
  int   max1; float s1;
  int   max2; float s2;
};

static constexpr int NX   = 32 * 3 * 224 * 224;     // 4,816,896
static constexpr int NP1  = 32 * 32 * 222 * 224;    // 50,921,472 padded conv1 outputs
static constexpr int NPIX = 222 * 224;              // 49,728 padded pixels per image
static constexpr int NBLK2 = 1232;                  // conv2 blocks
static constexpr int ITER2 = 5;                     // contiguous tiles per wave (6160 total)

// ---------------- reduction helpers (blockDim == 256) ----------------
DI float wave_maxf(float v) { for (int o = 32; o; o >>= 1) v = fmaxf(v, __shfl_down(v, o, 64)); return v; }
DI int   wave_maxi(int v)   { for (int o = 32; o; o >>= 1) v = max(v, __shfl_down(v, o, 64));   return v; }

DI float block_maxf(float v) {  // valid in thread 0; all values >= 0
  __shared__ float s[4];
  v = wave_maxf(v);
  int lane = threadIdx.x & 63, w = threadIdx.x >> 6;
  if (!lane) s[w] = v;
  __syncthreads();
  if (threadIdx.x < 64) {
    float t = (threadIdx.x < 4) ? s[threadIdx.x] : 0.f;
    v = wave_maxf(t);
  }
  return v;
}

DI int block_maxi(int v) {  // valid in thread 0; all values >= 0
  __shared__ int s[4];
  v = wave_maxi(v);
  int lane = threadIdx.x & 63, w = threadIdx.x >> 6;
  if (!lane) s[w] = v;
  __syncthreads();
  if (threadIdx.x < 64) {
    int t = (threadIdx.x < 4) ? s[threadIdx.x] : 0;
    v = wave_maxi(t);
  }
  return v;
}

// ---------------- stage kernels ----------------
__global__ void k_absmax_x(const float4* __restrict__ x, int n4, unsigned* slot) {
  float m = 0.f;
  for (int i = blockIdx.x * blockDim.x + threadIdx.x; i < n4; i += gridDim.x * blockDim.x) {
    float4 v = x[i];
    m = fmaxf(m, fmaxf(fmaxf(fabsf(v.x), fabsf(v.y)), fmaxf(fabsf(v.z), fabsf(v.w))));
  }
  m = block_maxf(m);
  if (!threadIdx.x) atomicMax(slot, __float_as_uint(m));
}

__global__ void k_absmax_w(const float* __restrict__ w1, const float* __restrict__ w2,
                           const float* __restrict__ wf1, const float* __restrict__ wf2,
                           Scal* sc) {
  const float* p; int n; unsigned* slot;
  if (blockIdx.x == 0)      { p = w1;  n = 864;   slot = &sc->max_w1; }
  else if (blockIdx.x == 1) { p = w2;  n = 18432; slot = &sc->max_w2; }
  else if (blockIdx.x == 2) { p = wf1; n = 8192;  slot = &sc->max_wf1; }
  else                      { p = wf2; n = 1280;  slot = &sc->max_wf2; }
  float m = 0.f;
  for (int i = threadIdx.x; i < n; i += blockDim.x) m = fmaxf(m, fabsf(p[i]));
  m = block_maxf(m);
  if (!threadIdx.x) atomicMax(slot, __float_as_uint(m));
}

__global__ void k_scales(Scal* sc) {
  sc->s_in = fmaxf(__uint_as_float(sc->max_x),  1e-8f) / 7.f;
  sc->sw1  = fmaxf(__uint_as_float(sc->max_w1), 1e-8f) / 7.f;
  sc->sw2  = fmaxf(__uint_as_float(sc->max_w2), 1e-8f) / 7.f;
  sc->swf1 = fmaxf(__uint_as_float(sc->max_wf1),1e-8f) / 7.f;
  sc->swf2 = fmaxf(__uint_as_float(sc->max_wf2),1e-8f) / 7.f;
}

// 4 floats -> 4 packed int8 codes per thread
__global__ void k_quant_x(const float4* __restrict__ x, unsigned* __restrict__ xq,
                          int n4, const Scal* __restrict__ sc) {
  float s = sc->s_in;
  int i = blockIdx.x * 256 + threadIdx.x;
  if (i >= n4) return;
  float4 v = x[i];
  float f[4] = {v.x, v.y, v.z, v.w};
  unsigned w = 0;
#pragma unroll
  for (int k = 0; k < 4; ++k) {
    float q = rintf(f[k] / s);
    q = fminf(fmaxf(q, -8.f), 7.f);
    w |= ((unsigned)((int)q & 255)) << (8 * k);
  }
  xq[i] = w;
}

// pack w1 as [oc][row] dwords {w0,w1,w2,0}; w2 directly into the MFMA B-frag
// layout w2frag[((tap*2+half)*64 + dl)*4 + q]; bias1 ints
__global__ void k_quant_w(const float* __restrict__ w1, const float* __restrict__ w2,
                          const float* __restrict__ b1, const Scal* __restrict__ sc,
                          unsigned* __restrict__ w1pk, unsigned* __restrict__ w2frag,
                          int* __restrict__ bint1) {
  int i = blockIdx.x * blockDim.x + threadIdx.x;
  if (i < 288) {
    int oc = i / 9, r = i - oc * 9;   // r = ic*3 + kh; bytes = kw 0..2
    float s = sc->sw1;
    unsigned w = 0;
#pragma unroll
    for (int k = 0; k < 3; ++k) {
      float q = rintf(w1[oc * 27 + r * 3 + k] / s);
      q = fminf(fmaxf(q, -8.f), 7.f);
      w |= ((unsigned)((int)q & 255)) << (8 * k);
    }
    w1pk[i] = w;
  } else if (i < 288 + 4608) {
    int j = i - 288;
    int icq = j & 7; int t = j >> 3;
    int kw = t % 3; t /= 3;
    int kh = t % 3; int oc = t / 3;
    float s = sc->sw2;
    unsigned w = 0;
#pragma unroll
    for (int k = 0; k < 4; ++k) {
      int ic = icq * 4 + k;
      float q = rintf(w2[(oc * 32 + ic) * 9 + kh * 3 + kw] / s);
      q = fminf(fmaxf(q, -8.f), 7.f);
      w |= ((unsigned)((int)q & 255)) << (8 * k);
    }
    int tap = kh * 3 + kw;
    int dl = (oc & 31) | ((icq >> 2) << 5);
    w2frag[(((tap * 2) + (oc >> 5)) * 64 + dl) * 4 + (icq & 3)] = w;
  } else if (i < 288 + 4608 + 32) {
    int j = i - 4896;
    bint1[j] = (int)rintf(b1[j] / (sc->s_in * sc->sw1));
  }
}

// conv1 LDS-tiled: one block = (b, strip of 6 oh rows). Stage 3 ic x 8 input
// rows (5.3 KB) + weights + bias in LDS once; 256 threads sweep 28 g x 6 oh x
// 32 oc tasks (21 iters) with sdot4+alignbyte on LDS segments. Stores planar
// int16 acc; block max of relu(acc) over valid cols.
__global__ void __launch_bounds__(256) k_conv1(
    const signed char* __restrict__ xq, const unsigned* __restrict__ w1pk,
    const int* __restrict__ bint1, short* __restrict__ y1acc, int* __restrict__ max1) {
  __shared__ signed char lx[3 * 8 * 224 + 16];  // [ic][row 0..7][224] + pad
  __shared__ unsigned lw[288];
  __shared__ int lb[32];
  int tid = threadIdx.x;
  int strip = blockIdx.x;   // 0..36 (222 = 6*37)
  int b = blockIdx.y;       // 0..31
  int oh0 = strip * 6;

  for (int i = tid; i < 288; i += 256) lw[i] = w1pk[i];
  if (tid < 32) lb[tid] = bint1[tid];
  {
    const unsigned* src = (const unsigned*)(xq + (size_t)b * 3 * 224 * 224);
    unsigned* dst = (unsigned*)lx;
    // 24 rows x 56 dwords = 1344 dwords, coalesced
#pragma unroll
    for (int it = 0; it < 6; ++it) {
      int i = it * 256 + tid;
      if (i < 1344) {
        int row = i / 56, d = i - row * 56;   // row = ic*8 + r
        int ic = row >> 3, r = row & 7;
        dst[i] = src[(ic * 224 + (oh0 + r)) * 56 + d];
      }
    }
  }
  __syncthreads();

  int mx = 0;
  for (int it = 0; it < 21; ++it) {
    int i = it * 256 + tid;          // 5376 tasks: g fast, then oh_l, then oc
    int g = i % 28;
    int r = i / 28;
    int oh_l = r % 6;
    int oc = r / 6;

    int bias = lb[oc];
    int acc[8];
#pragma unroll
    for (int j = 0; j < 8; ++j) acc[j] = bias;

#pragma unroll
    for (int seg = 0; seg < 9; ++seg) {
      int ic = seg / 3, kh = seg - ic * 3;
      const signed char* base = lx + (ic * 8 + oh_l + kh) * 224 + g * 8;
      uint2 lo = *(const uint2*)base;            // 8B aligned
      unsigned d0 = lo.x, d1 = lo.y;
      unsigned d2 = *(const unsigned*)(base + 8);
      unsigned wr = lw[oc * 9 + ic * 3 + kh];
      acc[0] = dot4(d0, wr, acc[0]);
      acc[1] = dot4(alignb(d1, d0, 1), wr, acc[1]);
      acc[2] = dot4(alignb(d1, d0, 2), wr, acc[2]);
      acc[3] = dot4(alignb(d1, d0, 3), wr, acc[3]);
      acc[4] = dot4(d1, wr, acc[4]);
      acc[5] = dot4(alignb(d2, d1, 1), wr, acc[5]);
      acc[6] = dot4(alignb(d2, d1, 2), wr, acc[6]);
      acc[7] = dot4(alignb(d2, d1, 3), wr, acc[7]);
    }

    size_t off = ((size_t)((b * 32 + oc) * 222 + oh0 + oh_l)) * 224 + g * 8;
    uint4 st;
    st.x = ((unsigned)(unsigned short)acc[0]) | ((unsigned)(unsigned short)acc[1] << 16);
    st.y = ((unsigned)(unsigned short)acc[2]) | ((unsigned)(unsigned short)acc[3] << 16);
    st.z = ((unsigned)(unsigned short)acc[4]) | ((unsigned)(unsigned short)acc[5] << 16);
    st.w = ((unsigned)(unsigned short)acc[6]) | ((unsigned)(unsigned short)acc[7] << 16);
    *(uint4*)(y1acc + off) = st;

#pragma unroll
    for (int j = 0; j < 8; ++j) if (g * 8 + j < 222) mx = max(mx, acc[j]);
  }
  mx = block_maxi(max(mx, 0));
  if (!tid) atomicMax(max1, mx);
}

__global__ void k_fin1(Scal* sc, const float* __restrict__ b2, int* __restrict__ bint2) {
  float sc1 = sc->s_in * sc->sw1;
  float s1 = fmaxf((float)sc->max1 * sc1, 1e-8f) / 15.f;
  if (!threadIdx.x) sc->s1 = s1;
  float sb = s1 * sc->sw2;
  bint2[threadIdx.x] = (int)rintf(b2[threadIdx.x] / sb);
}

// int16 planar acc -> NHWC uint8 relu4 codes (32 ic bytes contiguous per pixel)
__global__ void k_requant_t(const short* __restrict__ y1acc, const Scal* __restrict__ sc,
                            unsigned char* __restrict__ y1n) {
  int p = blockIdx.x * 256 + threadIdx.x;  // pixel within image (padded space)
  int b = blockIdx.y;
  if (p >= NPIX) return;
  float sc1 = sc->s_in * sc->sw1, s1 = sc->s1;
  const short* base = y1acc + (size_t)b * 32 * NPIX + p;
  unsigned w[8] = {0, 0, 0, 0, 0, 0, 0, 0};
#pragma unroll
  for (int oc = 0; oc < 32; ++oc) {
    int a = (int)base[(size_t)oc * NPIX];
    float y = (float)a * sc1;
    float q = rintf(y / s1);
    q = fminf(fmaxf(q, 0.f), 15.f);
    w[oc >> 2] |= ((unsigned)(int)q) << (8 * (oc & 3));
  }
  uint4* dst = (uint4*)(y1n + ((size_t)b * NPIX + p) * 32);
  dst[0] = make_uint4(w[0], w[1], w[2], w[3]);
  dst[1] = make_uint4(w[4], w[5], w[6], w[7]);
}

// conv2 pass A: each wave owns ITER2 CONTIGUOUS tiles (tile = 32px x 2 rows x
// 64oc, 36 MFMA) for L1 halo reuse. Weights staged once; no barriers in loop;
// owg!=6 fast path drops boundary predicates; one block reduce at the end.
__global__ void __launch_bounds__(256) k_conv2a(
    const unsigned char* __restrict__ y1n, const unsigned* __restrict__ w2frag,
    const int* __restrict__ bint2, int* __restrict__ max2) {
  __shared__ unsigned lw[4608];
  int tid = threadIdx.x;
  for (int i = tid; i < 4608; i += 256) lw[i] = w2frag[i];
  __syncthreads();

  int lane = tid & 63;
  int lane31 = lane & 31, lhalf = lane >> 5;
  int bias0 = bint2[lane31], bias1 = bint2[32 + lane31];
  size_t aoff = (size_t)lane31 * 32 + (size_t)lhalf * 16;
  int mx = 0;

  for (int it = 0; it < ITER2; ++it) {
    int tb = blockIdx.x * ITER2 + it;
    int wv = tb * 4 + (tid >> 6);
    int owg = wv % 7; int t = wv / 7;
    int ohg = t % 110; int b = t / 110;
    int oh0 = ohg * 2, ow0 = owg * 32;

    const unsigned char* base0 = y1n + ((size_t)((b * 222 + oh0) * 224 + ow0)) * 32 + aoff;
    v4i a[4][3];
#pragma unroll
    for (int i = 0; i < 4; ++i)
#pragma unroll
      for (int kw = 0; kw < 3; ++kw)
        a[i][kw] = *(const v4i*)(base0 + (size_t)i * (224 * 32) + kw * 32);

    v16i acc00, acc01, acc10, acc11;
#pragma unroll
    for (int r = 0; r < 16; ++r) {
      acc00[r] = bias0; acc01[r] = bias1;
      acc10[r] = bias0; acc11[r] = bias1;
    }

#pragma unroll
    for (int kh = 0; kh < 3; ++kh)
#pragma unroll
      for (int kw = 0; kw < 3; ++kw) {
        int tap = kh * 3 + kw;
        v4i b0 = *(const v4i*)(lw + (tap * 2 + 0) * 256 + lane * 4);
        v4i b1 = *(const v4i*)(lw + (tap * 2 + 1) * 256 + lane * 4);
        acc00 = __builtin_amdgcn_mfma_i32_32x32x32_i8(a[kh][kw], b0, acc00, 0, 0, 0);
        acc01 = __builtin_amdgcn_mfma_i32_32x32x32_i8(a[kh][kw], b1, acc01, 0, 0, 0);
        acc10 = __builtin_amdgcn_mfma_i32_32x32x32_i8(a[kh + 1][kw], b0, acc10, 0, 0, 0);
        acc11 = __builtin_amdgcn_mfma_i32_32x32x32_i8(a[kh + 1][kw], b1, acc11, 0, 0, 0);
      }

    if (owg != 6) {  // wave-uniform: all 32 columns valid
#pragma unroll
      for (int r = 0; r < 16; ++r)
        mx = max(mx, max(max(acc00[r], acc01[r]), max(acc10[r], acc11[r])));
    } else {
#pragma unroll
      for (int r = 0; r < 16; ++r) {
        int m = (r & 3) + 8 * (r >> 2) + 4 * lhalf;
        if (ow0 + m < 220)
          mx = max(mx, max(max(acc00[r], acc01[r]), max(acc10[r], acc11[r])));
      }
    }
  }
  mx = block_maxi(max(mx, 0));
  if (!tid) atomicMax(max2, mx);
}

// conv2 pass B: recompute acc per tile (contiguous chunk), quantize in-register
// (float sums, one int convert), pool into block-local ls[2048], flush at end.
__global__ void __launch_bounds__(256) k_conv2b(
    const unsigned char* __restrict__ y1n, const unsigned* __restrict__ w2frag,
    const int* __restrict__ bint2, const Scal* __restrict__ sc,
    int* __restrict__ pooled_i) {
  __shared__ unsigned lw[4608];
  __shared__ int ls[2048];
  int tid = threadIdx.x;
  for (int i = tid; i < 4608; i += 256) lw[i] = w2frag[i];
  for (int i = tid; i < 2048; i += 256) ls[i] = 0;
  __syncthreads();

  int lane = tid & 63;
  int lane31 = lane & 31, lhalf = lane >> 5;
  int bias0 = bint2[lane31], bias1 = bint2[32 + lane31];
  size_t aoff = (size_t)lane31 * 32 + (size_t)lhalf * 16;
  float h = (sc->s1 * sc->sw2) * (1.0f / sc->s2);

  for (int it = 0; it < ITER2; ++it) {
    int tb = blockIdx.x * ITER2 + it;
    int wv = tb * 4 + (tid >> 6);
    int owg = wv % 7; int t = wv / 7;
    int ohg = t % 110; int b = t / 110;
    int oh0 = ohg * 2, ow0 = owg * 32;

    const unsigned char* base0 = y1n + ((size_t)((b * 222 + oh0) * 224 + ow0)) * 32 + aoff;
    v4i a[4][3];
#pragma unroll
    for (int i = 0; i < 4; ++i)
#pragma unroll
      for (int kw = 0; kw < 3; ++kw)
        a[i][kw] = *(const v4i*)(base0 + (size_t)i * (224 * 32) + kw * 32);

    v16i acc00, acc01, acc10, acc11;
#pragma unroll
    for (int r = 0; r < 16; ++r) {
      acc00[r] = bias0; acc01[r] = bias1;
      acc10[r] = bias0; acc11[r] = bias1;
    }

#pragma unroll
    for (int kh = 0; kh < 3; ++kh)
#pragma unroll
      for (int kw = 0; kw < 3; ++kw) {
        int tap = kh * 3 + kw;
        v4i b0 = *(const v4i*)(lw + (tap * 2 + 0) * 256 + lane * 4);
        v4i b1 = *(const v4i*)(lw + (tap * 2 + 1) * 256 + lane * 4);
        acc00 = __builtin_amdgcn_mfma_i32_32x32x32_i8(a[kh][kw], b0, acc00, 0, 0, 0);
        acc01 = __builtin_amdgcn_mfma_i32_32x32x32_i8(a[kh][kw], b1, acc01, 0, 0, 0);
        acc10 = __builtin_amdgcn_mfma_i32_32x32x32_i8(a[kh + 1][kw], b0, acc10, 0, 0, 0);
        acc11 = __builtin_amdgcn_mfma_i32_32x32x32_i8(a[kh + 1][kw], b1, acc11, 0, 0, 0);
      }

    float fs0 = 0.f, fs1 = 0.f;
    if (owg != 6) {  // wave-uniform: all 32 columns valid
#pragma unroll
      for (int r = 0; r < 16; ++r) {
        fs0 += qclamp(acc00[r], h) + qclamp(acc10[r], h);
        fs1 += qclamp(acc01[r], h) + qclamp(acc11[r], h);
      }
    } else {
#pragma unroll
      for (int r = 0; r < 16; ++r) {
        int m = (r & 3) + 8 * (r >> 2) + 4 * lhalf;
        if (ow0 + m < 220) {
          fs0 += qclamp(acc00[r], h) + qclamp(acc10[r], h);
          fs1 += qclamp(acc01[r], h) + qclamp(acc11[r], h);
        }
      }
    }
    int isum0 = (int)fs0, isum1 = (int)fs1;  // exact: <= 32*15
    isum0 += __shfl_down(isum0, 32, 64);
    isum1 += __shfl_down(isum1, 32, 64);
    if (lhalf == 0) {
      atomicAdd(&ls[b * 64 + lane31], isum0);
      atomicAdd(&ls[b * 64 + 32 + lane31], isum1);
    }
  }
  __syncthreads();
  for (int i = tid; i < 2048; i += 256) {
    int v = ls[i];
    if (v != 0) atomicAdd(&pooled_i[i], v);
  }
}

__global__ void k_fin2(Scal* sc) {
  sc->s2 = fmaxf((float)sc->max2 * (sc->s1 * sc->sw2), 1e-8f) / 15.f;
}

// whole FC head + log_softmax in one 1024-thread block.
// LDS strides padded: wq1 row 65 (bank (j+k)%32, 2-way = free), y3 row 130.
__global__ void __launch_bounds__(1024) k_fc(
    const int* __restrict__ pooled_i, const float* __restrict__ wf1,
    const float* __restrict__ bf1, const float* __restrict__ wf2,
    const float* __restrict__ bf2, const Scal* __restrict__ sc,
    float* __restrict__ out) {
  __shared__ float pl[2048];
  __shared__ float wq1[128 * 65];
  __shared__ float y3[32 * 130];
  __shared__ float zz[320];
  __shared__ float s3sh;
  __shared__ float red16[16];
  int tid = threadIdx.x;
  float swf1 = sc->swf1, swf2 = sc->swf2, s2 = sc->s2;
  for (int i = tid; i < 2048; i += 1024) pl[i] = (float)pooled_i[i] * s2 / 48400.0f;
  for (int i = tid; i < 8192; i += 1024) {
    float q = rintf(wf1[i] / swf1);
    q = fminf(fmaxf(q, -8.f), 7.f);
    wq1[(i >> 6) * 65 + (i & 63)] = q * swf1;
  }
  __syncthreads();
  float sb1 = s2 * swf1;
  float lmax = 0.f;
#pragma unroll
  for (int o = tid; o < 4096; o += 1024) {
    int b = o >> 7, j = o & 127;
    float acc = rintf(bf1[j] / sb1) * sb1;
    const float* wrow = &wq1[j * 65];
    const float* xrow = &pl[b * 64];
#pragma unroll 16
    for (int k = 0; k < 64; ++k) acc += xrow[k] * wrow[k];
    float r = fmaxf(acc, 0.f);
    y3[b * 130 + j] = r;
    lmax = fmaxf(lmax, r);
  }
  // block max across 16 waves
  lmax = wave_maxf(lmax);
  {
    int lane = tid & 63, w = tid >> 6;
    if (!lane) red16[w] = lmax;
  }
  __syncthreads();
  if (tid < 64) {
    float t = (tid < 16) ? red16[tid] : 0.f;
    t = wave_maxf(t);
    if (!tid) s3sh = fmaxf(t, 1e-8f) / 15.f;
  }
  __syncthreads();
  float s3 = s3sh;
  float sb2 = s3 * swf2;
  if (tid < 320) {
    int o = tid;
    int b = o / 10, j = o - b * 10;
    float acc = rintf(bf2[j] / sb2) * sb2;
    const float* yy = &y3[b * 130];
    const float* wrow = &wf2[j * 128];
#pragma unroll 16
    for (int k = 0; k < 128; ++k) {
      float q = rintf(yy[k] / s3);
      q = fminf(fmaxf(q, 0.f), 15.f);
      float wv = rintf(wrow[k] / swf2);
      wv = fminf(fmaxf(wv, -8.f), 7.f);
      acc += (q * s3) * (wv * swf2);
    }
    zz[o] = acc;
  }
  __syncthreads();
  if (tid < 32) {
    const float* z = &zz[tid * 10];
    float mm = z[0];
    for (int k = 1; k < 10; ++k) mm = fmaxf(mm, z[k]);
    float ssum = 0.f;
    for (int k = 0; k < 10; ++k) ssum += expf(z[k] - mm);
    float l = mm + logf(ssum);
    for (int k = 0; k < 10; ++k) out[tid * 10 + k] = z[k] - l;
  }
}

extern "C" void kernel_launch(void* const* d_in, const int* in_sizes, int n_in,
                              void* d_out, int out_size, void* d_ws, size_t ws_size,
                              hipStream_t stream) {
  const float* x   = (const float*)d_in[0];
  const float* w1  = (const float*)d_in[1];
  const float* b1  = (const float*)d_in[2];
  const float* w2  = (const float*)d_in[3];
  const float* b2  = (const float*)d_in[4];
  const float* wf1 = (const float*)d_in[5];
  const float* bf1 = (const float*)d_in[6];
  const float* wf2 = (const float*)d_in[7];
  const float* bf2 = (const float*)d_in[8];
  float* out = (float*)d_out;

  char* ws = (char*)d_ws;
  Scal* sc = (Scal*)ws;
  size_t off = 1024;
  signed char* xq = (signed char*)(ws + off);   off += (size_t)NX + 256;  // +slack
  off = (off + 255) & ~(size_t)255;
  unsigned* w1pk = (unsigned*)(ws + off);       off += 2048;              // [oc][row] {w0,w1,w2,0}
  unsigned* w2frag = (unsigned*)(ws + off);     off += 4608 * 4;          // MFMA B-frag layout
  int* bint1 = (int*)(ws + off);                off += 256;
  int* bint2 = (int*)(ws + off);                off += 256;
  unsigned char* y1n = (unsigned char*)(ws + off); off += (size_t)NP1;    // NHWC codes
  off = (off + 255) & ~(size_t)255;
  int* pooled_i = (int*)(ws + off);             off += 8192;              // also slack for conv2 tail reads
  off = (off + 255) & ~(size_t)255;
  short* y1acc = (short*)(ws + off);            off += (size_t)NP1 * 2;   // planar int16 conv1 acc
  (void)ws_size; (void)in_sizes; (void)n_in; (void)out_size;

  hipMemsetAsync(sc, 0, 1024, stream);
  hipMemsetAsync(pooled_i, 0, 8192, stream);
  k_absmax_x<<<1024, 256, 0, stream>>>((const float4*)x, NX / 4, &sc->max_x);
  k_absmax_w<<<4, 256, 0, stream>>>(w1, w2, wf1, wf2, sc);
  k_scales<<<1, 1, 0, stream>>>(sc);
  k_quant_x<<<NX / 4 / 256, 256, 0, stream>>>((const float4*)x, (unsigned*)xq, NX / 4, sc);
  k_quant_w<<<22, 256, 0, stream>>>(w1, w2, b1, sc, w1pk, w2frag, bint1);
  k_conv1<<<dim3(37, 32), 256, 0, stream>>>(xq, w1pk, bint1, y1acc, &sc->max1);
  k_fin1<<<1, 64, 0, stream>>>(sc, b2, bint2);
  k_requant_t<<<dim3(195, 32), 256, 0, stream>>>(y1acc, sc, y1n);
  k_conv2a<<<NBLK2, 256, 0, stream>>>(y1n, w2frag, bint2, &sc->max2);
  k_fin2<<<1, 1, 0, stream>>>(sc);
  k_conv2b<<<NBLK2, 256, 0, stream>>>(y1n, w2frag, bint2, sc, pooled_i);
  k_fc<<<1, 1024, 0, stream>>>(pooled_i, wf1, bf1, wf2, bf2, sc, out);
}

// Round 16
// 302.284 us; speedup vs baseline: 1.6249x; 1.0628x over previous
//
#include <hip/hip_runtime.h>
#include <cstdint>
#include <cstddef>

#define DI __device__ __forceinline__

typedef int v4i  __attribute__((ext_vector_type(4)));
typedef int v16i __attribute__((ext_vector_type(16)));

#if defined(__has_builtin)
#if __has_builtin(__builtin_amdgcn_sdot4)
#define HAS_SDOT4 1
#endif
#if __has_builtin(__builtin_amdgcn_alignbyte)
#define HAS_ALIGNBYTE 1
#endif
#endif

DI int dot4(unsigned a, unsigned b, int c) {
#ifdef HAS_SDOT4
  return __builtin_amdgcn_sdot4((int)a, (int)b, c, false);
#else
#pragma unroll
  for (int k = 0; k < 4; ++k)
    c += (int)(signed char)(a >> (8 * k)) * (int)(signed char)(b >> (8 * k));
  return c;
#endif
}

DI unsigned alignb(unsigned hi, unsigned lo, int sh) {  // bytes (hi:lo) >> 8*sh, sh 0..3
#ifdef HAS_ALIGNBYTE
  return __builtin_amdgcn_alignbyte(hi, lo, sh);
#else
  return sh ? ((lo >> (8 * sh)) | (hi << (32 - 8 * sh))) : lo;
#endif
}

DI float qclamp(int a, float h) {  // clamp(rint(a*h), 0, 15) as float
  return fminf(fmaxf(rintf((float)a * h), 0.f), 15.f);
}

// ---------------- scalar block in workspace ----------------
struct Scal {
  unsigned max_x, max_w1, max_w2, max_wf1, max_wf2;  // float bits (abs-max, >=0)
  float s_in, sw1, sw2, swf1, swf2;
  int   max1; float s1;
  int   max2; float s2;
};

static constexpr int NX   = 32 * 3 * 224 * 224;     // 4,816,896
static constexpr int NP1  = 32 * 32 * 222 * 224;    // padded conv1 output count (y1n bytes)
static constexpr int NPIX = 222 * 224;              // 49,728 padded pixels per image
static constexpr int NBLK2 = 1232;                  // conv2 blocks
static constexpr int ITER2 = 5;                     // contiguous tiles per wave (6160 total)

// ---------------- reduction helpers (blockDim == 256) ----------------
DI float wave_maxf(float v) { for (int o = 32; o; o >>= 1) v = fmaxf(v, __shfl_down(v, o, 64)); return v; }
DI int   wave_maxi(int v)   { for (int o = 32; o; o >>= 1) v = max(v, __shfl_down(v, o, 64));   return v; }

DI float block_maxf(float v) {  // valid in thread 0; all values >= 0
  __shared__ float s[4];
  v = wave_maxf(v);
  int lane = threadIdx.x & 63, w = threadIdx.x >> 6;
  if (!lane) s[w] = v;
  __syncthreads();
  if (threadIdx.x < 64) {
    float t = (threadIdx.x < 4) ? s[threadIdx.x] : 0.f;
    v = wave_maxf(t);
  }
  return v;
}

DI int block_maxi(int v) {  // valid in thread 0; all values >= 0
  __shared__ int s[4];
  v = wave_maxi(v);
  int lane = threadIdx.x & 63, w = threadIdx.x >> 6;
  if (!lane) s[w] = v;
  __syncthreads();
  if (threadIdx.x < 64) {
    int t = (threadIdx.x < 4) ? s[threadIdx.x] : 0;
    v = wave_maxi(t);
  }
  return v;
}

// ---------------- stage kernels ----------------
__global__ void k_absmax_x(const float4* __restrict__ x, int n4, unsigned* slot) {
  float m = 0.f;
  for (int i = blockIdx.x * blockDim.x + threadIdx.x; i < n4; i += gridDim.x * blockDim.x) {
    float4 v = x[i];
    m = fmaxf(m, fmaxf(fmaxf(fabsf(v.x), fabsf(v.y)), fmaxf(fabsf(v.z), fabsf(v.w))));
  }
  m = block_maxf(m);
  if (!threadIdx.x) atomicMax(slot, __float_as_uint(m));
}

__global__ void k_absmax_w(const float* __restrict__ w1, const float* __restrict__ w2,
                           const float* __restrict__ wf1, const float* __restrict__ wf2,
                           Scal* sc) {
  const float* p; int n; unsigned* slot;
  if (blockIdx.x == 0)      { p = w1;  n = 864;   slot = &sc->max_w1; }
  else if (blockIdx.x == 1) { p = w2;  n = 18432; slot = &sc->max_w2; }
  else if (blockIdx.x == 2) { p = wf1; n = 8192;  slot = &sc->max_wf1; }
  else                      { p = wf2; n = 1280;  slot = &sc->max_wf2; }
  float m = 0.f;
  for (int i = threadIdx.x; i < n; i += blockDim.x) m = fmaxf(m, fabsf(p[i]));
  m = block_maxf(m);
  if (!threadIdx.x) atomicMax(slot, __float_as_uint(m));
}

__global__ void k_scales(Scal* sc) {
  sc->s_in = fmaxf(__uint_as_float(sc->max_x),  1e-8f) / 7.f;
  sc->sw1  = fmaxf(__uint_as_float(sc->max_w1), 1e-8f) / 7.f;
  sc->sw2  = fmaxf(__uint_as_float(sc->max_w2), 1e-8f) / 7.f;
  sc->swf1 = fmaxf(__uint_as_float(sc->max_wf1),1e-8f) / 7.f;
  sc->swf2 = fmaxf(__uint_as_float(sc->max_wf2),1e-8f) / 7.f;
}

// 4 floats -> 4 packed int8 codes per thread
__global__ void k_quant_x(const float4* __restrict__ x, unsigned* __restrict__ xq,
                          int n4, const Scal* __restrict__ sc) {
  float s = sc->s_in;
  int i = blockIdx.x * 256 + threadIdx.x;
  if (i >= n4) return;
  float4 v = x[i];
  float f[4] = {v.x, v.y, v.z, v.w};
  unsigned w = 0;
#pragma unroll
  for (int k = 0; k < 4; ++k) {
    float q = rintf(f[k] / s);
    q = fminf(fmaxf(q, -8.f), 7.f);
    w |= ((unsigned)((int)q & 255)) << (8 * k);
  }
  xq[i] = w;
}

// pack w1 as [oc][row] dwords {w0,w1,w2,0}; w2 directly into the MFMA B-frag
// layout w2frag[((tap*2+half)*64 + dl)*4 + q]; bias1 ints
__global__ void k_quant_w(const float* __restrict__ w1, const float* __restrict__ w2,
                          const float* __restrict__ b1, const Scal* __restrict__ sc,
                          unsigned* __restrict__ w1pk, unsigned* __restrict__ w2frag,
                          int* __restrict__ bint1) {
  int i = blockIdx.x * blockDim.x + threadIdx.x;
  if (i < 288) {
    int oc = i / 9, r = i - oc * 9;   // r = ic*3 + kh; bytes = kw 0..2
    float s = sc->sw1;
    unsigned w = 0;
#pragma unroll
    for (int k = 0; k < 3; ++k) {
      float q = rintf(w1[oc * 27 + r * 3 + k] / s);
      q = fminf(fmaxf(q, -8.f), 7.f);
      w |= ((unsigned)((int)q & 255)) << (8 * k);
    }
    w1pk[i] = w;
  } else if (i < 288 + 4608) {
    int j = i - 288;
    int icq = j & 7; int t = j >> 3;
    int kw = t % 3; t /= 3;
    int kh = t % 3; int oc = t / 3;
    float s = sc->sw2;
    unsigned w = 0;
#pragma unroll
    for (int k = 0; k < 4; ++k) {
      int ic = icq * 4 + k;
      float q = rintf(w2[(oc * 32 + ic) * 9 + kh * 3 + kw] / s);
      q = fminf(fmaxf(q, -8.f), 7.f);
      w |= ((unsigned)((int)q & 255)) << (8 * k);
    }
    int tap = kh * 3 + kw;
    int dl = (oc & 31) | ((icq >> 2) << 5);
    w2frag[(((tap * 2) + (oc >> 5)) * 64 + dl) * 4 + (icq & 3)] = w;
  } else if (i < 288 + 4608 + 32) {
    int j = i - 4896;
    bint1[j] = (int)rintf(b1[j] / (sc->s_in * sc->sw1));
  }
}

// conv1 pass A: LDS-tiled, MAX ONLY (no stores). One block = (b, 6-row strip).
__global__ void __launch_bounds__(256) k_conv1a(
    const signed char* __restrict__ xq, const unsigned* __restrict__ w1pk,
    const int* __restrict__ bint1, int* __restrict__ max1) {
  __shared__ signed char lx[3 * 8 * 224 + 16];
  __shared__ unsigned lw[288];
  __shared__ int lb[32];
  int tid = threadIdx.x;
  int strip = blockIdx.x;   // 0..36
  int b = blockIdx.y;       // 0..31
  int oh0 = strip * 6;

  for (int i = tid; i < 288; i += 256) lw[i] = w1pk[i];
  if (tid < 32) lb[tid] = bint1[tid];
  {
    const unsigned* src = (const unsigned*)(xq + (size_t)b * 3 * 224 * 224);
    unsigned* dst = (unsigned*)lx;
#pragma unroll
    for (int it = 0; it < 6; ++it) {
      int i = it * 256 + tid;
      if (i < 1344) {
        int row = i / 56, d = i - row * 56;
        int ic = row >> 3, r = row & 7;
        dst[i] = src[(ic * 224 + (oh0 + r)) * 56 + d];
      }
    }
  }
  __syncthreads();

  int mx = 0;
  for (int it = 0; it < 21; ++it) {
    int i = it * 256 + tid;
    int g = i % 28;
    int r = i / 28;
    int oh_l = r % 6;
    int oc = r / 6;

    int bias = lb[oc];
    int acc[8];
#pragma unroll
    for (int j = 0; j < 8; ++j) acc[j] = bias;

#pragma unroll
    for (int seg = 0; seg < 9; ++seg) {
      int ic = seg / 3, kh = seg - ic * 3;
      const signed char* base = lx + (ic * 8 + oh_l + kh) * 224 + g * 8;
      uint2 lo = *(const uint2*)base;
      unsigned d0 = lo.x, d1 = lo.y;
      unsigned d2 = *(const unsigned*)(base + 8);
      unsigned wr = lw[oc * 9 + ic * 3 + kh];
      acc[0] = dot4(d0, wr, acc[0]);
      acc[1] = dot4(alignb(d1, d0, 1), wr, acc[1]);
      acc[2] = dot4(alignb(d1, d0, 2), wr, acc[2]);
      acc[3] = dot4(alignb(d1, d0, 3), wr, acc[3]);
      acc[4] = dot4(d1, wr, acc[4]);
      acc[5] = dot4(alignb(d2, d1, 1), wr, acc[5]);
      acc[6] = dot4(alignb(d2, d1, 2), wr, acc[6]);
      acc[7] = dot4(alignb(d2, d1, 3), wr, acc[7]);
    }

#pragma unroll
    for (int j = 0; j < 8; ++j) if (g * 8 + j < 222) mx = max(mx, acc[j]);
  }
  mx = block_maxi(max(mx, 0));
  if (!tid) atomicMax(max1, mx);
}

__global__ void k_fin1(Scal* sc, const float* __restrict__ b2, int* __restrict__ bint2) {
  float sc1 = sc->s_in * sc->sw1;
  float s1 = fmaxf((float)sc->max1 * sc1, 1e-8f) / 15.f;
  if (!threadIdx.x) sc->s1 = s1;
  float sb = s1 * sc->sw2;
  bint2[threadIdx.x] = (int)rintf(b2[threadIdx.x] / sb);
}

// conv1 pass B: recompute acc, quantize in-register, store NHWC uint8 codes
// COALESCED (thread = (oh_l, px-pair, oc-quad); one u32 of 4 codes per px).
// Pixel slot layout: byte offset within 32B slot == oc (matches conv2 A-frag).
__global__ void __launch_bounds__(256) k_conv1b(
    const signed char* __restrict__ xq, const unsigned* __restrict__ w1pk,
    const int* __restrict__ bint1, const Scal* __restrict__ sc,
    unsigned char* __restrict__ y1n) {
  __shared__ signed char lx[3 * 8 * 224 + 16];
  __shared__ unsigned lw[288];
  __shared__ int lb[32];
  int tid = threadIdx.x;
  int strip = blockIdx.x;
  int b = blockIdx.y;
  int oh0 = strip * 6;

  for (int i = tid; i < 288; i += 256) lw[i] = w1pk[i];
  if (tid < 32) lb[tid] = bint1[tid];
  {
    const unsigned* src = (const unsigned*)(xq + (size_t)b * 3 * 224 * 224);
    unsigned* dst = (unsigned*)lx;
#pragma unroll
    for (int it = 0; it < 6; ++it) {
      int i = it * 256 + tid;
      if (i < 1344) {
        int row = i / 56, d = i - row * 56;
        int ic = row >> 3, r = row & 7;
        dst[i] = src[(ic * 224 + (oh0 + r)) * 56 + d];
      }
    }
  }
  __syncthreads();

  float h1 = (sc->s_in * sc->sw1) / sc->s1;

  for (int it = 0; it < 21; ++it) {
    int t = it * 256 + tid;         // 5376 tasks: oc4 fast(8), g2(112), oh_l(6)
    int oc4 = t & 7;
    int r2 = t >> 3;
    int g2 = r2 % 112;
    int oh_l = r2 / 112;
    int p = g2 * 2;                  // even pixel of the pair
    int qb = p & ~3, sh = p & 3;     // sh in {0,2}
    int oc0 = oc4 * 4;

    int acc0[4], acc1[4];
#pragma unroll
    for (int c = 0; c < 4; ++c) { acc0[c] = lb[oc0 + c]; acc1[c] = acc0[c]; }

#pragma unroll
    for (int seg = 0; seg < 9; ++seg) {
      int ic = seg / 3, kh = seg - ic * 3;
      const signed char* base = lx + (ic * 8 + oh_l + kh) * 224 + qb;
      unsigned d0 = *(const unsigned*)base;
      unsigned d1 = *(const unsigned*)(base + 4);
      unsigned wpx0 = alignb(d1, d0, sh);      // bytes p..p+3 (byte3 x w3=0)
      unsigned wpx1 = alignb(d1, d0, sh + 1);  // bytes p+1..p+4
#pragma unroll
      for (int c = 0; c < 4; ++c) {
        unsigned wr = lw[(oc0 + c) * 9 + seg];
        acc0[c] = dot4(wpx0, wr, acc0[c]);
        acc1[c] = dot4(wpx1, wr, acc1[c]);
      }
    }

    unsigned cw0 = 0, cw1 = 0;
#pragma unroll
    for (int c = 0; c < 4; ++c) {
      cw0 |= ((unsigned)(int)qclamp(acc0[c], h1)) << (8 * c);
      cw1 |= ((unsigned)(int)qclamp(acc1[c], h1)) << (8 * c);
    }
    size_t pidx = (size_t)(b * 222 + oh0 + oh_l) * 224 + p;
    unsigned* dst = (unsigned*)(y1n + pidx * 32 + oc0);  // byte offset == oc0
    dst[0] = cw0;        // pixel p,   ocs oc0..oc0+3
    dst[8] = cw1;        // pixel p+1 (+32 bytes = 8 dwords)
  }
}

// conv2 pass A: each wave owns ITER2 CONTIGUOUS tiles (tile = 32px x 2 rows x
// 64oc, 36 MFMA). Weights staged once; no barriers in loop; owg!=6 fast path.
__global__ void __launch_bounds__(256) k_conv2a(
    const unsigned char* __restrict__ y1n, const unsigned* __restrict__ w2frag,
    const int* __restrict__ bint2, int* __restrict__ max2) {
  __shared__ unsigned lw[4608];
  int tid = threadIdx.x;
  for (int i = tid; i < 4608; i += 256) lw[i] = w2frag[i];
  __syncthreads();

  int lane = tid & 63;
  int lane31 = lane & 31, lhalf = lane >> 5;
  int bias0 = bint2[lane31], bias1 = bint2[32 + lane31];
  size_t aoff = (size_t)lane31 * 32 + (size_t)lhalf * 16;
  int mx = 0;

  for (int it = 0; it < ITER2; ++it) {
    int tb = blockIdx.x * ITER2 + it;
    int wv = tb * 4 + (tid >> 6);
    int owg = wv % 7; int t = wv / 7;
    int ohg = t % 110; int b = t / 110;
    int oh0 = ohg * 2, ow0 = owg * 32;

    const unsigned char* base0 = y1n + ((size_t)((b * 222 + oh0) * 224 + ow0)) * 32 + aoff;
    v4i a[4][3];
#pragma unroll
    for (int i = 0; i < 4; ++i)
#pragma unroll
      for (int kw = 0; kw < 3; ++kw)
        a[i][kw] = *(const v4i*)(base0 + (size_t)i * (224 * 32) + kw * 32);

    v16i acc00, acc01, acc10, acc11;
#pragma unroll
    for (int r = 0; r < 16; ++r) {
      acc00[r] = bias0; acc01[r] = bias1;
      acc10[r] = bias0; acc11[r] = bias1;
    }

#pragma unroll
    for (int kh = 0; kh < 3; ++kh)
#pragma unroll
      for (int kw = 0; kw < 3; ++kw) {
        int tap = kh * 3 + kw;
        v4i b0 = *(const v4i*)(lw + (tap * 2 + 0) * 256 + lane * 4);
        v4i b1 = *(const v4i*)(lw + (tap * 2 + 1) * 256 + lane * 4);
        acc00 = __builtin_amdgcn_mfma_i32_32x32x32_i8(a[kh][kw], b0, acc00, 0, 0, 0);
        acc01 = __builtin_amdgcn_mfma_i32_32x32x32_i8(a[kh][kw], b1, acc01, 0, 0, 0);
        acc10 = __builtin_amdgcn_mfma_i32_32x32x32_i8(a[kh + 1][kw], b0, acc10, 0, 0, 0);
        acc11 = __builtin_amdgcn_mfma_i32_32x32x32_i8(a[kh + 1][kw], b1, acc11, 0, 0, 0);
      }

    if (owg != 6) {
#pragma unroll
      for (int r = 0; r < 16; ++r)
        mx = max(mx, max(max(acc00[r], acc01[r]), max(acc10[r], acc11[r])));
    } else {
#pragma unroll
      for (int r = 0; r < 16; ++r) {
        int m = (r & 3) + 8 * (r >> 2) + 4 * lhalf;
        if (ow0 + m < 220)
          mx = max(mx, max(max(acc00[r], acc01[r]), max(acc10[r], acc11[r])));
      }
    }
  }
  mx = block_maxi(max(mx, 0));
  if (!tid) atomicMax(max2, mx);
}

// conv2 pass B: recompute acc per tile, quantize in-register (float sums),
// pool into block-local ls[2048], flush at end.
__global__ void __launch_bounds__(256) k_conv2b(
    const unsigned char* __restrict__ y1n, const unsigned* __restrict__ w2frag,
    const int* __restrict__ bint2, const Scal* __restrict__ sc,
    int* __restrict__ pooled_i) {
  __shared__ unsigned lw[4608];
  __shared__ int ls[2048];
  int tid = threadIdx.x;
  for (int i = tid; i < 4608; i += 256) lw[i] = w2frag[i];
  for (int i = tid; i < 2048; i += 256) ls[i] = 0;
  __syncthreads();

  int lane = tid & 63;
  int lane31 = lane & 31, lhalf = lane >> 5;
  int bias0 = bint2[lane31], bias1 = bint2[32 + lane31];
  size_t aoff = (size_t)lane31 * 32 + (size_t)lhalf * 16;
  float h = (sc->s1 * sc->sw2) * (1.0f / sc->s2);

  for (int it = 0; it < ITER2; ++it) {
    int tb = blockIdx.x * ITER2 + it;
    int wv = tb * 4 + (tid >> 6);
    int owg = wv % 7; int t = wv / 7;
    int ohg = t % 110; int b = t / 110;
    int oh0 = ohg * 2, ow0 = owg * 32;

    const unsigned char* base0 = y1n + ((size_t)((b * 222 + oh0) * 224 + ow0)) * 32 + aoff;
    v4i a[4][3];
#pragma unroll
    for (int i = 0; i < 4; ++i)
#pragma unroll
      for (int kw = 0; kw < 3; ++kw)
        a[i][kw] = *(const v4i*)(base0 + (size_t)i * (224 * 32) + kw * 32);

    v16i acc00, acc01, acc10, acc11;
#pragma unroll
    for (int r = 0; r < 16; ++r) {
      acc00[r] = bias0; acc01[r] = bias1;
      acc10[r] = bias0; acc11[r] = bias1;
    }

#pragma unroll
    for (int kh = 0; kh < 3; ++kh)
#pragma unroll
      for (int kw = 0; kw < 3; ++kw) {
        int tap = kh * 3 + kw;
        v4i b0 = *(const v4i*)(lw + (tap * 2 + 0) * 256 + lane * 4);
        v4i b1 = *(const v4i*)(lw + (tap * 2 + 1) * 256 + lane * 4);
        acc00 = __builtin_amdgcn_mfma_i32_32x32x32_i8(a[kh][kw], b0, acc00, 0, 0, 0);
        acc01 = __builtin_amdgcn_mfma_i32_32x32x32_i8(a[kh][kw], b1, acc01, 0, 0, 0);
        acc10 = __builtin_amdgcn_mfma_i32_32x32x32_i8(a[kh + 1][kw], b0, acc10, 0, 0, 0);
        acc11 = __builtin_amdgcn_mfma_i32_32x32x32_i8(a[kh + 1][kw], b1, acc11, 0, 0, 0);
      }

    float fs0 = 0.f, fs1 = 0.f;
    if (owg != 6) {
#pragma unroll
      for (int r = 0; r < 16; ++r) {
        fs0 += qclamp(acc00[r], h) + qclamp(acc10[r], h);
        fs1 += qclamp(acc01[r], h) + qclamp(acc11[r], h);
      }
    } else {
#pragma unroll
      for (int r = 0; r < 16; ++r) {
        int m = (r & 3) + 8 * (r >> 2) + 4 * lhalf;
        if (ow0 + m < 220) {
          fs0 += qclamp(acc00[r], h) + qclamp(acc10[r], h);
          fs1 += qclamp(acc01[r], h) + qclamp(acc11[r], h);
        }
      }
    }
    int isum0 = (int)fs0, isum1 = (int)fs1;
    isum0 += __shfl_down(isum0, 32, 64);
    isum1 += __shfl_down(isum1, 32, 64);
    if (lhalf == 0) {
      atomicAdd(&ls[b * 64 + lane31], isum0);
      atomicAdd(&ls[b * 64 + 32 + lane31], isum1);
    }
  }
  __syncthreads();
  for (int i = tid; i < 2048; i += 256) {
    int v = ls[i];
    if (v != 0) atomicAdd(&pooled_i[i], v);
  }
}

__global__ void k_fin2(Scal* sc) {
  sc->s2 = fmaxf((float)sc->max2 * (sc->s1 * sc->sw2), 1e-8f) / 15.f;
}

// whole FC head + log_softmax in one 1024-thread block.
__global__ void __launch_bounds__(1024) k_fc(
    const int* __restrict__ pooled_i, const float* __restrict__ wf1,
    const float* __restrict__ bf1, const float* __restrict__ wf2,
    const float* __restrict__ bf2, const Scal* __restrict__ sc,
    float* __restrict__ out) {
  __shared__ float pl[2048];
  __shared__ float wq1[128 * 65];
  __shared__ float y3[32 * 130];
  __shared__ float zz[320];
  __shared__ float s3sh;
  __shared__ float red16[16];
  int tid = threadIdx.x;
  float swf1 = sc->swf1, swf2 = sc->swf2, s2 = sc->s2;
  for (int i = tid; i < 2048; i += 1024) pl[i] = (float)pooled_i[i] * s2 / 48400.0f;
  for (int i = tid; i < 8192; i += 1024) {
    float q = rintf(wf1[i] / swf1);
    q = fminf(fmaxf(q, -8.f), 7.f);
    wq1[(i >> 6) * 65 + (i & 63)] = q * swf1;
  }
  __syncthreads();
  float sb1 = s2 * swf1;
  float lmax = 0.f;
#pragma unroll
  for (int o = tid; o < 4096; o += 1024) {
    int b = o >> 7, j = o & 127;
    float acc = rintf(bf1[j] / sb1) * sb1;
    const float* wrow = &wq1[j * 65];
    const float* xrow = &pl[b * 64];
#pragma unroll 16
    for (int k = 0; k < 64; ++k) acc += xrow[k] * wrow[k];
    float r = fmaxf(acc, 0.f);
    y3[b * 130 + j] = r;
    lmax = fmaxf(lmax, r);
  }
  lmax = wave_maxf(lmax);
  {
    int lane = tid & 63, w = tid >> 6;
    if (!lane) red16[w] = lmax;
  }
  __syncthreads();
  if (tid < 64) {
    float t = (tid < 16) ? red16[tid] : 0.f;
    t = wave_maxf(t);
    if (!tid) s3sh = fmaxf(t, 1e-8f) / 15.f;
  }
  __syncthreads();
  float s3 = s3sh;
  float sb2 = s3 * swf2;
  if (tid < 320) {
    int o = tid;
    int b = o / 10, j = o - b * 10;
    float acc = rintf(bf2[j] / sb2) * sb2;
    const float* yy = &y3[b * 130];
    const float* wrow = &wf2[j * 128];
#pragma unroll 16
    for (int k = 0; k < 128; ++k) {
      float q = rintf(yy[k] / s3);
      q = fminf(fmaxf(q, 0.f), 15.f);
      float wv = rintf(wrow[k] / swf2);
      wv = fminf(fmaxf(wv, -8.f), 7.f);
      acc += (q * s3) * (wv * swf2);
    }
    zz[o] = acc;
  }
  __syncthreads();
  if (tid < 32) {
    const float* z = &zz[tid * 10];
    float mm = z[0];
    for (int k = 1; k < 10; ++k) mm = fmaxf(mm, z[k]);
    float ssum = 0.f;
    for (int k = 0; k < 10; ++k) ssum += expf(z[k] - mm);
    float l = mm + logf(ssum);
    for (int k = 0; k < 10; ++k) out[tid * 10 + k] = z[k] - l;
  }
}

extern "C" void kernel_launch(void* const* d_in, const int* in_sizes, int n_in,
                              void* d_out, int out_size, void* d_ws, size_t ws_size,
                              hipStream_t stream) {
  const float* x   = (const float*)d_in[0];
  const float* w1  = (const float*)d_in[1];
  const float* b1  = (const float*)d_in[2];
  const float* w2  = (const float*)d_in[3];
  const float* b2  = (const float*)d_in[4];
  const float* wf1 = (const float*)d_in[5];
  const float* bf1 = (const float*)d_in[6];
  const float* wf2 = (const float*)d_in[7];
  const float* bf2 = (const float*)d_in[8];
  float* out = (float*)d_out;

  char* ws = (char*)d_ws;
  Scal* sc = (Scal*)ws;
  size_t off = 1024;
  signed char* xq = (signed char*)(ws + off);   off += (size_t)NX + 256;  // +slack
  off = (off + 255) & ~(size_t)255;
  unsigned* w1pk = (unsigned*)(ws + off);       off += 2048;              // [oc][row] {w0,w1,w2,0}
  unsigned* w2frag = (unsigned*)(ws + off);     off += 4608 * 4;          // MFMA B-frag layout
  int* bint1 = (int*)(ws + off);                off += 256;
  int* bint2 = (int*)(ws + off);                off += 256;
  unsigned char* y1n = (unsigned char*)(ws + off); off += (size_t)NP1;    // NHWC codes
  off = (off + 255) & ~(size_t)255;
  int* pooled_i = (int*)(ws + off);             off += 8192;              // also slack for conv2 tail reads
  (void)ws_size; (void)in_sizes; (void)n_in; (void)out_size;

  hipMemsetAsync(sc, 0, 1024, stream);
  hipMemsetAsync(pooled_i, 0, 8192, stream);
  k_absmax_x<<<1024, 256, 0, stream>>>((const float4*)x, NX / 4, &sc->max_x);
  k_absmax_w<<<4, 256, 0, stream>>>(w1, w2, wf1, wf2, sc);
  k_scales<<<1, 1, 0, stream>>>(sc);
  k_quant_x<<<NX / 4 / 256, 256, 0, stream>>>((const float4*)x, (unsigned*)xq, NX / 4, sc);
  k_quant_w<<<22, 256, 0, stream>>>(w1, w2, b1, sc, w1pk, w2frag, bint1);
  k_conv1a<<<dim3(37, 32), 256, 0, stream>>>(xq, w1pk, bint1, &sc->max1);
  k_fin1<<<1, 64, 0, stream>>>(sc, b2, bint2);
  k_conv1b<<<dim3(37, 32), 256, 0, stream>>>(xq, w1pk, bint1, sc, y1n);
  k_conv2a<<<NBLK2, 256, 0, stream>>>(y1n, w2frag, bint2, &sc->max2);
  k_fin2<<<1, 1, 0, stream>>>(sc);
  k_conv2b<<<NBLK2, 256, 0, stream>>>(y1n, w2frag, bint2, sc, pooled_i);
  k_fc<<<1, 1024, 0, stream>>>(pooled_i, wf1, bf1, wf2, bf2, sc, out);
}

// Round 18
// 289.908 us; speedup vs baseline: 1.6943x; 1.0427x over previous
//
#include <hip/hip_runtime.h>
#include <cstdint>
#include <cstddef>

#define DI __device__ __forceinline__

typedef int v4i  __attribute__((ext_vector_type(4)));
typedef int v16i __attribute__((ext_vector_type(16)));

#if defined(__has_builtin)
#if __has_builtin(__builtin_amdgcn_sdot4)
#define HAS_SDOT4 1
#endif
#if __has_builtin(__builtin_amdgcn_alignbyte)
#define HAS_ALIGNBYTE 1
#endif
#endif

DI int dot4(unsigned a, unsigned b, int c) {
#ifdef HAS_SDOT4
  return __builtin_amdgcn_sdot4((int)a, (int)b, c, false);
#else
#pragma unroll
  for (int k = 0; k < 4; ++k)
    c += (int)(signed char)(a >> (8 * k)) * (int)(signed char)(b >> (8 * k));
  return c;
#endif
}

DI unsigned alignb(unsigned hi, unsigned lo, int sh) {  // bytes (hi:lo) >> 8*sh, sh 0..3
#ifdef HAS_ALIGNBYTE
  return __builtin_amdgcn_alignbyte(hi, lo, sh);
#else
  return sh ? ((lo >> (8 * sh)) | (hi << (32 - 8 * sh))) : lo;
#endif
}

DI float qclamp(int a, float h) {  // clamp(rint(a*h), 0, 15) as float
  return fminf(fmaxf(rintf((float)a * h), 0.f), 15.f);
}

// ---------------- scalar block in workspace ----------------
struct Scal {
  unsigned max_x, max_w1, max_w2, max_wf1, max_wf2;  // float bits (abs-max, >=0)
  int max1, max2;
};

DI float mkscale(unsigned bits, float d) { return fmaxf(__uint_as_float(bits), 1e-8f) / d; }
// derived scales — identical expressions everywhere (deterministic fp)
DI float d_s_in(const Scal* sc) { return mkscale(sc->max_x, 7.f); }
DI float d_sw1(const Scal* sc)  { return mkscale(sc->max_w1, 7.f); }
DI float d_sw2(const Scal* sc)  { return mkscale(sc->max_w2, 7.f); }
DI float d_s1(const Scal* sc)   { return fmaxf((float)sc->max1 * (d_s_in(sc) * d_sw1(sc)), 1e-8f) / 15.f; }
DI float d_s2(const Scal* sc)   { return fmaxf((float)sc->max2 * (d_s1(sc) * d_sw2(sc)), 1e-8f) / 15.f; }

static constexpr int NX   = 32 * 3 * 224 * 224;     // 4,816,896
static constexpr int NP1  = 32 * 32 * 222 * 224;    // y1n bytes (padded NHWC codes)
static constexpr int NQX  = NX / 4 / 256;           // 4704 quant_x blocks
static constexpr int NBLK2 = 1540;                  // conv2 blocks (6.01/CU)
static constexpr int ITER2 = 4;                     // contiguous tiles per wave (6160 total)

// ---------------- reduction helpers ----------------
DI float wave_maxf(float v) { for (int o = 32; o; o >>= 1) v = fmaxf(v, __shfl_down(v, o, 64)); return v; }
DI int   wave_maxi(int v)   { for (int o = 32; o; o >>= 1) v = max(v, __shfl_down(v, o, 64));   return v; }

DI float block_maxf(float v) {  // valid in thread 0 (256 threads); all values >= 0
  __shared__ float s[4];
  v = wave_maxf(v);
  int lane = threadIdx.x & 63, w = threadIdx.x >> 6;
  if (!lane) s[w] = v;
  __syncthreads();
  if (threadIdx.x < 64) {
    float t = (threadIdx.x < 4) ? s[threadIdx.x] : 0.f;
    v = wave_maxf(t);
  }
  return v;
}

DI int block_maxi(int v) {  // valid in thread 0 (256 threads); all values >= 0
  __shared__ int s[4];
  v = wave_maxi(v);
  int lane = threadIdx.x & 63, w = threadIdx.x >> 6;
  if (!lane) s[w] = v;
  __syncthreads();
  if (threadIdx.x < 64) {
    int t = (threadIdx.x < 4) ? s[threadIdx.x] : 0;
    v = wave_maxi(t);
  }
  return v;
}

// ---------------- stage kernels ----------------
// merged absmax: blocks 0..1023 = x (grid-stride 1024*256); 1024..1027 = weights
__global__ void k_absmax_xw(const float4* __restrict__ x, int n4,
                            const float* __restrict__ w1, const float* __restrict__ w2,
                            const float* __restrict__ wf1, const float* __restrict__ wf2,
                            Scal* sc) {
  if (blockIdx.x < 1024) {
    float m = 0.f;
    for (int i = blockIdx.x * 256 + threadIdx.x; i < n4; i += 1024 * 256) {
      float4 v = x[i];
      m = fmaxf(m, fmaxf(fmaxf(fabsf(v.x), fabsf(v.y)), fmaxf(fabsf(v.z), fabsf(v.w))));
    }
    m = block_maxf(m);
    if (!threadIdx.x) atomicMax(&sc->max_x, __float_as_uint(m));
    return;
  }
  const float* p; int n; unsigned* slot;
  int wb = blockIdx.x - 1024;
  if (wb == 0)      { p = w1;  n = 864;   slot = &sc->max_w1; }
  else if (wb == 1) { p = w2;  n = 18432; slot = &sc->max_w2; }
  else if (wb == 2) { p = wf1; n = 8192;  slot = &sc->max_wf1; }
  else              { p = wf2; n = 1280;  slot = &sc->max_wf2; }
  float m = 0.f;
  for (int i = threadIdx.x; i < n; i += 256) m = fmaxf(m, fabsf(p[i]));
  m = block_maxf(m);
  if (!threadIdx.x) atomicMax(slot, __float_as_uint(m));
}

// merged quant: blocks < NQX quantize x (4 floats -> 4 codes/thread);
// blocks >= NQX pack w1 dwords {w0,w1,w2,0}, w2 MFMA B-frags, bias1 ints
__global__ void k_quant_xw(const float4* __restrict__ x,
                           const float* __restrict__ w1, const float* __restrict__ w2,
                           const float* __restrict__ b1, const Scal* __restrict__ sc,
                           unsigned* __restrict__ xq, unsigned* __restrict__ w1pk,
                           unsigned* __restrict__ w2frag, int* __restrict__ bint1) {
  if (blockIdx.x < NQX) {
    float s = d_s_in(sc);
    int i = blockIdx.x * 256 + threadIdx.x;
    float4 v = x[i];
    float f[4] = {v.x, v.y, v.z, v.w};
    unsigned w = 0;
#pragma unroll
    for (int k = 0; k < 4; ++k) {
      float q = rintf(f[k] / s);
      q = fminf(fmaxf(q, -8.f), 7.f);
      w |= ((unsigned)((int)q & 255)) << (8 * k);
    }
    xq[i] = w;
    return;
  }
  int i = (blockIdx.x - NQX) * 256 + threadIdx.x;
  if (i < 288) {
    int oc = i / 9, r = i - oc * 9;   // r = ic*3 + kh; bytes = kw 0..2
    float s = d_sw1(sc);
    unsigned w = 0;
#pragma unroll
    for (int k = 0; k < 3; ++k) {
      float q = rintf(w1[oc * 27 + r * 3 + k] / s);
      q = fminf(fmaxf(q, -8.f), 7.f);
      w |= ((unsigned)((int)q & 255)) << (8 * k);
    }
    w1pk[i] = w;
  } else if (i < 288 + 4608) {
    int j = i - 288;
    int icq = j & 7; int t = j >> 3;
    int kw = t % 3; t /= 3;
    int kh = t % 3; int oc = t / 3;
    float s = d_sw2(sc);
    unsigned w = 0;
#pragma unroll
    for (int k = 0; k < 4; ++k) {
      int ic = icq * 4 + k;
      float q = rintf(w2[(oc * 32 + ic) * 9 + kh * 3 + kw] / s);
      q = fminf(fmaxf(q, -8.f), 7.f);
      w |= ((unsigned)((int)q & 255)) << (8 * k);
    }
    int tap = kh * 3 + kw;
    int dl = (oc & 31) | ((icq >> 2) << 5);
    w2frag[(((tap * 2) + (oc >> 5)) * 64 + dl) * 4 + (icq & 3)] = w;
  } else if (i < 288 + 4608 + 32) {
    int j = i - 4896;
    bint1[j] = (int)rintf(b1[j] / (d_s_in(sc) * d_sw1(sc)));
  }
}

// conv1 pass A: LDS-tiled, MAX ONLY (no stores). One block = (b, 6-row strip).
__global__ void __launch_bounds__(256) k_conv1a(
    const signed char* __restrict__ xq, const unsigned* __restrict__ w1pk,
    const int* __restrict__ bint1, int* __restrict__ max1) {
  __shared__ signed char lx[3 * 8 * 224 + 16];
  __shared__ unsigned lw[288];
  __shared__ int lb[32];
  int tid = threadIdx.x;
  int strip = blockIdx.x;   // 0..36
  int b = blockIdx.y;       // 0..31
  int oh0 = strip * 6;

  for (int i = tid; i < 288; i += 256) lw[i] = w1pk[i];
  if (tid < 32) lb[tid] = bint1[tid];
  {
    const unsigned* src = (const unsigned*)(xq + (size_t)b * 3 * 224 * 224);
    unsigned* dst = (unsigned*)lx;
#pragma unroll
    for (int it = 0; it < 6; ++it) {
      int i = it * 256 + tid;
      if (i < 1344) {
        int row = i / 56, d = i - row * 56;
        int ic = row >> 3, r = row & 7;
        dst[i] = src[(ic * 224 + (oh0 + r)) * 56 + d];
      }
    }
  }
  __syncthreads();

  int mx = 0;
  for (int it = 0; it < 21; ++it) {
    int i = it * 256 + tid;
    int g = i % 28;
    int r = i / 28;
    int oh_l = r % 6;
    int oc = r / 6;

    int bias = lb[oc];
    int acc[8];
#pragma unroll
    for (int j = 0; j < 8; ++j) acc[j] = bias;

#pragma unroll
    for (int seg = 0; seg < 9; ++seg) {
      int ic = seg / 3, kh = seg - ic * 3;
      const signed char* base = lx + (ic * 8 + oh_l + kh) * 224 + g * 8;
      uint2 lo = *(const uint2*)base;
      unsigned d0 = lo.x, d1 = lo.y;
      unsigned d2 = *(const unsigned*)(base + 8);
      unsigned wr = lw[oc * 9 + ic * 3 + kh];
      acc[0] = dot4(d0, wr, acc[0]);
      acc[1] = dot4(alignb(d1, d0, 1), wr, acc[1]);
      acc[2] = dot4(alignb(d1, d0, 2), wr, acc[2]);
      acc[3] = dot4(alignb(d1, d0, 3), wr, acc[3]);
      acc[4] = dot4(d1, wr, acc[4]);
      acc[5] = dot4(alignb(d2, d1, 1), wr, acc[5]);
      acc[6] = dot4(alignb(d2, d1, 2), wr, acc[6]);
      acc[7] = dot4(alignb(d2, d1, 3), wr, acc[7]);
    }

#pragma unroll
    for (int j = 0; j < 8; ++j) if (g * 8 + j < 222) mx = max(mx, acc[j]);
  }
  mx = block_maxi(max(mx, 0));
  if (!tid) atomicMax(max1, mx);
}

// conv1 pass B: recompute acc, quantize in-register, store NHWC uint8 codes
// coalesced (thread = (oh_l, px-pair, oc-quad); byte offset in 32B slot == oc).
__global__ void __launch_bounds__(256) k_conv1b(
    const signed char* __restrict__ xq, const unsigned* __restrict__ w1pk,
    const int* __restrict__ bint1, const Scal* __restrict__ sc,
    unsigned char* __restrict__ y1n) {
  __shared__ signed char lx[3 * 8 * 224 + 16];
  __shared__ unsigned lw[288];
  __shared__ int lb[32];
  int tid = threadIdx.x;
  int strip = blockIdx.x;
  int b = blockIdx.y;
  int oh0 = strip * 6;

  for (int i = tid; i < 288; i += 256) lw[i] = w1pk[i];
  if (tid < 32) lb[tid] = bint1[tid];
  {
    const unsigned* src = (const unsigned*)(xq + (size_t)b * 3 * 224 * 224);
    unsigned* dst = (unsigned*)lx;
#pragma unroll
    for (int it = 0; it < 6; ++it) {
      int i = it * 256 + tid;
      if (i < 1344) {
        int row = i / 56, d = i - row * 56;
        int ic = row >> 3, r = row & 7;
        dst[i] = src[(ic * 224 + (oh0 + r)) * 56 + d];
      }
    }
  }
  __syncthreads();

  float h1 = (d_s_in(sc) * d_sw1(sc)) / d_s1(sc);

  for (int it = 0; it < 21; ++it) {
    int t = it * 256 + tid;         // 5376 tasks: oc4 fast(8), g2(112), oh_l(6)
    int oc4 = t & 7;
    int r2 = t >> 3;
    int g2 = r2 % 112;
    int oh_l = r2 / 112;
    int p = g2 * 2;                  // even pixel of the pair
    int qb = p & ~3, sh = p & 3;     // sh in {0,2}
    int oc0 = oc4 * 4;

    int acc0[4], acc1[4];
#pragma unroll
    for (int c = 0; c < 4; ++c) { acc0[c] = lb[oc0 + c]; acc1[c] = acc0[c]; }

#pragma unroll
    for (int seg = 0; seg < 9; ++seg) {
      int ic = seg / 3, kh = seg - ic * 3;
      const signed char* base = lx + (ic * 8 + oh_l + kh) * 224 + qb;
      unsigned d0 = *(const unsigned*)base;
      unsigned d1 = *(const unsigned*)(base + 4);
      unsigned wpx0 = alignb(d1, d0, sh);      // bytes p..p+3 (byte3 x w3=0)
      unsigned wpx1 = alignb(d1, d0, sh + 1);  // bytes p+1..p+4
#pragma unroll
      for (int c = 0; c < 4; ++c) {
        unsigned wr = lw[(oc0 + c) * 9 + seg];
        acc0[c] = dot4(wpx0, wr, acc0[c]);
        acc1[c] = dot4(wpx1, wr, acc1[c]);
      }
    }

    unsigned cw0 = 0, cw1 = 0;
#pragma unroll
    for (int c = 0; c < 4; ++c) {
      cw0 |= ((unsigned)(int)qclamp(acc0[c], h1)) << (8 * c);
      cw1 |= ((unsigned)(int)qclamp(acc1[c], h1)) << (8 * c);
    }
    size_t pidx = (size_t)(b * 222 + oh0 + oh_l) * 224 + p;
    unsigned* dst = (unsigned*)(y1n + pidx * 32 + oc0);  // byte offset == oc0
    dst[0] = cw0;        // pixel p
    dst[8] = cw1;        // pixel p+1 (+32 bytes)
  }
}

// conv2 pass A: each wave owns ITER2 CONTIGUOUS tiles (32px x 2 rows x 64oc,
// 36 MFMA). Weights + per-block bint2 staged once; no barriers in loop.
__global__ void __launch_bounds__(256) k_conv2a(
    const unsigned char* __restrict__ y1n, const unsigned* __restrict__ w2frag,
    const float* __restrict__ b2, const Scal* __restrict__ sc, int* __restrict__ max2) {
  __shared__ unsigned lw[4608];
  __shared__ int lb2[64];
  int tid = threadIdx.x;
  for (int i = tid; i < 4608; i += 256) lw[i] = w2frag[i];
  if (tid < 64) {
    float sb = d_s1(sc) * d_sw2(sc);
    lb2[tid] = (int)rintf(b2[tid] / sb);
  }
  __syncthreads();

  int lane = tid & 63;
  int lane31 = lane & 31, lhalf = lane >> 5;
  int bias0 = lb2[lane31], bias1 = lb2[32 + lane31];
  size_t aoff = (size_t)lane31 * 32 + (size_t)lhalf * 16;
  int mx = 0;

  for (int it = 0; it < ITER2; ++it) {
    int tb = blockIdx.x * ITER2 + it;
    int wv = tb * 4 + (tid >> 6);
    int owg = wv % 7; int t = wv / 7;
    int ohg = t % 110; int b = t / 110;
    int oh0 = ohg * 2, ow0 = owg * 32;

    const unsigned char* base0 = y1n + ((size_t)((b * 222 + oh0) * 224 + ow0)) * 32 + aoff;
    v4i a[4][3];
#pragma unroll
    for (int i = 0; i < 4; ++i)
#pragma unroll
      for (int kw = 0; kw < 3; ++kw)
        a[i][kw] = *(const v4i*)(base0 + (size_t)i * (224 * 32) + kw * 32);

    v16i acc00, acc01, acc10, acc11;
#pragma unroll
    for (int r = 0; r < 16; ++r) {
      acc00[r] = bias0; acc01[r] = bias1;
      acc10[r] = bias0; acc11[r] = bias1;
    }

#pragma unroll
    for (int kh = 0; kh < 3; ++kh)
#pragma unroll
      for (int kw = 0; kw < 3; ++kw) {
        int tap = kh * 3 + kw;
        v4i b0 = *(const v4i*)(lw + (tap * 2 + 0) * 256 + lane * 4);
        v4i b1 = *(const v4i*)(lw + (tap * 2 + 1) * 256 + lane * 4);
        acc00 = __builtin_amdgcn_mfma_i32_32x32x32_i8(a[kh][kw], b0, acc00, 0, 0, 0);
        acc01 = __builtin_amdgcn_mfma_i32_32x32x32_i8(a[kh][kw], b1, acc01, 0, 0, 0);
        acc10 = __builtin_amdgcn_mfma_i32_32x32x32_i8(a[kh + 1][kw], b0, acc10, 0, 0, 0);
        acc11 = __builtin_amdgcn_mfma_i32_32x32x32_i8(a[kh + 1][kw], b1, acc11, 0, 0, 0);
      }

    if (owg != 6) {
#pragma unroll
      for (int r = 0; r < 16; ++r)
        mx = max(mx, max(max(acc00[r], acc01[r]), max(acc10[r], acc11[r])));
    } else {
#pragma unroll
      for (int r = 0; r < 16; ++r) {
        int m = (r & 3) + 8 * (r >> 2) + 4 * lhalf;
        if (ow0 + m < 220)
          mx = max(mx, max(max(acc00[r], acc01[r]), max(acc10[r], acc11[r])));
      }
    }
  }
  mx = block_maxi(max(mx, 0));
  if (!tid) atomicMax(max2, mx);
}

// conv2 pass B: recompute acc per tile, quantize in-register (float sums),
// pool into block-local ls[2048], flush at end.
__global__ void __launch_bounds__(256) k_conv2b(
    const unsigned char* __restrict__ y1n, const unsigned* __restrict__ w2frag,
    const float* __restrict__ b2, const Scal* __restrict__ sc,
    int* __restrict__ pooled_i) {
  __shared__ unsigned lw[4608];
  __shared__ int ls[2048];
  __shared__ int lb2[64];
  int tid = threadIdx.x;
  for (int i = tid; i < 4608; i += 256) lw[i] = w2frag[i];
  for (int i = tid; i < 2048; i += 256) ls[i] = 0;
  if (tid < 64) {
    float sb = d_s1(sc) * d_sw2(sc);
    lb2[tid] = (int)rintf(b2[tid] / sb);
  }
  __syncthreads();

  int lane = tid & 63;
  int lane31 = lane & 31, lhalf = lane >> 5;
  int bias0 = lb2[lane31], bias1 = lb2[32 + lane31];
  size_t aoff = (size_t)lane31 * 32 + (size_t)lhalf * 16;
  float h = (d_s1(sc) * d_sw2(sc)) * (1.0f / d_s2(sc));

  for (int it = 0; it < ITER2; ++it) {
    int tb = blockIdx.x * ITER2 + it;
    int wv = tb * 4 + (tid >> 6);
    int owg = wv % 7; int t = wv / 7;
    int ohg = t % 110; int b = t / 110;
    int oh0 = ohg * 2, ow0 = owg * 32;

    const unsigned char* base0 = y1n + ((size_t)((b * 222 + oh0) * 224 + ow0)) * 32 + aoff;
    v4i a[4][3];
#pragma unroll
    for (int i = 0; i < 4; ++i)
#pragma unroll
      for (int kw = 0; kw < 3; ++kw)
        a[i][kw] = *(const v4i*)(base0 + (size_t)i * (224 * 32) + kw * 32);

    v16i acc00, acc01, acc10, acc11;
#pragma unroll
    for (int r = 0; r < 16; ++r) {
      acc00[r] = bias0; acc01[r] = bias1;
      acc10[r] = bias0; acc11[r] = bias1;
    }

#pragma unroll
    for (int kh = 0; kh < 3; ++kh)
#pragma unroll
      for (int kw = 0; kw < 3; ++kw) {
        int tap = kh * 3 + kw;
        v4i b0 = *(const v4i*)(lw + (tap * 2 + 0) * 256 + lane * 4);
        v4i b1 = *(const v4i*)(lw + (tap * 2 + 1) * 256 + lane * 4);
        acc00 = __builtin_amdgcn_mfma_i32_32x32x32_i8(a[kh][kw], b0, acc00, 0, 0, 0);
        acc01 = __builtin_amdgcn_mfma_i32_32x32x32_i8(a[kh][kw], b1, acc01, 0, 0, 0);
        acc10 = __builtin_amdgcn_mfma_i32_32x32x32_i8(a[kh + 1][kw], b0, acc10, 0, 0, 0);
        acc11 = __builtin_amdgcn_mfma_i32_32x32x32_i8(a[kh + 1][kw], b1, acc11, 0, 0, 0);
      }

    float fs0 = 0.f, fs1 = 0.f;
    if (owg != 6) {
#pragma unroll
      for (int r = 0; r < 16; ++r) {
        fs0 += qclamp(acc00[r], h) + qclamp(acc10[r], h);
        fs1 += qclamp(acc01[r], h) + qclamp(acc11[r], h);
      }
    } else {
#pragma unroll
      for (int r = 0; r < 16; ++r) {
        int m = (r & 3) + 8 * (r >> 2) + 4 * lhalf;
        if (ow0 + m < 220) {
          fs0 += qclamp(acc00[r], h) + qclamp(acc10[r], h);
          fs1 += qclamp(acc01[r], h) + qclamp(acc11[r], h);
        }
      }
    }
    int isum0 = (int)fs0, isum1 = (int)fs1;
    isum0 += __shfl_down(isum0, 32, 64);
    isum1 += __shfl_down(isum1, 32, 64);
    if (lhalf == 0) {
      atomicAdd(&ls[b * 64 + lane31], isum0);
      atomicAdd(&ls[b * 64 + 32 + lane31], isum1);
    }
  }
  __syncthreads();
  for (int i = tid; i < 2048; i += 256) {
    int v = ls[i];
    if (v != 0) atomicAdd(&pooled_i[i], v);
  }
}

// whole FC head + log_softmax in one 1024-thread block.
__global__ void __launch_bounds__(1024) k_fc(
    const int* __restrict__ pooled_i, const float* __restrict__ wf1,
    const float* __restrict__ bf1, const float* __restrict__ wf2,
    const float* __restrict__ bf2, const Scal* __restrict__ sc,
    float* __restrict__ out) {
  __shared__ float pl[2048];
  __shared__ float wq1[128 * 65];
  __shared__ float y3[32 * 130];
  __shared__ float zz[320];
  __shared__ float s3sh;
  __shared__ float red16[16];
  int tid = threadIdx.x;
  float swf1 = mkscale(sc->max_wf1, 7.f), swf2 = mkscale(sc->max_wf2, 7.f);
  float s2 = d_s2(sc);
  for (int i = tid; i < 2048; i += 1024) pl[i] = (float)pooled_i[i] * s2 / 48400.0f;
  for (int i = tid; i < 8192; i += 1024) {
    float q = rintf(wf1[i] / swf1);
    q = fminf(fmaxf(q, -8.f), 7.f);
    wq1[(i >> 6) * 65 + (i & 63)] = q * swf1;
  }
  __syncthreads();
  float sb1 = s2 * swf1;
  float lmax = 0.f;
#pragma unroll
  for (int o = tid; o < 4096; o += 1024) {
    int b = o >> 7, j = o & 127;
    float acc = rintf(bf1[j] / sb1) * sb1;
    const float* wrow = &wq1[j * 65];
    const float* xrow = &pl[b * 64];
#pragma unroll 16
    for (int k = 0; k < 64; ++k) acc += xrow[k] * wrow[k];
    float r = fmaxf(acc, 0.f);
    y3[b * 130 + j] = r;
    lmax = fmaxf(lmax, r);
  }
  lmax = wave_maxf(lmax);
  {
    int lane = tid & 63, w = tid >> 6;
    if (!lane) red16[w] = lmax;
  }
  __syncthreads();
  if (tid < 64) {
    float t = (tid < 16) ? red16[tid] : 0.f;
    t = wave_maxf(t);
    if (!tid) s3sh = fmaxf(t, 1e-8f) / 15.f;
  }
  __syncthreads();
  float s3 = s3sh;
  float sb2 = s3 * swf2;
  if (tid < 320) {
    int o = tid;
    int b = o / 10, j = o - b * 10;
    float acc = rintf(bf2[j] / sb2) * sb2;
    const float* yy = &y3[b * 130];
    const float* wrow = &wf2[j * 128];
#pragma unroll 16
    for (int k = 0; k < 128; ++k) {
      float q = rintf(yy[k] / s3);
      q = fminf(fmaxf(q, 0.f), 15.f);
      float wv = rintf(wrow[k] / swf2);
      wv = fminf(fmaxf(wv, -8.f), 7.f);
      acc += (q * s3) * (wv * swf2);
    }
    zz[o] = acc;
  }
  __syncthreads();
  if (tid < 32) {
    const float* z = &zz[tid * 10];
    float mm = z[0];
    for (int k = 1; k < 10; ++k) mm = fmaxf(mm, z[k]);
    float ssum = 0.f;
    for (int k = 0; k < 10; ++k) ssum += expf(z[k] - mm);
    float l = mm + logf(ssum);
    for (int k = 0; k < 10; ++k) out[tid * 10 + k] = z[k] - l;
  }
}

extern "C" void kernel_launch(void* const* d_in, const int* in_sizes, int n_in,
                              void* d_out, int out_size, void* d_ws, size_t ws_size,
                              hipStream_t stream) {
  const float* x   = (const float*)d_in[0];
  const float* w1  = (const float*)d_in[1];
  const float* b1  = (const float*)d_in[2];
  const float* w2  = (const float*)d_in[3];
  const float* b2  = (const float*)d_in[4];
  const float* wf1 = (const float*)d_in[5];
  const float* bf1 = (const float*)d_in[6];
  const float* wf2 = (const float*)d_in[7];
  const float* bf2 = (const float*)d_in[8];
  float* out = (float*)d_out;

  char* ws = (char*)d_ws;
  Scal* sc = (Scal*)ws;
  int* pooled_i = (int*)(ws + 1024);            // sc + pooled zeroed by ONE memset
  size_t off = 1024 + 8192;
  signed char* xq = (signed char*)(ws + off);   off += (size_t)NX + 256;  // +slack
  off = (off + 255) & ~(size_t)255;
  unsigned* w1pk = (unsigned*)(ws + off);       off += 2048;              // [oc][row] {w0,w1,w2,0}
  unsigned* w2frag = (unsigned*)(ws + off);     off += 4608 * 4;          // MFMA B-frag layout
  int* bint1 = (int*)(ws + off);                off += 256;
  unsigned char* y1n = (unsigned char*)(ws + off); off += (size_t)NP1 + 256; // NHWC codes + tail slack
  (void)ws_size; (void)in_sizes; (void)n_in; (void)out_size;

  hipMemsetAsync(ws, 0, 1024 + 8192, stream);
  k_absmax_xw<<<1028, 256, 0, stream>>>((const float4*)x, NX / 4, w1, w2, wf1, wf2, sc);
  k_quant_xw<<<NQX + 22, 256, 0, stream>>>((const float4*)x, w1, w2, b1, sc,
                                           (unsigned*)xq, w1pk, w2frag, bint1);
  k_conv1a<<<dim3(37, 32), 256, 0, stream>>>(xq, w1pk, bint1, &sc->max1);
  k_conv1b<<<dim3(37, 32), 256, 0, stream>>>(xq, w1pk, bint1, sc, y1n);
  k_conv2a<<<NBLK2, 256, 0, stream>>>(y1n, w2frag, b2, sc, &sc->max2);
  k_conv2b<<<NBLK2, 256, 0, stream>>>(y1n, w2frag, b2, sc, pooled_i);
  k_fc<<<1, 1024, 0, stream>>>(pooled_i, wf1, bf1, wf2, bf2, sc, out);
}